// Round 1
// baseline (3676.814 us; speedup 1.0000x reference)
//
#include <hip/hip_runtime.h>

// GNN forward: 3 x (edge-MLP -> GAT(softmax over col) -> BN+ReLU) -> mean-pool -> MLP.
// All f32. Key restructure: cat(x[row],x[col],ea)@W1 = xa[row]+xb[col]+ea@W1c with
// xa=x@W1a, xb=x@W1b precomputed per node. gat_bias cancels inside BatchNorm -> dropped.
// Workspace usage ~276 MB (edge_attr ping buffer reused in-place across layers).

#define NN 50000
#define NE 800000
#define DP 68           // padded LDS row (floats) to de-conflict banks
#define NEG_SLOPE 0.2f

__device__ __forceinline__ float4 ld4(const float* __restrict__ p){ return *(const float4* __restrict__)p; }
__device__ __forceinline__ void st4(float* __restrict__ p, float4 v){ *(float4* __restrict__)p = v; }
__device__ __forceinline__ float4 f4zero(){ return make_float4(0.f,0.f,0.f,0.f); }
__device__ __forceinline__ float4 f4add3(float4 a, float4 b, float4 c){
  return make_float4(a.x+b.x+c.x, a.y+b.y+c.y, a.z+b.z+c.z, a.w+b.w+c.w);
}
__device__ __forceinline__ float4 f4fma(float a, float4 b, float4 c){
  return make_float4(fmaf(a,b.x,c.x), fmaf(a,b.y,c.y), fmaf(a,b.z,c.z), fmaf(a,b.w,c.w));
}
__device__ __forceinline__ float4 f4relu(float4 a){
  return make_float4(fmaxf(a.x,0.f), fmaxf(a.y,0.f), fmaxf(a.z,0.f), fmaxf(a.w,0.f));
}
__device__ __forceinline__ float f4dot(float4 a, float4 b){
  return fmaf(a.x,b.x, fmaf(a.y,b.y, fmaf(a.z,b.z, a.w*b.w)));
}
// order-preserving float<->uint encode for atomicMax on floats
__device__ __forceinline__ unsigned enc_ord(float f){
  unsigned b = __float_as_uint(f);
  return (b & 0x80000000u) ? ~b : (b | 0x80000000u);
}
__device__ __forceinline__ float dec_ord(unsigned u){
  return (u & 0x80000000u) ? __uint_as_float(u & 0x7FFFFFFFu) : __uint_as_float(~u);
}

// 64x64 @ 64x64 block GEMM fragment: thread owns 4 rows (el0..el0+3) x 4 cols (d0..d0+3).
// inT: LDS [64][DP], W: LDS [64][64] row-major k x d.
__device__ __forceinline__ void gemm_tile(const float* inT, const float* W,
                                          int el0, int d0, float4 acc[4]){
#pragma unroll 4
  for (int kc = 0; kc < 16; ++kc){
    float4 w0 = ld4(&W[(kc*4+0)*64 + d0]);
    float4 w1 = ld4(&W[(kc*4+1)*64 + d0]);
    float4 w2 = ld4(&W[(kc*4+2)*64 + d0]);
    float4 w3 = ld4(&W[(kc*4+3)*64 + d0]);
#pragma unroll
    for (int i = 0; i < 4; ++i){
      float4 iv = ld4(&inT[(el0+i)*DP + kc*4]);
      acc[i] = f4fma(iv.x, w0, acc[i]);
      acc[i] = f4fma(iv.y, w1, acc[i]);
      acc[i] = f4fma(iv.z, w2, acc[i]);
      acc[i] = f4fma(iv.w, w3, acc[i]);
    }
  }
}

// ---------------- node prep: xa = x@W1a, xb = x@W1b, xw = x@gat_w, s_src/s_dst dots
__global__ __launch_bounds__(256) void node_prep(
    const float* __restrict__ x_in,
    const float* __restrict__ em_w1, const float* __restrict__ gat_w,
    const float* __restrict__ att_src, const float* __restrict__ att_dst,
    float* __restrict__ xa, float* __restrict__ xb, float* __restrict__ xw,
    float* __restrict__ ssrc, float* __restrict__ sdst, int l)
{
  __shared__ float xt[64*DP];
  __shared__ float Ws[64*64];
  __shared__ float asrc[64], adst[64];
  const int t = threadIdx.x;
  const int n0 = blockIdx.x * 64;

  { // stage x tile (zero-pad tail rows)
    int nl = t >> 2, q = t & 3;
    int n = n0 + nl;
    float4 v0, v1, v2, v3;
    if (n < NN){
      const float* src = x_in + (size_t)n*64 + q*16;
      v0 = ld4(src); v1 = ld4(src+4); v2 = ld4(src+8); v3 = ld4(src+12);
    } else { v0 = v1 = v2 = v3 = f4zero(); }
    float* dst = &xt[nl*DP + q*16];
    st4(dst, v0); st4(dst+4, v1); st4(dst+8, v2); st4(dst+12, v3);
  }
  if (t < 64) asrc[t] = att_src[l*64 + t];
  else if (t < 128) adst[t-64] = att_dst[l*64 + (t-64)];

  const int nl0 = (t >> 4) << 2;
  const int d0  = (t & 15) << 2;

  for (int p = 0; p < 3; ++p){
    const float* wp = (p == 0) ? (em_w1 + l*12288)
                    : (p == 1) ? (em_w1 + l*12288 + 4096)
                               : (gat_w + l*4096);
    float* op = (p == 0) ? xa : (p == 1) ? xb : xw;
    __syncthreads();                       // x staged / previous-pass W reads done
    for (int i = t; i < 1024; i += 256) st4(&Ws[i*4], ld4(wp + i*4));
    __syncthreads();
    float4 acc[4] = {f4zero(), f4zero(), f4zero(), f4zero()};
    gemm_tile(xt, Ws, nl0, d0, acc);
#pragma unroll
    for (int i = 0; i < 4; ++i){
      int n = n0 + nl0 + i;
      if (n < NN) st4(op + (size_t)n*64 + d0, acc[i]);
    }
    if (p == 2){
      float4 a4 = ld4(&asrc[d0]);
      float4 b4 = ld4(&adst[d0]);
      float ps[4], pd[4];
#pragma unroll
      for (int i = 0; i < 4; ++i){ ps[i] = f4dot(acc[i], a4); pd[i] = f4dot(acc[i], b4); }
#pragma unroll
      for (int off = 8; off; off >>= 1){
#pragma unroll
        for (int i = 0; i < 4; ++i){ ps[i] += __shfl_xor(ps[i], off); pd[i] += __shfl_xor(pd[i], off); }
      }
      if ((t & 15) == 0){
#pragma unroll
        for (int i = 0; i < 4; ++i){
          int n = n0 + nl0 + i;
          if (n < NN){ ssrc[n] = ps[i]; sdst[n] = pd[i]; }
        }
      }
    }
  }
}

// ---------------- fused edge MLP + attention logit + segment max
__global__ __launch_bounds__(256) void edge_mlp(
    const float* __restrict__ ea_in, float* __restrict__ ea_out,
    const float* __restrict__ xa, const float* __restrict__ xb,
    const float* __restrict__ ssrc, const float* __restrict__ sdst,
    const int* __restrict__ ei,
    const float* __restrict__ em_w1, const float* __restrict__ em_b1,
    const float* __restrict__ em_w2, const float* __restrict__ em_b2,
    const float* __restrict__ edge_w, const float* __restrict__ att_edge,
    float* __restrict__ lrelu, unsigned* __restrict__ mU, int l)
{
  __shared__ float W1c[64*64];
  __shared__ float W2s[64*64];
  __shared__ float tile[64*DP];     // reused: ea input, then eh
  __shared__ float b1s[64], b2s[64], vs[64];
  __shared__ int rs[64], cs[64];

  const int t = threadIdx.x;
  const int e0 = blockIdx.x * 64;   // NE % 64 == 0, no tail

  { const float* w1p = em_w1 + l*12288 + 8192;   // rows 128..191 of em_w1[l]
    const float* w2p = em_w2 + l*4096;
    for (int i = t; i < 1024; i += 256){
      st4(&W1c[i*4], ld4(w1p + i*4));
      st4(&W2s[i*4], ld4(w2p + i*4));
    }
  }
  if (t < 64){
    rs[t] = ei[e0 + t];
    // v = edge_w[l] @ att_edge[l]
    float a = 0.f;
    const float* ew = edge_w + l*4096 + t*64;
    const float* ae = att_edge + l*64;
#pragma unroll 8
    for (int j = 0; j < 64; ++j) a = fmaf(ew[j], ae[j], a);
    vs[t] = a;
  } else if (t < 128){
    cs[t-64] = ei[NE + e0 + (t-64)];
  } else if (t < 192){
    b1s[t-128] = em_b1[l*64 + (t-128)];
  } else {
    b2s[t-192] = em_b2[l*64 + (t-192)];
  }
  { // stage edge_attr tile
    int nl = t >> 2, q = t & 3;
    const float* src = ea_in + (size_t)(e0+nl)*64 + q*16;
    float4 v0 = ld4(src), v1 = ld4(src+4), v2 = ld4(src+8), v3 = ld4(src+12);
    float* dst = &tile[nl*DP + q*16];
    st4(dst, v0); st4(dst+4, v1); st4(dst+8, v2); st4(dst+12, v3);
  }
  __syncthreads();

  const int el0 = (t >> 4) << 2;
  const int d0  = (t & 15) << 2;
  const int r0 = rs[el0+0], r1 = rs[el0+1], r2 = rs[el0+2], r3 = rs[el0+3];
  const int c0 = cs[el0+0], c1 = cs[el0+1], c2 = cs[el0+2], c3 = cs[el0+3];

  float4 acc[4];
  { float4 bv = ld4(&b1s[d0]);
    acc[0] = f4add3(bv, ld4(xa + (size_t)r0*64 + d0), ld4(xb + (size_t)c0*64 + d0));
    acc[1] = f4add3(bv, ld4(xa + (size_t)r1*64 + d0), ld4(xb + (size_t)c1*64 + d0));
    acc[2] = f4add3(bv, ld4(xa + (size_t)r2*64 + d0), ld4(xb + (size_t)c2*64 + d0));
    acc[3] = f4add3(bv, ld4(xa + (size_t)r3*64 + d0), ld4(xb + (size_t)c3*64 + d0));
  }
  gemm_tile(tile, W1c, el0, d0, acc);   // + ea @ W1c

  __syncthreads();                      // everyone done reading ea tile
#pragma unroll
  for (int i = 0; i < 4; ++i) st4(&tile[(el0+i)*DP + d0], f4relu(acc[i]));  // eh
  __syncthreads();

  float4 bv2 = ld4(&b2s[d0]);
  float4 acc2[4] = {bv2, bv2, bv2, bv2};
  gemm_tile(tile, W2s, el0, d0, acc2);  // newE = eh @ W2 + b2

  float4 vv = ld4(&vs[d0]);
  float p0 = f4dot(acc2[0], vv), p1 = f4dot(acc2[1], vv);
  float p2 = f4dot(acc2[2], vv), p3 = f4dot(acc2[3], vv);
#pragma unroll
  for (int off = 8; off; off >>= 1){
    p0 += __shfl_xor(p0, off);
    p1 += __shfl_xor(p1, off);
    p2 += __shfl_xor(p2, off);
    p3 += __shfl_xor(p3, off);
  }
#pragma unroll
  for (int i = 0; i < 4; ++i)
    st4(ea_out + (size_t)(e0+el0+i)*64 + d0, acc2[i]);

  if ((t & 15) == 0){
    float pv[4] = {p0, p1, p2, p3};
    int rr[4] = {r0, r1, r2, r3};
    int cc[4] = {c0, c1, c2, c3};
#pragma unroll
    for (int i = 0; i < 4; ++i){
      float logit = ssrc[rr[i]] + sdst[cc[i]] + pv[i];
      float lr = logit > 0.f ? logit : NEG_SLOPE * logit;
      lrelu[e0 + el0 + i] = lr;
      atomicMax(&mU[cc[i]], enc_ord(lr));
    }
  }
}

// ---------------- z = exp(lrelu - m[col]); s[col] += z
__global__ __launch_bounds__(256) void edge_z(
    const float* __restrict__ lrelu, const unsigned* __restrict__ mU,
    const int* __restrict__ ei_col, float* __restrict__ zbuf,
    float* __restrict__ ssum)
{
  int e = blockIdx.x * 256 + threadIdx.x;   // NE % 256 == 0
  int c = ei_col[e];
  float m = dec_ord(mU[c]);
  float z = expf(lrelu[e] - m);
  zbuf[e] = z;
  atomicAdd(&ssum[c], z);
}

// ---------------- h[col] += (z/(s[col]+eps)) * xw[row]
__global__ __launch_bounds__(256) void edge_agg(
    const float* __restrict__ zbuf, const float* __restrict__ ssum,
    const int* __restrict__ ei, const float* __restrict__ xw,
    float* __restrict__ h)
{
  const int t = threadIdx.x;
  const int j = t & 15;          // dim quad
  const int eg = t >> 4;         // 16 edges per pass
  const int e0 = blockIdx.x * 64;
#pragma unroll
  for (int p = 0; p < 4; ++p){
    int e = e0 + p*16 + eg;
    int r = ei[e], c = ei[NE + e];
    float alpha = zbuf[e] / (ssum[c] + 1e-16f);
    float4 xv = ld4(xw + (size_t)r*64 + j*4);
    float* hp = h + (size_t)c*64 + j*4;
    atomicAdd(hp+0, alpha * xv.x);
    atomicAdd(hp+1, alpha * xv.y);
    atomicAdd(hp+2, alpha * xv.z);
    atomicAdd(hp+3, alpha * xv.w);
  }
}

// ---------------- BN stats (sum, sumsq per dim)
__global__ __launch_bounds__(256) void bn_stats(
    const float* __restrict__ h, float* __restrict__ musum, float* __restrict__ sqsum)
{
  const int t = threadIdx.x;
  const int d = t & 63, sub = t >> 6;
  const int base = blockIdx.x * 256;
  float s = 0.f, s2 = 0.f;
  for (int i = sub; i < 256; i += 4){
    int n = base + i;
    if (n < NN){ float v = h[(size_t)n*64 + d]; s += v; s2 = fmaf(v, v, s2); }
  }
  __shared__ float r1[4][64], r2[4][64];
  r1[sub][d] = s; r2[sub][d] = s2;
  __syncthreads();
  if (sub == 0){
    s  = r1[0][d] + r1[1][d] + r1[2][d] + r1[3][d];
    s2 = r2[0][d] + r2[1][d] + r2[2][d] + r2[3][d];
    atomicAdd(&musum[d], s);
    atomicAdd(&sqsum[d], s2);
  }
}

// ---------------- x = relu(BN(h))
__global__ __launch_bounds__(256) void bn_apply(
    const float* __restrict__ h, const float* __restrict__ musum,
    const float* __restrict__ sqsum, const float* __restrict__ gamma,
    const float* __restrict__ beta, float* __restrict__ xout, int l)
{
  int idx = blockIdx.x * 256 + threadIdx.x;   // (NN*64) % 256 == 0
  int d = idx & 63;
  float mu = musum[d] * (1.0f / NN);
  float var = sqsum[d] * (1.0f / NN) - mu * mu;
  float inv = rsqrtf(var + 1e-5f);
  float v = (h[idx] - mu) * inv * gamma[l*64 + d] + beta[l*64 + d];
  xout[idx] = fmaxf(v, 0.f);
}

// ---------------- global mean pool accumulate
__global__ __launch_bounds__(256) void pool_kernel(
    const float* __restrict__ x, const int* __restrict__ batch,
    float* __restrict__ pools, float* __restrict__ pcnt)
{
  int idx = blockIdx.x * 256 + threadIdx.x;
  int n = idx >> 6, d = idx & 63;
  int g = batch[n];
  atomicAdd(&pools[g*64 + d], x[idx]);
  if (d == 0) atomicAdd(&pcnt[g], 1.0f);
}

// ---------------- readout MLP (one block)
__global__ __launch_bounds__(256) void final_mlp(
    const float* __restrict__ pools, const float* __restrict__ pcnt,
    const float* __restrict__ w1, const float* __restrict__ b1,
    const float* __restrict__ w2, const float* __restrict__ b2,
    const float* __restrict__ w3, const float* __restrict__ b3,
    float* __restrict__ out)
{
  __shared__ float g[32*64], h1[32*64], h2[32*32];
  const int t = threadIdx.x;
  for (int i = t; i < 2048; i += 256) g[i] = pools[i] / fmaxf(pcnt[i >> 6], 1.0f);
  __syncthreads();
  for (int i = t; i < 2048; i += 256){
    int gi = i >> 6, d = i & 63;
    float a = b1[d];
    for (int k = 0; k < 64; ++k) a = fmaf(g[gi*64 + k], w1[k*64 + d], a);
    h1[i] = fmaxf(a, 0.f);
  }
  __syncthreads();
  for (int i = t; i < 1024; i += 256){
    int gi = i >> 5, d = i & 31;
    float a = b2[d];
    for (int k = 0; k < 64; ++k) a = fmaf(h1[gi*64 + k], w2[k*32 + d], a);
    h2[i] = fmaxf(a, 0.f);
  }
  __syncthreads();
  if (t < 32){
    float a = b3[0];
    for (int k = 0; k < 32; ++k) a = fmaf(h2[t*32 + k], w3[k], a);
    out[t] = a;
  }
}

extern "C" void kernel_launch(void* const* d_in, const int* in_sizes, int n_in,
                              void* d_out, int out_size, void* d_ws, size_t ws_size,
                              hipStream_t stream)
{
  (void)in_sizes; (void)n_in; (void)out_size; (void)ws_size;
  const float* x0       = (const float*)d_in[0];
  const int*   ei       = (const int*)  d_in[1];
  const float* ea0      = (const float*)d_in[2];
  const int*   batch    = (const int*)  d_in[3];
  const float* em_w1    = (const float*)d_in[4];
  const float* em_b1    = (const float*)d_in[5];
  const float* em_w2    = (const float*)d_in[6];
  const float* em_b2    = (const float*)d_in[7];
  const float* gat_w    = (const float*)d_in[8];
  const float* att_src  = (const float*)d_in[9];
  const float* att_dst  = (const float*)d_in[10];
  const float* edge_w   = (const float*)d_in[11];
  const float* att_edge = (const float*)d_in[12];
  // d_in[13] gat_bias: cancels inside BatchNorm -> unused
  const float* bn_gamma = (const float*)d_in[14];
  const float* bn_beta  = (const float*)d_in[15];
  const float* mlp_w1   = (const float*)d_in[16];
  const float* mlp_b1   = (const float*)d_in[17];
  const float* mlp_w2   = (const float*)d_in[18];
  const float* mlp_b2   = (const float*)d_in[19];
  const float* mlp_w3   = (const float*)d_in[20];
  const float* mlp_b3   = (const float*)d_in[21];
  float* out = (float*)d_out;

  const size_t N64 = (size_t)NN * 64, E64 = (size_t)NE * 64;
  float* ws    = (float*)d_ws;
  float* wsE   = ws;                 // E64  : edge_attr (in-place across layers)
  float* xa    = wsE + E64;          // N64
  float* xb    = xa + N64;           // N64
  float* xw    = xb + N64;           // N64
  float* xcur  = xw + N64;           // N64
  float* hbuf  = xcur + N64;         // N64  -- memset region start
  unsigned* mU = (unsigned*)(hbuf + N64);  // NN
  float* ssum  = (float*)(mU + NN);  // NN
  float* musum = ssum + NN;          // 64
  float* sqsum = musum + 64;         // 64   -- memset region end
  float* lrelu = sqsum + 64;         // NE
  float* zbuf  = lrelu + NE;         // NE
  float* pools = zbuf + NE;          // 2048
  float* pcnt  = pools + 2048;       // 32
  float* ssrc  = pcnt + 32;          // NN
  float* sdst  = ssrc + NN;          // NN

  const size_t zero_bytes = (N64 + NN + NN + 128) * sizeof(float);

  for (int l = 0; l < 3; ++l){
    const float* x_in  = (l == 0) ? x0  : xcur;
    const float* ea_in = (l == 0) ? ea0 : wsE;

    hipMemsetAsync(hbuf, 0, zero_bytes, stream);

    node_prep<<<(NN + 63) / 64, 256, 0, stream>>>(
        x_in, em_w1, gat_w, att_src, att_dst, xa, xb, xw, ssrc, sdst, l);

    edge_mlp<<<NE / 64, 256, 0, stream>>>(
        ea_in, wsE, xa, xb, ssrc, sdst, ei,
        em_w1, em_b1, em_w2, em_b2, edge_w, att_edge, lrelu, mU, l);

    edge_z<<<NE / 256, 256, 0, stream>>>(lrelu, mU, ei + NE, zbuf, ssum);

    edge_agg<<<NE / 64, 256, 0, stream>>>(zbuf, ssum, ei, xw, hbuf);

    bn_stats<<<(NN + 255) / 256, 256, 0, stream>>>(hbuf, musum, sqsum);

    bn_apply<<<(int)(N64 / 256), 256, 0, stream>>>(
        hbuf, musum, sqsum, bn_gamma, bn_beta, xcur, l);
  }

  hipMemsetAsync(pools, 0, (2048 + 32) * sizeof(float), stream);
  pool_kernel<<<(int)(N64 / 256), 256, 0, stream>>>(xcur, batch, pools, pcnt);
  final_mlp<<<1, 256, 0, stream>>>(pools, pcnt, mlp_w1, mlp_b1, mlp_w2, mlp_b2,
                                   mlp_w3, mlp_b3, out);
}

// Round 2
// 1844.460 us; speedup vs baseline: 1.9934x; 1.9934x over previous
//
#include <hip/hip_runtime.h>

// GNN forward: 3 x (edge-MLP -> GAT(softmax over col) -> BN+ReLU) -> mean-pool -> MLP.
// All f32. Round-2 change: counting-sort edges by col ONCE (edge_index is layer-
// invariant), keep edge_attr in sorted order across layers. Segment softmax +
// aggregation become one atomic-free kernel (col_agg): one wave per destination
// node walks its contiguous segment. Kills the 3x682us atomic-bound edge_agg.

#define NN 50000
#define NE 800000
#define DP 68           // padded LDS row (floats) to de-conflict banks
#define NEG_SLOPE 0.2f

__device__ __forceinline__ float4 ld4(const float* __restrict__ p){ return *(const float4* __restrict__)p; }
__device__ __forceinline__ void st4(float* __restrict__ p, float4 v){ *(float4* __restrict__)p = v; }
__device__ __forceinline__ float4 f4zero(){ return make_float4(0.f,0.f,0.f,0.f); }
__device__ __forceinline__ float4 f4add3(float4 a, float4 b, float4 c){
  return make_float4(a.x+b.x+c.x, a.y+b.y+c.y, a.z+b.z+c.z, a.w+b.w+c.w);
}
__device__ __forceinline__ float4 f4fma(float a, float4 b, float4 c){
  return make_float4(fmaf(a,b.x,c.x), fmaf(a,b.y,c.y), fmaf(a,b.z,c.z), fmaf(a,b.w,c.w));
}
__device__ __forceinline__ float4 f4relu(float4 a){
  return make_float4(fmaxf(a.x,0.f), fmaxf(a.y,0.f), fmaxf(a.z,0.f), fmaxf(a.w,0.f));
}
__device__ __forceinline__ float f4dot(float4 a, float4 b){
  return fmaf(a.x,b.x, fmaf(a.y,b.y, fmaf(a.z,b.z, a.w*b.w)));
}

// 64x64 @ 64x64 block GEMM fragment: thread owns 4 rows x 4 cols.
__device__ __forceinline__ void gemm_tile(const float* inT, const float* W,
                                          int el0, int d0, float4 acc[4]){
#pragma unroll 4
  for (int kc = 0; kc < 16; ++kc){
    float4 w0 = ld4(&W[(kc*4+0)*64 + d0]);
    float4 w1 = ld4(&W[(kc*4+1)*64 + d0]);
    float4 w2 = ld4(&W[(kc*4+2)*64 + d0]);
    float4 w3 = ld4(&W[(kc*4+3)*64 + d0]);
#pragma unroll
    for (int i = 0; i < 4; ++i){
      float4 iv = ld4(&inT[(el0+i)*DP + kc*4]);
      acc[i] = f4fma(iv.x, w0, acc[i]);
      acc[i] = f4fma(iv.y, w1, acc[i]);
      acc[i] = f4fma(iv.z, w2, acc[i]);
      acc[i] = f4fma(iv.w, w3, acc[i]);
    }
  }
}

// ---------------- sort: histogram of col
__global__ __launch_bounds__(256) void hist_kernel(const int* __restrict__ ei_col,
                                                   int* __restrict__ cnt){
  int e = blockIdx.x * 256 + threadIdx.x;
  atomicAdd(&cnt[ei_col[e]], 1);
}

// ---------------- sort: exclusive prefix sum over NN bins (single block)
__global__ __launch_bounds__(256) void scan_kernel(const int* __restrict__ cnt,
                                                   int* __restrict__ off){
  __shared__ int wsum[4];
  __shared__ int carry_s;
  const int t = threadIdx.x;
  const int lane = t & 63, w = t >> 6;
  if (t == 0) carry_s = 0;
  __syncthreads();
  for (int base = 0; base < NN; base += 256){
    int idx = base + t;
    int v = (idx < NN) ? cnt[idx] : 0;
    int x = v;
#pragma unroll
    for (int o = 1; o < 64; o <<= 1){
      int u = __shfl_up(x, o);
      if (lane >= o) x += u;
    }
    if (lane == 63) wsum[w] = x;
    __syncthreads();
    int wo = carry_s;
#pragma unroll
    for (int k = 0; k < 4; ++k) if (k < w) wo += wsum[k];
    int incl = x + wo;
    if (idx < NN) off[idx] = incl - v;   // exclusive
    __syncthreads();
    if (t == 255) carry_s = incl;
    __syncthreads();
  }
  if (t == 0) off[NN] = carry_s;
}

// ---------------- sort: scatter into sorted position
__global__ __launch_bounds__(256) void scatter_kernel(
    const int* __restrict__ ei, const int* __restrict__ off, int* __restrict__ cur,
    int* __restrict__ srow, int* __restrict__ scol, int* __restrict__ perm){
  int e = blockIdx.x * 256 + threadIdx.x;
  int r = ei[e], c = ei[NE + e];
  int pos = off[c] + atomicAdd(&cur[c], 1);
  srow[pos] = r; scol[pos] = c; perm[pos] = e;
}

// ---------------- node prep: xa = x@W1a, xb = x@W1b, xw = x@gat_w, s_src/s_dst dots
__global__ __launch_bounds__(256) void node_prep(
    const float* __restrict__ x_in,
    const float* __restrict__ em_w1, const float* __restrict__ gat_w,
    const float* __restrict__ att_src, const float* __restrict__ att_dst,
    float* __restrict__ xa, float* __restrict__ xb, float* __restrict__ xw,
    float* __restrict__ ssrc, float* __restrict__ sdst, int l)
{
  __shared__ float xt[64*DP];
  __shared__ float Ws[64*64];
  __shared__ float asrc[64], adst[64];
  const int t = threadIdx.x;
  const int n0 = blockIdx.x * 64;

  { int nl = t >> 2, q = t & 3;
    int n = n0 + nl;
    float4 v0, v1, v2, v3;
    if (n < NN){
      const float* src = x_in + (size_t)n*64 + q*16;
      v0 = ld4(src); v1 = ld4(src+4); v2 = ld4(src+8); v3 = ld4(src+12);
    } else { v0 = v1 = v2 = v3 = f4zero(); }
    float* dst = &xt[nl*DP + q*16];
    st4(dst, v0); st4(dst+4, v1); st4(dst+8, v2); st4(dst+12, v3);
  }
  if (t < 64) asrc[t] = att_src[l*64 + t];
  else if (t < 128) adst[t-64] = att_dst[l*64 + (t-64)];

  const int nl0 = (t >> 4) << 2;
  const int d0  = (t & 15) << 2;

  for (int p = 0; p < 3; ++p){
    const float* wp = (p == 0) ? (em_w1 + l*12288)
                    : (p == 1) ? (em_w1 + l*12288 + 4096)
                               : (gat_w + l*4096);
    float* op = (p == 0) ? xa : (p == 1) ? xb : xw;
    __syncthreads();
    for (int i = t; i < 1024; i += 256) st4(&Ws[i*4], ld4(wp + i*4));
    __syncthreads();
    float4 acc[4] = {f4zero(), f4zero(), f4zero(), f4zero()};
    gemm_tile(xt, Ws, nl0, d0, acc);
#pragma unroll
    for (int i = 0; i < 4; ++i){
      int n = n0 + nl0 + i;
      if (n < NN) st4(op + (size_t)n*64 + d0, acc[i]);
    }
    if (p == 2){
      float4 a4 = ld4(&asrc[d0]);
      float4 b4 = ld4(&adst[d0]);
      float ps[4], pd[4];
#pragma unroll
      for (int i = 0; i < 4; ++i){ ps[i] = f4dot(acc[i], a4); pd[i] = f4dot(acc[i], b4); }
#pragma unroll
      for (int off = 8; off; off >>= 1){
#pragma unroll
        for (int i = 0; i < 4; ++i){ ps[i] += __shfl_xor(ps[i], off); pd[i] += __shfl_xor(pd[i], off); }
      }
      if ((t & 15) == 0){
#pragma unroll
        for (int i = 0; i < 4; ++i){
          int n = n0 + nl0 + i;
          if (n < NN){ ssrc[n] = ps[i]; sdst[n] = pd[i]; }
        }
      }
    }
  }
}

// ---------------- fused edge MLP + attention logit (sorted edge order, no atomics)
__global__ __launch_bounds__(256) void edge_mlp(
    const float* __restrict__ ea_in, float* __restrict__ ea_out,
    const float* __restrict__ xa, const float* __restrict__ xb,
    const float* __restrict__ ssrc, const float* __restrict__ sdst,
    const int* __restrict__ srow, const int* __restrict__ scol,
    const int* __restrict__ permp,                 // null after layer 0
    const float* __restrict__ em_w1, const float* __restrict__ em_b1,
    const float* __restrict__ em_w2, const float* __restrict__ em_b2,
    const float* __restrict__ edge_w, const float* __restrict__ att_edge,
    float* __restrict__ lrelu, int l)
{
  __shared__ float W1c[64*64];
  __shared__ float W2s[64*64];
  __shared__ float tile[64*DP];     // reused: ea input, then eh
  __shared__ float b1s[64], b2s[64], vs[64];
  __shared__ int rs[64], cs[64];

  const int t = threadIdx.x;
  const int e0 = blockIdx.x * 64;   // NE % 64 == 0

  { const float* w1p = em_w1 + l*12288 + 8192;   // rows 128..191 of em_w1[l]
    const float* w2p = em_w2 + l*4096;
    for (int i = t; i < 1024; i += 256){
      st4(&W1c[i*4], ld4(w1p + i*4));
      st4(&W2s[i*4], ld4(w2p + i*4));
    }
  }
  if (t < 64){
    rs[t] = srow[e0 + t];
    float a = 0.f;
    const float* ew = edge_w + l*4096 + t*64;
    const float* ae = att_edge + l*64;
#pragma unroll 8
    for (int j = 0; j < 64; ++j) a = fmaf(ew[j], ae[j], a);
    vs[t] = a;
  } else if (t < 128){
    cs[t-64] = scol[e0 + (t-64)];
  } else if (t < 192){
    b1s[t-128] = em_b1[l*64 + (t-128)];
  } else {
    b2s[t-192] = em_b2[l*64 + (t-192)];
  }
  { // stage edge_attr tile (gather via perm on layer 0)
    int nl = t >> 2, q = t & 3;
    int se = e0 + nl;
    int ge = permp ? permp[se] : se;
    const float* src = ea_in + (size_t)ge*64 + q*16;
    float4 v0 = ld4(src), v1 = ld4(src+4), v2 = ld4(src+8), v3 = ld4(src+12);
    float* dst = &tile[nl*DP + q*16];
    st4(dst, v0); st4(dst+4, v1); st4(dst+8, v2); st4(dst+12, v3);
  }
  __syncthreads();

  const int el0 = (t >> 4) << 2;
  const int d0  = (t & 15) << 2;
  const int r0 = rs[el0+0], r1 = rs[el0+1], r2 = rs[el0+2], r3 = rs[el0+3];
  const int c0 = cs[el0+0], c1 = cs[el0+1], c2 = cs[el0+2], c3 = cs[el0+3];

  float4 acc[4];
  { float4 bv = ld4(&b1s[d0]);
    acc[0] = f4add3(bv, ld4(xa + (size_t)r0*64 + d0), ld4(xb + (size_t)c0*64 + d0));
    acc[1] = f4add3(bv, ld4(xa + (size_t)r1*64 + d0), ld4(xb + (size_t)c1*64 + d0));
    acc[2] = f4add3(bv, ld4(xa + (size_t)r2*64 + d0), ld4(xb + (size_t)c2*64 + d0));
    acc[3] = f4add3(bv, ld4(xa + (size_t)r3*64 + d0), ld4(xb + (size_t)c3*64 + d0));
  }
  gemm_tile(tile, W1c, el0, d0, acc);   // + ea @ W1c

  __syncthreads();
#pragma unroll
  for (int i = 0; i < 4; ++i) st4(&tile[(el0+i)*DP + d0], f4relu(acc[i]));  // eh
  __syncthreads();

  float4 bv2 = ld4(&b2s[d0]);
  float4 acc2[4] = {bv2, bv2, bv2, bv2};
  gemm_tile(tile, W2s, el0, d0, acc2);  // newE = eh @ W2 + b2

  float4 vv = ld4(&vs[d0]);
  float p0 = f4dot(acc2[0], vv), p1 = f4dot(acc2[1], vv);
  float p2 = f4dot(acc2[2], vv), p3 = f4dot(acc2[3], vv);
#pragma unroll
  for (int off = 8; off; off >>= 1){
    p0 += __shfl_xor(p0, off);
    p1 += __shfl_xor(p1, off);
    p2 += __shfl_xor(p2, off);
    p3 += __shfl_xor(p3, off);
  }
#pragma unroll
  for (int i = 0; i < 4; ++i)
    st4(ea_out + (size_t)(e0+el0+i)*64 + d0, acc2[i]);

  if ((t & 15) == 0){
    float pv[4] = {p0, p1, p2, p3};
    int rr[4] = {r0, r1, r2, r3};
    int cc[4] = {c0, c1, c2, c3};
#pragma unroll
    for (int i = 0; i < 4; ++i){
      float logit = ssrc[rr[i]] + sdst[cc[i]] + pv[i];
      lrelu[e0 + el0 + i] = logit > 0.f ? logit : NEG_SLOPE * logit;
    }
  }
}

// ---------------- segment softmax + aggregation, atomic-free: one wave per col
__global__ __launch_bounds__(256) void col_agg(
    const float* __restrict__ lrelu, const int* __restrict__ srow,
    const int* __restrict__ off, const float* __restrict__ xw,
    float* __restrict__ h)
{
  const int t = threadIdx.x;
  const int lane = t & 63;
  const int c = blockIdx.x * 4 + (t >> 6);    // NN/4 = 12500 blocks exactly
  const int s0 = off[c], s1 = off[c+1];
  const int L = s1 - s0;

  float m = -3.402823466e38f;
  for (int i = lane; i < L; i += 64) m = fmaxf(m, lrelu[s0+i]);
#pragma unroll
  for (int o = 32; o; o >>= 1) m = fmaxf(m, __shfl_xor(m, o));

  float z0 = 0.f, z1 = 0.f;
  if (lane < L)      z0 = expf(lrelu[s0+lane] - m);
  if (lane+64 < L)   z1 = expf(lrelu[s0+lane+64] - m);
  float s = z0 + z1;
  for (int i = lane+128; i < L; i += 64) s += expf(lrelu[s0+i] - m);  // never in practice
#pragma unroll
  for (int o = 32; o; o >>= 1) s += __shfl_xor(s, o);
  const float inv = 1.f / (s + 1e-16f);

  float hv = 0.f;
  if (L <= 128){
    for (int i = 0; i < L; ++i){
      float z = (i < 64) ? __shfl(z0, i) : __shfl(z1, i - 64);
      int r = srow[s0+i];
      hv = fmaf(z * inv, xw[(size_t)r*64 + lane], hv);
    }
  } else {
    for (int i = 0; i < L; ++i){
      float z = expf(lrelu[s0+i] - m);
      int r = srow[s0+i];
      hv = fmaf(z * inv, xw[(size_t)r*64 + lane], hv);
    }
  }
  h[(size_t)c*64 + lane] = hv;
}

// ---------------- BN stats (sum, sumsq per dim)
__global__ __launch_bounds__(256) void bn_stats(
    const float* __restrict__ h, float* __restrict__ musum, float* __restrict__ sqsum)
{
  const int t = threadIdx.x;
  const int d = t & 63, sub = t >> 6;
  const int base = blockIdx.x * 256;
  float s = 0.f, s2 = 0.f;
  for (int i = sub; i < 256; i += 4){
    int n = base + i;
    if (n < NN){ float v = h[(size_t)n*64 + d]; s += v; s2 = fmaf(v, v, s2); }
  }
  __shared__ float r1[4][64], r2[4][64];
  r1[sub][d] = s; r2[sub][d] = s2;
  __syncthreads();
  if (sub == 0){
    s  = r1[0][d] + r1[1][d] + r1[2][d] + r1[3][d];
    s2 = r2[0][d] + r2[1][d] + r2[2][d] + r2[3][d];
    atomicAdd(&musum[d], s);
    atomicAdd(&sqsum[d], s2);
  }
}

// ---------------- x = relu(BN(h))
__global__ __launch_bounds__(256) void bn_apply(
    const float* __restrict__ h, const float* __restrict__ musum,
    const float* __restrict__ sqsum, const float* __restrict__ gamma,
    const float* __restrict__ beta, float* __restrict__ xout, int l)
{
  int idx = blockIdx.x * 256 + threadIdx.x;
  int d = idx & 63;
  float mu = musum[d] * (1.0f / NN);
  float var = sqsum[d] * (1.0f / NN) - mu * mu;
  float inv = rsqrtf(var + 1e-5f);
  float v = (h[idx] - mu) * inv * gamma[l*64 + d] + beta[l*64 + d];
  xout[idx] = fmaxf(v, 0.f);
}

// ---------------- global mean pool accumulate
__global__ __launch_bounds__(256) void pool_kernel(
    const float* __restrict__ x, const int* __restrict__ batch,
    float* __restrict__ pools, float* __restrict__ pcnt)
{
  int idx = blockIdx.x * 256 + threadIdx.x;
  int n = idx >> 6, d = idx & 63;
  int g = batch[n];
  atomicAdd(&pools[g*64 + d], x[idx]);
  if (d == 0) atomicAdd(&pcnt[g], 1.0f);
}

// ---------------- readout MLP (one block)
__global__ __launch_bounds__(256) void final_mlp(
    const float* __restrict__ pools, const float* __restrict__ pcnt,
    const float* __restrict__ w1, const float* __restrict__ b1,
    const float* __restrict__ w2, const float* __restrict__ b2,
    const float* __restrict__ w3, const float* __restrict__ b3,
    float* __restrict__ out)
{
  __shared__ float g[32*64], h1[32*64], h2[32*32];
  const int t = threadIdx.x;
  for (int i = t; i < 2048; i += 256) g[i] = pools[i] / fmaxf(pcnt[i >> 6], 1.0f);
  __syncthreads();
  for (int i = t; i < 2048; i += 256){
    int gi = i >> 6, d = i & 63;
    float a = b1[d];
    for (int k = 0; k < 64; ++k) a = fmaf(g[gi*64 + k], w1[k*64 + d], a);
    h1[i] = fmaxf(a, 0.f);
  }
  __syncthreads();
  for (int i = t; i < 1024; i += 256){
    int gi = i >> 5, d = i & 31;
    float a = b2[d];
    for (int k = 0; k < 64; ++k) a = fmaf(h1[gi*64 + k], w2[k*32 + d], a);
    h2[i] = fmaxf(a, 0.f);
  }
  __syncthreads();
  if (t < 32){
    float a = b3[0];
    for (int k = 0; k < 32; ++k) a = fmaf(h2[t*32 + k], w3[k], a);
    out[t] = a;
  }
}

extern "C" void kernel_launch(void* const* d_in, const int* in_sizes, int n_in,
                              void* d_out, int out_size, void* d_ws, size_t ws_size,
                              hipStream_t stream)
{
  (void)in_sizes; (void)n_in; (void)out_size; (void)ws_size;
  const float* x0       = (const float*)d_in[0];
  const int*   ei       = (const int*)  d_in[1];
  const float* ea0      = (const float*)d_in[2];
  const int*   batch    = (const int*)  d_in[3];
  const float* em_w1    = (const float*)d_in[4];
  const float* em_b1    = (const float*)d_in[5];
  const float* em_w2    = (const float*)d_in[6];
  const float* em_b2    = (const float*)d_in[7];
  const float* gat_w    = (const float*)d_in[8];
  const float* att_src  = (const float*)d_in[9];
  const float* att_dst  = (const float*)d_in[10];
  const float* edge_w   = (const float*)d_in[11];
  const float* att_edge = (const float*)d_in[12];
  // d_in[13] gat_bias: cancels inside BatchNorm -> unused
  const float* bn_gamma = (const float*)d_in[14];
  const float* bn_beta  = (const float*)d_in[15];
  const float* mlp_w1   = (const float*)d_in[16];
  const float* mlp_b1   = (const float*)d_in[17];
  const float* mlp_w2   = (const float*)d_in[18];
  const float* mlp_b2   = (const float*)d_in[19];
  const float* mlp_w3   = (const float*)d_in[20];
  const float* mlp_b3   = (const float*)d_in[21];
  float* out = (float*)d_out;

  const size_t N64 = (size_t)NN * 64, E64 = (size_t)NE * 64;
  float* ws    = (float*)d_ws;
  float* wsE   = ws;                 // E64 : edge_attr, sorted order (in-place layers)
  float* xa    = wsE + E64;          // N64
  float* xb    = xa + N64;           // N64
  float* xw    = xb + N64;           // N64
  float* xcur  = xw + N64;           // N64
  float* hbuf  = xcur + N64;         // N64
  float* musum = hbuf + N64;         // 64  -- per-layer memset start
  float* sqsum = musum + 64;         // 64  -- per-layer memset end
  float* lrelu = sqsum + 64;         // NE
  float* pools = lrelu + NE;         // 2048
  float* pcnt  = pools + 2048;       // 32
  float* ssrc  = pcnt + 32;          // NN
  float* sdst  = ssrc + NN;          // NN
  int*   cnt   = (int*)(sdst + NN);  // NN  -- once memset start
  int*   cur   = cnt + NN;           // NN  -- once memset end
  int*   soff  = cur + NN;           // NN+1
  int*   srow  = soff + NN + 1;      // NE
  int*   scol  = srow + NE;          // NE
  int*   perm  = scol + NE;          // NE

  // ---- one-time (per call) counting sort of edges by col
  hipMemsetAsync(cnt, 0, 2 * NN * sizeof(int), stream);
  hist_kernel<<<NE / 256, 256, 0, stream>>>(ei + NE, cnt);
  scan_kernel<<<1, 256, 0, stream>>>(cnt, soff);
  scatter_kernel<<<NE / 256, 256, 0, stream>>>(ei, soff, cur, srow, scol, perm);

  for (int l = 0; l < 3; ++l){
    const float* x_in  = (l == 0) ? x0  : xcur;
    const float* ea_in = (l == 0) ? ea0 : wsE;
    const int*   permp = (l == 0) ? perm : nullptr;

    hipMemsetAsync(musum, 0, 128 * sizeof(float), stream);

    node_prep<<<(NN + 63) / 64, 256, 0, stream>>>(
        x_in, em_w1, gat_w, att_src, att_dst, xa, xb, xw, ssrc, sdst, l);

    edge_mlp<<<NE / 64, 256, 0, stream>>>(
        ea_in, wsE, xa, xb, ssrc, sdst, srow, scol, permp,
        em_w1, em_b1, em_w2, em_b2, edge_w, att_edge, lrelu, l);

    col_agg<<<NN / 4, 256, 0, stream>>>(lrelu, srow, soff, xw, hbuf);

    bn_stats<<<(NN + 255) / 256, 256, 0, stream>>>(hbuf, musum, sqsum);

    bn_apply<<<(int)(N64 / 256), 256, 0, stream>>>(
        hbuf, musum, sqsum, bn_gamma, bn_beta, xcur, l);
  }

  hipMemsetAsync(pools, 0, (2048 + 32) * sizeof(float), stream);
  pool_kernel<<<(int)(N64 / 256), 256, 0, stream>>>(xcur, batch, pools, pcnt);
  final_mlp<<<1, 256, 0, stream>>>(pools, pcnt, mlp_w1, mlp_b1, mlp_w2, mlp_b2,
                                   mlp_w3, mlp_b3, out);
}

// Round 3
// 1424.965 us; speedup vs baseline: 2.5803x; 1.2944x over previous
//
#include <hip/hip_runtime.h>

// GNN forward: 3 x (edge-MLP -> GAT(softmax over col) -> BN+ReLU) -> mean-pool -> MLP.
// All f32. Round-3 change: batch is sorted -> mean-pool via contiguous graph
// segments (graph_bounds + seg_pool), killing the 506us atomic-contended
// pool_kernel (3.2M atomicAdds onto 2048 words).

#define NN 50000
#define NE 800000
#define DP 68           // padded LDS row (floats) to de-conflict banks
#define NEG_SLOPE 0.2f

__device__ __forceinline__ float4 ld4(const float* __restrict__ p){ return *(const float4* __restrict__)p; }
__device__ __forceinline__ void st4(float* __restrict__ p, float4 v){ *(float4* __restrict__)p = v; }
__device__ __forceinline__ float4 f4zero(){ return make_float4(0.f,0.f,0.f,0.f); }
__device__ __forceinline__ float4 f4add3(float4 a, float4 b, float4 c){
  return make_float4(a.x+b.x+c.x, a.y+b.y+c.y, a.z+b.z+c.z, a.w+b.w+c.w);
}
__device__ __forceinline__ float4 f4fma(float a, float4 b, float4 c){
  return make_float4(fmaf(a,b.x,c.x), fmaf(a,b.y,c.y), fmaf(a,b.z,c.z), fmaf(a,b.w,c.w));
}
__device__ __forceinline__ float4 f4relu(float4 a){
  return make_float4(fmaxf(a.x,0.f), fmaxf(a.y,0.f), fmaxf(a.z,0.f), fmaxf(a.w,0.f));
}
__device__ __forceinline__ float f4dot(float4 a, float4 b){
  return fmaf(a.x,b.x, fmaf(a.y,b.y, fmaf(a.z,b.z, a.w*b.w)));
}

// 64x64 @ 64x64 block GEMM fragment: thread owns 4 rows x 4 cols.
__device__ __forceinline__ void gemm_tile(const float* inT, const float* W,
                                          int el0, int d0, float4 acc[4]){
#pragma unroll 4
  for (int kc = 0; kc < 16; ++kc){
    float4 w0 = ld4(&W[(kc*4+0)*64 + d0]);
    float4 w1 = ld4(&W[(kc*4+1)*64 + d0]);
    float4 w2 = ld4(&W[(kc*4+2)*64 + d0]);
    float4 w3 = ld4(&W[(kc*4+3)*64 + d0]);
#pragma unroll
    for (int i = 0; i < 4; ++i){
      float4 iv = ld4(&inT[(el0+i)*DP + kc*4]);
      acc[i] = f4fma(iv.x, w0, acc[i]);
      acc[i] = f4fma(iv.y, w1, acc[i]);
      acc[i] = f4fma(iv.z, w2, acc[i]);
      acc[i] = f4fma(iv.w, w3, acc[i]);
    }
  }
}

// ---------------- sort: histogram of col
__global__ __launch_bounds__(256) void hist_kernel(const int* __restrict__ ei_col,
                                                   int* __restrict__ cnt){
  int e = blockIdx.x * 256 + threadIdx.x;
  atomicAdd(&cnt[ei_col[e]], 1);
}

// ---------------- sort: exclusive prefix sum over NN bins (single block)
__global__ __launch_bounds__(256) void scan_kernel(const int* __restrict__ cnt,
                                                   int* __restrict__ off){
  __shared__ int wsum[4];
  __shared__ int carry_s;
  const int t = threadIdx.x;
  const int lane = t & 63, w = t >> 6;
  if (t == 0) carry_s = 0;
  __syncthreads();
  for (int base = 0; base < NN; base += 256){
    int idx = base + t;
    int v = (idx < NN) ? cnt[idx] : 0;
    int x = v;
#pragma unroll
    for (int o = 1; o < 64; o <<= 1){
      int u = __shfl_up(x, o);
      if (lane >= o) x += u;
    }
    if (lane == 63) wsum[w] = x;
    __syncthreads();
    int wo = carry_s;
#pragma unroll
    for (int k = 0; k < 4; ++k) if (k < w) wo += wsum[k];
    int incl = x + wo;
    if (idx < NN) off[idx] = incl - v;   // exclusive
    __syncthreads();
    if (t == 255) carry_s = incl;
    __syncthreads();
  }
  if (t == 0) off[NN] = carry_s;
}

// ---------------- sort: scatter into sorted position
__global__ __launch_bounds__(256) void scatter_kernel(
    const int* __restrict__ ei, const int* __restrict__ off, int* __restrict__ cur,
    int* __restrict__ srow, int* __restrict__ scol, int* __restrict__ perm){
  int e = blockIdx.x * 256 + threadIdx.x;
  int r = ei[e], c = ei[NE + e];
  int pos = off[c] + atomicAdd(&cur[c], 1);
  srow[pos] = r; scol[pos] = c; perm[pos] = e;
}

// ---------------- graph segment boundaries from sorted batch
__global__ __launch_bounds__(256) void graph_bounds(const int* __restrict__ batch,
                                                    int* __restrict__ goff){
  int n = blockIdx.x * 256 + threadIdx.x;
  if (n >= NN) return;
  int bn = batch[n];
  int bp = (n == 0) ? -1 : batch[n-1];
  for (int g = bp + 1; g <= bn; ++g) goff[g] = n;
  if (n == NN - 1){ for (int g = bn + 1; g <= 32; ++g) goff[g] = NN; }
}

// ---------------- node prep: xa = x@W1a, xb = x@W1b, xw = x@gat_w, s_src/s_dst dots
__global__ __launch_bounds__(256) void node_prep(
    const float* __restrict__ x_in,
    const float* __restrict__ em_w1, const float* __restrict__ gat_w,
    const float* __restrict__ att_src, const float* __restrict__ att_dst,
    float* __restrict__ xa, float* __restrict__ xb, float* __restrict__ xw,
    float* __restrict__ ssrc, float* __restrict__ sdst, int l)
{
  __shared__ float xt[64*DP];
  __shared__ float Ws[64*64];
  __shared__ float asrc[64], adst[64];
  const int t = threadIdx.x;
  const int n0 = blockIdx.x * 64;

  { int nl = t >> 2, q = t & 3;
    int n = n0 + nl;
    float4 v0, v1, v2, v3;
    if (n < NN){
      const float* src = x_in + (size_t)n*64 + q*16;
      v0 = ld4(src); v1 = ld4(src+4); v2 = ld4(src+8); v3 = ld4(src+12);
    } else { v0 = v1 = v2 = v3 = f4zero(); }
    float* dst = &xt[nl*DP + q*16];
    st4(dst, v0); st4(dst+4, v1); st4(dst+8, v2); st4(dst+12, v3);
  }
  if (t < 64) asrc[t] = att_src[l*64 + t];
  else if (t < 128) adst[t-64] = att_dst[l*64 + (t-64)];

  const int nl0 = (t >> 4) << 2;
  const int d0  = (t & 15) << 2;

  for (int p = 0; p < 3; ++p){
    const float* wp = (p == 0) ? (em_w1 + l*12288)
                    : (p == 1) ? (em_w1 + l*12288 + 4096)
                               : (gat_w + l*4096);
    float* op = (p == 0) ? xa : (p == 1) ? xb : xw;
    __syncthreads();
    for (int i = t; i < 1024; i += 256) st4(&Ws[i*4], ld4(wp + i*4));
    __syncthreads();
    float4 acc[4] = {f4zero(), f4zero(), f4zero(), f4zero()};
    gemm_tile(xt, Ws, nl0, d0, acc);
#pragma unroll
    for (int i = 0; i < 4; ++i){
      int n = n0 + nl0 + i;
      if (n < NN) st4(op + (size_t)n*64 + d0, acc[i]);
    }
    if (p == 2){
      float4 a4 = ld4(&asrc[d0]);
      float4 b4 = ld4(&adst[d0]);
      float ps[4], pd[4];
#pragma unroll
      for (int i = 0; i < 4; ++i){ ps[i] = f4dot(acc[i], a4); pd[i] = f4dot(acc[i], b4); }
#pragma unroll
      for (int off = 8; off; off >>= 1){
#pragma unroll
        for (int i = 0; i < 4; ++i){ ps[i] += __shfl_xor(ps[i], off); pd[i] += __shfl_xor(pd[i], off); }
      }
      if ((t & 15) == 0){
#pragma unroll
        for (int i = 0; i < 4; ++i){
          int n = n0 + nl0 + i;
          if (n < NN){ ssrc[n] = ps[i]; sdst[n] = pd[i]; }
        }
      }
    }
  }
}

// ---------------- fused edge MLP + attention logit (sorted edge order, no atomics)
__global__ __launch_bounds__(256) void edge_mlp(
    const float* __restrict__ ea_in, float* __restrict__ ea_out,
    const float* __restrict__ xa, const float* __restrict__ xb,
    const float* __restrict__ ssrc, const float* __restrict__ sdst,
    const int* __restrict__ srow, const int* __restrict__ scol,
    const int* __restrict__ permp,                 // null after layer 0
    const float* __restrict__ em_w1, const float* __restrict__ em_b1,
    const float* __restrict__ em_w2, const float* __restrict__ em_b2,
    const float* __restrict__ edge_w, const float* __restrict__ att_edge,
    float* __restrict__ lrelu, int l)
{
  __shared__ float W1c[64*64];
  __shared__ float W2s[64*64];
  __shared__ float tile[64*DP];     // reused: ea input, then eh
  __shared__ float b1s[64], b2s[64], vs[64];
  __shared__ int rs[64], cs[64];

  const int t = threadIdx.x;
  const int e0 = blockIdx.x * 64;   // NE % 64 == 0

  { const float* w1p = em_w1 + l*12288 + 8192;   // rows 128..191 of em_w1[l]
    const float* w2p = em_w2 + l*4096;
    for (int i = t; i < 1024; i += 256){
      st4(&W1c[i*4], ld4(w1p + i*4));
      st4(&W2s[i*4], ld4(w2p + i*4));
    }
  }
  if (t < 64){
    rs[t] = srow[e0 + t];
    float a = 0.f;
    const float* ew = edge_w + l*4096 + t*64;
    const float* ae = att_edge + l*64;
#pragma unroll 8
    for (int j = 0; j < 64; ++j) a = fmaf(ew[j], ae[j], a);
    vs[t] = a;
  } else if (t < 128){
    cs[t-64] = scol[e0 + (t-64)];
  } else if (t < 192){
    b1s[t-128] = em_b1[l*64 + (t-128)];
  } else {
    b2s[t-192] = em_b2[l*64 + (t-192)];
  }
  { // stage edge_attr tile (gather via perm on layer 0)
    int nl = t >> 2, q = t & 3;
    int se = e0 + nl;
    int ge = permp ? permp[se] : se;
    const float* src = ea_in + (size_t)ge*64 + q*16;
    float4 v0 = ld4(src), v1 = ld4(src+4), v2 = ld4(src+8), v3 = ld4(src+12);
    float* dst = &tile[nl*DP + q*16];
    st4(dst, v0); st4(dst+4, v1); st4(dst+8, v2); st4(dst+12, v3);
  }
  __syncthreads();

  const int el0 = (t >> 4) << 2;
  const int d0  = (t & 15) << 2;
  const int r0 = rs[el0+0], r1 = rs[el0+1], r2 = rs[el0+2], r3 = rs[el0+3];
  const int c0 = cs[el0+0], c1 = cs[el0+1], c2 = cs[el0+2], c3 = cs[el0+3];

  float4 acc[4];
  { float4 bv = ld4(&b1s[d0]);
    acc[0] = f4add3(bv, ld4(xa + (size_t)r0*64 + d0), ld4(xb + (size_t)c0*64 + d0));
    acc[1] = f4add3(bv, ld4(xa + (size_t)r1*64 + d0), ld4(xb + (size_t)c1*64 + d0));
    acc[2] = f4add3(bv, ld4(xa + (size_t)r2*64 + d0), ld4(xb + (size_t)c2*64 + d0));
    acc[3] = f4add3(bv, ld4(xa + (size_t)r3*64 + d0), ld4(xb + (size_t)c3*64 + d0));
  }
  gemm_tile(tile, W1c, el0, d0, acc);   // + ea @ W1c

  __syncthreads();
#pragma unroll
  for (int i = 0; i < 4; ++i) st4(&tile[(el0+i)*DP + d0], f4relu(acc[i]));  // eh
  __syncthreads();

  float4 bv2 = ld4(&b2s[d0]);
  float4 acc2[4] = {bv2, bv2, bv2, bv2};
  gemm_tile(tile, W2s, el0, d0, acc2);  // newE = eh @ W2 + b2

  float4 vv = ld4(&vs[d0]);
  float p0 = f4dot(acc2[0], vv), p1 = f4dot(acc2[1], vv);
  float p2 = f4dot(acc2[2], vv), p3 = f4dot(acc2[3], vv);
#pragma unroll
  for (int off = 8; off; off >>= 1){
    p0 += __shfl_xor(p0, off);
    p1 += __shfl_xor(p1, off);
    p2 += __shfl_xor(p2, off);
    p3 += __shfl_xor(p3, off);
  }
#pragma unroll
  for (int i = 0; i < 4; ++i)
    st4(ea_out + (size_t)(e0+el0+i)*64 + d0, acc2[i]);

  if ((t & 15) == 0){
    float pv[4] = {p0, p1, p2, p3};
    int rr[4] = {r0, r1, r2, r3};
    int cc[4] = {c0, c1, c2, c3};
#pragma unroll
    for (int i = 0; i < 4; ++i){
      float logit = ssrc[rr[i]] + sdst[cc[i]] + pv[i];
      lrelu[e0 + el0 + i] = logit > 0.f ? logit : NEG_SLOPE * logit;
    }
  }
}

// ---------------- segment softmax + aggregation, atomic-free: one wave per col
__global__ __launch_bounds__(256) void col_agg(
    const float* __restrict__ lrelu, const int* __restrict__ srow,
    const int* __restrict__ off, const float* __restrict__ xw,
    float* __restrict__ h)
{
  const int t = threadIdx.x;
  const int lane = t & 63;
  const int c = blockIdx.x * 4 + (t >> 6);    // NN/4 = 12500 blocks exactly
  const int s0 = off[c], s1 = off[c+1];
  const int L = s1 - s0;

  float m = -3.402823466e38f;
  for (int i = lane; i < L; i += 64) m = fmaxf(m, lrelu[s0+i]);
#pragma unroll
  for (int o = 32; o; o >>= 1) m = fmaxf(m, __shfl_xor(m, o));

  float z0 = 0.f, z1 = 0.f;
  if (lane < L)      z0 = expf(lrelu[s0+lane] - m);
  if (lane+64 < L)   z1 = expf(lrelu[s0+lane+64] - m);
  float s = z0 + z1;
  for (int i = lane+128; i < L; i += 64) s += expf(lrelu[s0+i] - m);
#pragma unroll
  for (int o = 32; o; o >>= 1) s += __shfl_xor(s, o);
  const float inv = 1.f / (s + 1e-16f);

  float hv = 0.f;
  if (L <= 128){
    for (int i = 0; i < L; ++i){
      float z = (i < 64) ? __shfl(z0, i) : __shfl(z1, i - 64);
      int r = srow[s0+i];
      hv = fmaf(z * inv, xw[(size_t)r*64 + lane], hv);
    }
  } else {
    for (int i = 0; i < L; ++i){
      float z = expf(lrelu[s0+i] - m);
      int r = srow[s0+i];
      hv = fmaf(z * inv, xw[(size_t)r*64 + lane], hv);
    }
  }
  h[(size_t)c*64 + lane] = hv;
}

// ---------------- BN stats (sum, sumsq per dim)
__global__ __launch_bounds__(256) void bn_stats(
    const float* __restrict__ h, float* __restrict__ musum, float* __restrict__ sqsum)
{
  const int t = threadIdx.x;
  const int d = t & 63, sub = t >> 6;
  const int base = blockIdx.x * 256;
  float s = 0.f, s2 = 0.f;
  for (int i = sub; i < 256; i += 4){
    int n = base + i;
    if (n < NN){ float v = h[(size_t)n*64 + d]; s += v; s2 = fmaf(v, v, s2); }
  }
  __shared__ float r1[4][64], r2[4][64];
  r1[sub][d] = s; r2[sub][d] = s2;
  __syncthreads();
  if (sub == 0){
    s  = r1[0][d] + r1[1][d] + r1[2][d] + r1[3][d];
    s2 = r2[0][d] + r2[1][d] + r2[2][d] + r2[3][d];
    atomicAdd(&musum[d], s);
    atomicAdd(&sqsum[d], s2);
  }
}

// ---------------- x = relu(BN(h))
__global__ __launch_bounds__(256) void bn_apply(
    const float* __restrict__ h, const float* __restrict__ musum,
    const float* __restrict__ sqsum, const float* __restrict__ gamma,
    const float* __restrict__ beta, float* __restrict__ xout, int l)
{
  int idx = blockIdx.x * 256 + threadIdx.x;
  int d = idx & 63;
  float mu = musum[d] * (1.0f / NN);
  float var = sqsum[d] * (1.0f / NN) - mu * mu;
  float inv = rsqrtf(var + 1e-5f);
  float v = (h[idx] - mu) * inv * gamma[l*64 + d] + beta[l*64 + d];
  xout[idx] = fmaxf(v, 0.f);
}

// ---------------- mean pool: one block per graph, contiguous segment, no atomics
__global__ __launch_bounds__(256) void seg_pool(
    const float* __restrict__ x, const int* __restrict__ goff,
    float* __restrict__ pools, float* __restrict__ pcnt)
{
  const int g = blockIdx.x;
  const int t = threadIdx.x;
  const int d = t & 63, sub = t >> 6;
  const int s0 = goff[g], s1 = goff[g+1];
  float s = 0.f;
  for (int n = s0 + sub; n < s1; n += 4) s += x[(size_t)n*64 + d];
  __shared__ float r[4][64];
  r[sub][d] = s;
  __syncthreads();
  if (sub == 0){
    s = r[0][d] + r[1][d] + r[2][d] + r[3][d];
    pools[g*64 + d] = s;
    if (d == 0) pcnt[g] = (float)(s1 - s0);
  }
}

// ---------------- readout MLP (one block)
__global__ __launch_bounds__(256) void final_mlp(
    const float* __restrict__ pools, const float* __restrict__ pcnt,
    const float* __restrict__ w1, const float* __restrict__ b1,
    const float* __restrict__ w2, const float* __restrict__ b2,
    const float* __restrict__ w3, const float* __restrict__ b3,
    float* __restrict__ out)
{
  __shared__ float g[32*64], h1[32*64], h2[32*32];
  const int t = threadIdx.x;
  for (int i = t; i < 2048; i += 256) g[i] = pools[i] / fmaxf(pcnt[i >> 6], 1.0f);
  __syncthreads();
  for (int i = t; i < 2048; i += 256){
    int gi = i >> 6, d = i & 63;
    float a = b1[d];
    for (int k = 0; k < 64; ++k) a = fmaf(g[gi*64 + k], w1[k*64 + d], a);
    h1[i] = fmaxf(a, 0.f);
  }
  __syncthreads();
  for (int i = t; i < 1024; i += 256){
    int gi = i >> 5, d = i & 31;
    float a = b2[d];
    for (int k = 0; k < 64; ++k) a = fmaf(h1[gi*64 + k], w2[k*32 + d], a);
    h2[i] = fmaxf(a, 0.f);
  }
  __syncthreads();
  if (t < 32){
    float a = b3[0];
    for (int k = 0; k < 32; ++k) a = fmaf(h2[t*32 + k], w3[k], a);
    out[t] = a;
  }
}

extern "C" void kernel_launch(void* const* d_in, const int* in_sizes, int n_in,
                              void* d_out, int out_size, void* d_ws, size_t ws_size,
                              hipStream_t stream)
{
  (void)in_sizes; (void)n_in; (void)out_size; (void)ws_size;
  const float* x0       = (const float*)d_in[0];
  const int*   ei       = (const int*)  d_in[1];
  const float* ea0      = (const float*)d_in[2];
  const int*   batch    = (const int*)  d_in[3];
  const float* em_w1    = (const float*)d_in[4];
  const float* em_b1    = (const float*)d_in[5];
  const float* em_w2    = (const float*)d_in[6];
  const float* em_b2    = (const float*)d_in[7];
  const float* gat_w    = (const float*)d_in[8];
  const float* att_src  = (const float*)d_in[9];
  const float* att_dst  = (const float*)d_in[10];
  const float* edge_w   = (const float*)d_in[11];
  const float* att_edge = (const float*)d_in[12];
  // d_in[13] gat_bias: cancels inside BatchNorm -> unused
  const float* bn_gamma = (const float*)d_in[14];
  const float* bn_beta  = (const float*)d_in[15];
  const float* mlp_w1   = (const float*)d_in[16];
  const float* mlp_b1   = (const float*)d_in[17];
  const float* mlp_w2   = (const float*)d_in[18];
  const float* mlp_b2   = (const float*)d_in[19];
  const float* mlp_w3   = (const float*)d_in[20];
  const float* mlp_b3   = (const float*)d_in[21];
  float* out = (float*)d_out;

  const size_t N64 = (size_t)NN * 64, E64 = (size_t)NE * 64;
  float* ws    = (float*)d_ws;
  float* wsE   = ws;                 // E64 : edge_attr, sorted order (in-place layers)
  float* xa    = wsE + E64;          // N64
  float* xb    = xa + N64;           // N64
  float* xw    = xb + N64;           // N64
  float* xcur  = xw + N64;           // N64
  float* hbuf  = xcur + N64;         // N64
  float* musum = hbuf + N64;         // 64  -- per-layer memset start
  float* sqsum = musum + 64;         // 64  -- per-layer memset end
  float* lrelu = sqsum + 64;         // NE
  float* pools = lrelu + NE;         // 2048
  float* pcnt  = pools + 2048;       // 32
  float* ssrc  = pcnt + 32;          // NN
  float* sdst  = ssrc + NN;          // NN
  int*   cnt   = (int*)(sdst + NN);  // NN  -- once memset start
  int*   cur   = cnt + NN;           // NN  -- once memset end
  int*   soff  = cur + NN;           // NN+1
  int*   srow  = soff + NN + 1;      // NE
  int*   scol  = srow + NE;          // NE
  int*   perm  = scol + NE;          // NE
  int*   goff  = perm + NE;          // 33

  // ---- one-time (per call) counting sort of edges by col + graph bounds
  hipMemsetAsync(cnt, 0, 2 * NN * sizeof(int), stream);
  hist_kernel<<<NE / 256, 256, 0, stream>>>(ei + NE, cnt);
  scan_kernel<<<1, 256, 0, stream>>>(cnt, soff);
  scatter_kernel<<<NE / 256, 256, 0, stream>>>(ei, soff, cur, srow, scol, perm);
  graph_bounds<<<(NN + 255) / 256, 256, 0, stream>>>(batch, goff);

  for (int l = 0; l < 3; ++l){
    const float* x_in  = (l == 0) ? x0  : xcur;
    const float* ea_in = (l == 0) ? ea0 : wsE;
    const int*   permp = (l == 0) ? perm : nullptr;

    hipMemsetAsync(musum, 0, 128 * sizeof(float), stream);

    node_prep<<<(NN + 63) / 64, 256, 0, stream>>>(
        x_in, em_w1, gat_w, att_src, att_dst, xa, xb, xw, ssrc, sdst, l);

    edge_mlp<<<NE / 64, 256, 0, stream>>>(
        ea_in, wsE, xa, xb, ssrc, sdst, srow, scol, permp,
        em_w1, em_b1, em_w2, em_b2, edge_w, att_edge, lrelu, l);

    col_agg<<<NN / 4, 256, 0, stream>>>(lrelu, srow, soff, xw, hbuf);

    bn_stats<<<(NN + 255) / 256, 256, 0, stream>>>(hbuf, musum, sqsum);

    bn_apply<<<(int)(N64 / 256), 256, 0, stream>>>(
        hbuf, musum, sqsum, bn_gamma, bn_beta, xcur, l);
  }

  seg_pool<<<32, 256, 0, stream>>>(xcur, goff, pools, pcnt);
  final_mlp<<<1, 256, 0, stream>>>(pools, pcnt, mlp_w1, mlp_b1, mlp_w2, mlp_b2,
                                   mlp_w3, mlp_b3, out);
}

// Round 4
// 1233.118 us; speedup vs baseline: 2.9817x; 1.1556x over previous
//
#include <hip/hip_runtime.h>

// GNN forward: 3 x (edge-MLP -> GAT(softmax over col) -> BN+ReLU) -> mean-pool -> MLP.
// Round-4: edge GEMMs via bf16 MFMA (16x16x32, f32 accum). edge_attr stored bf16
// across layers. Weights pre-converted to MFMA B-fragment layout once (prep_weights).
// A/B fragments use one consistent lane->k mapping (k is summed, so any consistent
// permutation is correct); C/D layout is the verified col=lane&15, row=(lane>>4)*4+reg.
// Node-side math stays f32 (accuracy anchor). em_b1 folded into xa.

#define NN 50000
#define NE 800000
#define DP 68
#define NEG_SLOPE 0.2f

typedef __attribute__((ext_vector_type(8))) __bf16 bf16x8;
typedef __attribute__((ext_vector_type(4))) float f32x4;

__device__ __forceinline__ float4 ld4(const float* __restrict__ p){ return *(const float4* __restrict__)p; }
__device__ __forceinline__ void st4(float* __restrict__ p, float4 v){ *(float4* __restrict__)p = v; }
__device__ __forceinline__ float4 f4zero(){ return make_float4(0.f,0.f,0.f,0.f); }
__device__ __forceinline__ float4 f4add(float4 a, float4 b){
  return make_float4(a.x+b.x, a.y+b.y, a.z+b.z, a.w+b.w);
}
__device__ __forceinline__ float4 f4fma(float a, float4 b, float4 c){
  return make_float4(fmaf(a,b.x,c.x), fmaf(a,b.y,c.y), fmaf(a,b.z,c.z), fmaf(a,b.w,c.w));
}
__device__ __forceinline__ float f4dot(float4 a, float4 b){
  return fmaf(a.x,b.x, fmaf(a.y,b.y, fmaf(a.z,b.z, a.w*b.w)));
}
__device__ __forceinline__ bf16x8 cvt8(float4 a, float4 b){
  bf16x8 r;
  r[0]=(__bf16)a.x; r[1]=(__bf16)a.y; r[2]=(__bf16)a.z; r[3]=(__bf16)a.w;
  r[4]=(__bf16)b.x; r[5]=(__bf16)b.y; r[6]=(__bf16)b.z; r[7]=(__bf16)b.w;
  return r;
}

// 64x64 @ 64x64 f32 block GEMM fragment (node_prep only).
__device__ __forceinline__ void gemm_tile(const float* inT, const float* W,
                                          int el0, int d0, float4 acc[4]){
#pragma unroll 4
  for (int kc = 0; kc < 16; ++kc){
    float4 w0 = ld4(&W[(kc*4+0)*64 + d0]);
    float4 w1 = ld4(&W[(kc*4+1)*64 + d0]);
    float4 w2 = ld4(&W[(kc*4+2)*64 + d0]);
    float4 w3 = ld4(&W[(kc*4+3)*64 + d0]);
#pragma unroll
    for (int i = 0; i < 4; ++i){
      float4 iv = ld4(&inT[(el0+i)*DP + kc*4]);
      acc[i] = f4fma(iv.x, w0, acc[i]);
      acc[i] = f4fma(iv.y, w1, acc[i]);
      acc[i] = f4fma(iv.z, w2, acc[i]);
      acc[i] = f4fma(iv.w, w3, acc[i]);
    }
  }
}

// ---------------- sort: histogram of col
__global__ __launch_bounds__(256) void hist_kernel(const int* __restrict__ ei_col,
                                                   int* __restrict__ cnt){
  int e = blockIdx.x * 256 + threadIdx.x;
  atomicAdd(&cnt[ei_col[e]], 1);
}

// ---------------- sort: exclusive prefix sum over NN bins (single block)
__global__ __launch_bounds__(256) void scan_kernel(const int* __restrict__ cnt,
                                                   int* __restrict__ off){
  __shared__ int wsum[4];
  __shared__ int carry_s;
  const int t = threadIdx.x;
  const int lane = t & 63, w = t >> 6;
  if (t == 0) carry_s = 0;
  __syncthreads();
  for (int base = 0; base < NN; base += 256){
    int idx = base + t;
    int v = (idx < NN) ? cnt[idx] : 0;
    int x = v;
#pragma unroll
    for (int o = 1; o < 64; o <<= 1){
      int u = __shfl_up(x, o);
      if (lane >= o) x += u;
    }
    if (lane == 63) wsum[w] = x;
    __syncthreads();
    int wo = carry_s;
#pragma unroll
    for (int k = 0; k < 4; ++k) if (k < w) wo += wsum[k];
    int incl = x + wo;
    if (idx < NN) off[idx] = incl - v;
    __syncthreads();
    if (t == 255) carry_s = incl;
    __syncthreads();
  }
  if (t == 0) off[NN] = carry_s;
}

// ---------------- sort: scatter into sorted position
__global__ __launch_bounds__(256) void scatter_kernel(
    const int* __restrict__ ei, const int* __restrict__ off, int* __restrict__ cur,
    int* __restrict__ srow, int* __restrict__ scol, int* __restrict__ perm){
  int e = blockIdx.x * 256 + threadIdx.x;
  int r = ei[e], c = ei[NE + e];
  int pos = off[c] + atomicAdd(&cur[c], 1);
  srow[pos] = r; scol[pos] = c; perm[pos] = e;
}

// ---------------- graph segment boundaries from sorted batch
__global__ __launch_bounds__(256) void graph_bounds(const int* __restrict__ batch,
                                                    int* __restrict__ goff){
  int n = blockIdx.x * 256 + threadIdx.x;
  if (n >= NN) return;
  int bn = batch[n];
  int bp = (n == 0) ? -1 : batch[n-1];
  for (int g = bp + 1; g <= bn; ++g) goff[g] = n;
  if (n == NN - 1){ for (int g = bn + 1; g <= 32; ++g) goff[g] = NN; }
}

// ---------------- weights -> bf16 MFMA B-fragment layout + v = edge_w @ att_edge
// Fragment mapping (consistent for A and B everywhere): lane l, elem e, step ks:
//   k = ks*32 + (l>>4)*8 + e, n(col)/m(row) = 16*nt + (l&15); piece = (nt*2+ks)*64 + l.
__global__ __launch_bounds__(256) void prep_weights(
    const float* __restrict__ em_w1, const float* __restrict__ em_w2,
    const float* __restrict__ edge_w, const float* __restrict__ att_edge,
    __bf16* __restrict__ w1f, __bf16* __restrict__ w2f, float* __restrict__ vbuf)
{
  const int l = blockIdx.x, t = threadIdx.x;
  const float* W1 = em_w1 + l*12288 + 8192;   // rows 128..191 of em_w1[l]
  const float* W2 = em_w2 + l*4096;
  for (int p = t; p < 512; p += 256){
    int li = p & 63, ks = (p >> 6) & 1, nt = p >> 7;
    int kbase = ks*32 + (li >> 4)*8;
    int j = nt*16 + (li & 15);
    bf16x8 v1, v2;
#pragma unroll
    for (int e = 0; e < 8; ++e){
      v1[e] = (__bf16)W1[(size_t)(kbase+e)*64 + j];
      v2[e] = (__bf16)W2[(size_t)(kbase+e)*64 + j];
    }
    *(bf16x8*)(w1f + (size_t)l*4096 + p*8) = v1;
    *(bf16x8*)(w2f + (size_t)l*4096 + p*8) = v2;
  }
  if (t < 64){
    float a = 0.f;
    const float* ew = edge_w + l*4096 + t*64;
    const float* ae = att_edge + l*64;
#pragma unroll 8
    for (int j = 0; j < 64; ++j) a = fmaf(ew[j], ae[j], a);
    vbuf[l*64 + t] = a;
  }
}

// ---------------- node prep: xa = x@W1a + b1, xb = x@W1b, xw = x@gat_w, att dots
__global__ __launch_bounds__(256) void node_prep(
    const float* __restrict__ x_in,
    const float* __restrict__ em_w1, const float* __restrict__ em_b1,
    const float* __restrict__ gat_w,
    const float* __restrict__ att_src, const float* __restrict__ att_dst,
    float* __restrict__ xa, float* __restrict__ xb, float* __restrict__ xw,
    float* __restrict__ ssrc, float* __restrict__ sdst, int l)
{
  __shared__ float xt[64*DP];
  __shared__ float Ws[64*64];
  __shared__ float asrc[64], adst[64], b1s[64];
  const int t = threadIdx.x;
  const int n0 = blockIdx.x * 64;

  { int nl = t >> 2, q = t & 3;
    int n = n0 + nl;
    float4 v0, v1, v2, v3;
    if (n < NN){
      const float* src = x_in + (size_t)n*64 + q*16;
      v0 = ld4(src); v1 = ld4(src+4); v2 = ld4(src+8); v3 = ld4(src+12);
    } else { v0 = v1 = v2 = v3 = f4zero(); }
    float* dst = &xt[nl*DP + q*16];
    st4(dst, v0); st4(dst+4, v1); st4(dst+8, v2); st4(dst+12, v3);
  }
  if (t < 64) asrc[t] = att_src[l*64 + t];
  else if (t < 128) adst[t-64] = att_dst[l*64 + (t-64)];
  else if (t < 192) b1s[t-128] = em_b1[l*64 + (t-128)];

  const int nl0 = (t >> 4) << 2;
  const int d0  = (t & 15) << 2;

  for (int p = 0; p < 3; ++p){
    const float* wp = (p == 0) ? (em_w1 + l*12288)
                    : (p == 1) ? (em_w1 + l*12288 + 4096)
                               : (gat_w + l*4096);
    float* op = (p == 0) ? xa : (p == 1) ? xb : xw;
    __syncthreads();
    for (int i = t; i < 1024; i += 256) st4(&Ws[i*4], ld4(wp + i*4));
    __syncthreads();
    float4 acc[4] = {f4zero(), f4zero(), f4zero(), f4zero()};
    gemm_tile(xt, Ws, nl0, d0, acc);
    if (p == 0){
      float4 bb = ld4(&b1s[d0]);
#pragma unroll
      for (int i = 0; i < 4; ++i) acc[i] = f4add(acc[i], bb);
    }
#pragma unroll
    for (int i = 0; i < 4; ++i){
      int n = n0 + nl0 + i;
      if (n < NN) st4(op + (size_t)n*64 + d0, acc[i]);
    }
    if (p == 2){
      float4 a4 = ld4(&asrc[d0]);
      float4 b4 = ld4(&adst[d0]);
      float ps[4], pd[4];
#pragma unroll
      for (int i = 0; i < 4; ++i){ ps[i] = f4dot(acc[i], a4); pd[i] = f4dot(acc[i], b4); }
#pragma unroll
      for (int off = 8; off; off >>= 1){
#pragma unroll
        for (int i = 0; i < 4; ++i){ ps[i] += __shfl_xor(ps[i], off); pd[i] += __shfl_xor(pd[i], off); }
      }
      if ((t & 15) == 0){
#pragma unroll
        for (int i = 0; i < 4; ++i){
          int n = n0 + nl0 + i;
          if (n < NN){ ssrc[n] = ps[i]; sdst[n] = pd[i]; }
        }
      }
    }
  }
}

// ---------------- fused edge MLP (MFMA) + attention logit, 128 edges/block
__global__ __launch_bounds__(256) void edge_mlp(
    const float* __restrict__ ea0,   // layer-0 f32 edge_attr (orig order); null l>0
    const __bf16* ea_in,             // bf16 sorted edge_attr (aliases ea_out)
    __bf16* ea_out,
    const float* __restrict__ xa, const float* __restrict__ xb,
    const float* __restrict__ ssrc, const float* __restrict__ sdst,
    const int* __restrict__ srow, const int* __restrict__ scol,
    const int* __restrict__ permp,
    const __bf16* __restrict__ w1f, const __bf16* __restrict__ w2f,
    const float* __restrict__ b2v, const float* __restrict__ vv,
    float* __restrict__ lrelu, int store_ea)
{
  __shared__ __align__(16) unsigned ehw[2048];   // 8 KB: eh in bf16 frag layout
  __shared__ float b2s[64], vs[64];
  __shared__ int rs[128], cs[128], ps[128];
  const int t = threadIdx.x;
  const int w = t >> 6, l = t & 63, m = l & 15, kg = l >> 4;
  const int eb = blockIdx.x * 128;

  if (t < 128){ rs[t] = srow[eb+t]; cs[t] = scol[eb+t]; }
  else if (t < 192){ b2s[t-128] = b2v[t-128]; vs[t-128] = vv[t-128]; }
  if (permp && t < 128) ps[t] = permp[eb+t];
  __syncthreads();

  const bf16x8* B1 = (const bf16x8*)w1f;
  const bf16x8* B2 = (const bf16x8*)w2f;
  const f32x4 z4 = {0.f, 0.f, 0.f, 0.f};

  for (int tile = 0; tile < 2; ++tile){
    const int tb = tile * 64;
    // ---- A fragments (GEMM1): edge row = 16w + m, k = ks*32 + kg*8 + e
    bf16x8 a0, a1;
    { const int elA = tb + 16*w + m;
      if (ea0){
        const float* s = ea0 + (size_t)ps[elA]*64 + kg*8;
        a0 = cvt8(ld4(s),    ld4(s+4));
        a1 = cvt8(ld4(s+32), ld4(s+36));
      } else {
        const __bf16* s = ea_in + (size_t)(eb+elA)*64 + kg*8;
        a0 = *(const bf16x8*)s;
        a1 = *(const bf16x8*)(s+32);
      }
    }
    // ---- GEMM1: acc[nt] = ea @ W1c (f32)
    f32x4 acc[4];
#pragma unroll
    for (int nt = 0; nt < 4; ++nt){
      acc[nt] = __builtin_amdgcn_mfma_f32_16x16x32_bf16(a0, B1[(nt*2+0)*64 + l], z4, 0, 0, 0);
      acc[nt] = __builtin_amdgcn_mfma_f32_16x16x32_bf16(a1, B1[(nt*2+1)*64 + l], acc[nt], 0, 0, 0);
    }
    // ---- epilogue1: + xa[row] (incl b1) + xb[col], relu, -> eh frag LDS (bf16, paired)
    int rr[4], cc[4];
#pragma unroll
    for (int r = 0; r < 4; ++r){
      int el = tb + 16*w + 4*kg + r;   // C-layout row
      rr[r] = rs[el]; cc[r] = cs[el];
    }
#pragma unroll
    for (int nt = 0; nt < 4; ++nt){
      const int j = nt*16 + m;
#pragma unroll
      for (int r = 0; r < 4; ++r){
        float v = acc[nt][r] + xa[(size_t)rr[r]*64 + j] + xb[(size_t)cc[r]*64 + j];
        v = fmaxf(v, 0.f);
        unsigned short hu = __builtin_bit_cast(unsigned short, (__bf16)v);
        int pu = __shfl_xor((int)hu, 1);
        if (!(m & 1)){
          unsigned word = (unsigned)hu | ((unsigned)(pu & 0xffff) << 16);
          int piece = (w*2 + (nt>>1))*64 + (((nt&1)<<1) | (m>>3))*16 + 4*kg + r;
          ehw[piece*4 + ((m&7)>>1)] = word;
        }
      }
    }
    asm volatile("" ::: "memory");   // order eh writes before cross-lane reads (same wave)
    // ---- A2 fragments from eh frag LDS
    bf16x8 a20 = *(const bf16x8*)((const __bf16*)ehw + (size_t)((w*2+0)*64 + kg*16 + m)*8);
    bf16x8 a21 = *(const bf16x8*)((const __bf16*)ehw + (size_t)((w*2+1)*64 + kg*16 + m)*8);
    // ---- GEMM2: acc2[nt] = eh @ W2
    f32x4 acc2[4];
#pragma unroll
    for (int nt = 0; nt < 4; ++nt){
      acc2[nt] = __builtin_amdgcn_mfma_f32_16x16x32_bf16(a20, B2[(nt*2+0)*64 + l], z4, 0, 0, 0);
      acc2[nt] = __builtin_amdgcn_mfma_f32_16x16x32_bf16(a21, B2[(nt*2+1)*64 + l], acc2[nt], 0, 0, 0);
    }
    // ---- epilogue2: + b2, store bf16 ea_out, logit partials
    float p0 = 0.f, p1 = 0.f, p2 = 0.f, p3 = 0.f;
#pragma unroll
    for (int nt = 0; nt < 4; ++nt){
      const int j = nt*16 + m;
      const float bj = b2s[j], vj = vs[j];
      float v0 = acc2[nt][0] + bj, v1 = acc2[nt][1] + bj;
      float v2 = acc2[nt][2] + bj, v3 = acc2[nt][3] + bj;
      if (store_ea){
        const size_t rowb = (size_t)(eb + tb + 16*w + 4*kg)*64 + j;
        ea_out[rowb +   0] = (__bf16)v0;
        ea_out[rowb +  64] = (__bf16)v1;
        ea_out[rowb + 128] = (__bf16)v2;
        ea_out[rowb + 192] = (__bf16)v3;
      }
      p0 = fmaf(v0, vj, p0); p1 = fmaf(v1, vj, p1);
      p2 = fmaf(v2, vj, p2); p3 = fmaf(v3, vj, p3);
    }
#pragma unroll
    for (int o = 8; o; o >>= 1){
      p0 += __shfl_xor(p0, o); p1 += __shfl_xor(p1, o);
      p2 += __shfl_xor(p2, o); p3 += __shfl_xor(p3, o);
    }
    if (m == 0){
      float pv[4] = {p0, p1, p2, p3};
#pragma unroll
      for (int r = 0; r < 4; ++r){
        int el = tb + 16*w + 4*kg + r;
        float logit = ssrc[rr[r]] + sdst[cc[r]] + pv[r];
        lrelu[eb + el] = logit > 0.f ? logit : NEG_SLOPE * logit;
      }
    }
    asm volatile("" ::: "memory");   // keep next tile's eh writes after this tile's reads
  }
}

// ---------------- segment softmax + aggregation, atomic-free: one wave per col
__global__ __launch_bounds__(256) void col_agg(
    const float* __restrict__ lrelu, const int* __restrict__ srow,
    const int* __restrict__ off, const float* __restrict__ xw,
    float* __restrict__ h)
{
  const int t = threadIdx.x;
  const int lane = t & 63;
  const int c = blockIdx.x * 4 + (t >> 6);
  const int s0 = off[c], s1 = off[c+1];
  const int L = s1 - s0;

  float m = -3.402823466e38f;
  for (int i = lane; i < L; i += 64) m = fmaxf(m, lrelu[s0+i]);
#pragma unroll
  for (int o = 32; o; o >>= 1) m = fmaxf(m, __shfl_xor(m, o));

  float z0 = 0.f, z1 = 0.f;
  if (lane < L)      z0 = expf(lrelu[s0+lane] - m);
  if (lane+64 < L)   z1 = expf(lrelu[s0+lane+64] - m);
  float s = z0 + z1;
  for (int i = lane+128; i < L; i += 64) s += expf(lrelu[s0+i] - m);
#pragma unroll
  for (int o = 32; o; o >>= 1) s += __shfl_xor(s, o);
  const float inv = 1.f / (s + 1e-16f);

  float hv = 0.f;
  if (L <= 128){
    for (int i = 0; i < L; ++i){
      float z = (i < 64) ? __shfl(z0, i) : __shfl(z1, i - 64);
      int r = srow[s0+i];
      hv = fmaf(z * inv, xw[(size_t)r*64 + lane], hv);
    }
  } else {
    for (int i = 0; i < L; ++i){
      float z = expf(lrelu[s0+i] - m);
      int r = srow[s0+i];
      hv = fmaf(z * inv, xw[(size_t)r*64 + lane], hv);
    }
  }
  h[(size_t)c*64 + lane] = hv;
}

// ---------------- BN stats (sum, sumsq per dim)
__global__ __launch_bounds__(256) void bn_stats(
    const float* __restrict__ h, float* __restrict__ musum, float* __restrict__ sqsum)
{
  const int t = threadIdx.x;
  const int d = t & 63, sub = t >> 6;
  const int base = blockIdx.x * 256;
  float s = 0.f, s2 = 0.f;
  for (int i = sub; i < 256; i += 4){
    int n = base + i;
    if (n < NN){ float v = h[(size_t)n*64 + d]; s += v; s2 = fmaf(v, v, s2); }
  }
  __shared__ float r1[4][64], r2[4][64];
  r1[sub][d] = s; r2[sub][d] = s2;
  __syncthreads();
  if (sub == 0){
    s  = r1[0][d] + r1[1][d] + r1[2][d] + r1[3][d];
    s2 = r2[0][d] + r2[1][d] + r2[2][d] + r2[3][d];
    atomicAdd(&musum[d], s);
    atomicAdd(&sqsum[d], s2);
  }
}

// ---------------- x = relu(BN(h))
__global__ __launch_bounds__(256) void bn_apply(
    const float* __restrict__ h, const float* __restrict__ musum,
    const float* __restrict__ sqsum, const float* __restrict__ gamma,
    const float* __restrict__ beta, float* __restrict__ xout, int l)
{
  int idx = blockIdx.x * 256 + threadIdx.x;
  int d = idx & 63;
  float mu = musum[d] * (1.0f / NN);
  float var = sqsum[d] * (1.0f / NN) - mu * mu;
  float inv = rsqrtf(var + 1e-5f);
  float v = (h[idx] - mu) * inv * gamma[l*64 + d] + beta[l*64 + d];
  xout[idx] = fmaxf(v, 0.f);
}

// ---------------- mean pool: one block per graph, contiguous segment
__global__ __launch_bounds__(256) void seg_pool(
    const float* __restrict__ x, const int* __restrict__ goff,
    float* __restrict__ pools, float* __restrict__ pcnt)
{
  const int g = blockIdx.x;
  const int t = threadIdx.x;
  const int d = t & 63, sub = t >> 6;
  const int s0 = goff[g], s1 = goff[g+1];
  float s = 0.f;
  for (int n = s0 + sub; n < s1; n += 4) s += x[(size_t)n*64 + d];
  __shared__ float r[4][64];
  r[sub][d] = s;
  __syncthreads();
  if (sub == 0){
    s = r[0][d] + r[1][d] + r[2][d] + r[3][d];
    pools[g*64 + d] = s;
    if (d == 0) pcnt[g] = (float)(s1 - s0);
  }
}

// ---------------- readout MLP (one block)
__global__ __launch_bounds__(256) void final_mlp(
    const float* __restrict__ pools, const float* __restrict__ pcnt,
    const float* __restrict__ w1, const float* __restrict__ b1,
    const float* __restrict__ w2, const float* __restrict__ b2,
    const float* __restrict__ w3, const float* __restrict__ b3,
    float* __restrict__ out)
{
  __shared__ float g[32*64], h1[32*64], h2[32*32];
  const int t = threadIdx.x;
  for (int i = t; i < 2048; i += 256) g[i] = pools[i] / fmaxf(pcnt[i >> 6], 1.0f);
  __syncthreads();
  for (int i = t; i < 2048; i += 256){
    int gi = i >> 6, d = i & 63;
    float a = b1[d];
    for (int k = 0; k < 64; ++k) a = fmaf(g[gi*64 + k], w1[k*64 + d], a);
    h1[i] = fmaxf(a, 0.f);
  }
  __syncthreads();
  for (int i = t; i < 1024; i += 256){
    int gi = i >> 5, d = i & 31;
    float a = b2[d];
    for (int k = 0; k < 64; ++k) a = fmaf(h1[gi*64 + k], w2[k*32 + d], a);
    h2[i] = fmaxf(a, 0.f);
  }
  __syncthreads();
  if (t < 32){
    float a = b3[0];
    for (int k = 0; k < 32; ++k) a = fmaf(h2[t*32 + k], w3[k], a);
    out[t] = a;
  }
}

extern "C" void kernel_launch(void* const* d_in, const int* in_sizes, int n_in,
                              void* d_out, int out_size, void* d_ws, size_t ws_size,
                              hipStream_t stream)
{
  (void)in_sizes; (void)n_in; (void)out_size; (void)ws_size;
  const float* x0       = (const float*)d_in[0];
  const int*   ei       = (const int*)  d_in[1];
  const float* ea0      = (const float*)d_in[2];
  const int*   batch    = (const int*)  d_in[3];
  const float* em_w1    = (const float*)d_in[4];
  const float* em_b1    = (const float*)d_in[5];
  const float* em_w2    = (const float*)d_in[6];
  const float* em_b2    = (const float*)d_in[7];
  const float* gat_w    = (const float*)d_in[8];
  const float* att_src  = (const float*)d_in[9];
  const float* att_dst  = (const float*)d_in[10];
  const float* edge_w   = (const float*)d_in[11];
  const float* att_edge = (const float*)d_in[12];
  // d_in[13] gat_bias: cancels inside BatchNorm -> unused
  const float* bn_gamma = (const float*)d_in[14];
  const float* bn_beta  = (const float*)d_in[15];
  const float* mlp_w1   = (const float*)d_in[16];
  const float* mlp_b1   = (const float*)d_in[17];
  const float* mlp_w2   = (const float*)d_in[18];
  const float* mlp_b2   = (const float*)d_in[19];
  const float* mlp_w3   = (const float*)d_in[20];
  const float* mlp_b3   = (const float*)d_in[21];
  float* out = (float*)d_out;

  const size_t N64 = (size_t)NN * 64, E64 = (size_t)NE * 64;
  float* ws    = (float*)d_ws;
  float* wsE   = ws;                 // E64 f32 slots; used as bf16 edge_attr (sorted)
  float* xa    = wsE + E64;          // N64  (= x@W1a + b1)
  float* xb    = xa + N64;           // N64
  float* xw    = xb + N64;           // N64
  float* xcur  = xw + N64;           // N64
  float* hbuf  = xcur + N64;         // N64
  float* musum = hbuf + N64;         // 64  -- per-layer memset start
  float* sqsum = musum + 64;         // 64  -- per-layer memset end
  float* lrelu = sqsum + 64;         // NE
  float* pools = lrelu + NE;         // 2048
  float* pcnt  = pools + 2048;       // 32
  float* ssrc  = pcnt + 32;          // NN
  float* sdst  = ssrc + NN;          // NN
  int*   cnt   = (int*)(sdst + NN);  // NN  -- once memset start
  int*   cur   = cnt + NN;           // NN  -- once memset end
  int*   soff  = cur + NN;           // NN+1
  int*   srow  = soff + NN + 1;      // NE
  int*   scol  = srow + NE;          // NE
  int*   perm  = scol + NE;          // NE
  int*   goff  = perm + NE;          // 33 (pad to 40 for alignment)
  __bf16* eaB  = (__bf16*)wsE;
  __bf16* w1f  = (__bf16*)(goff + 40);   // 3*4096 bf16
  __bf16* w2f  = w1f + 3*4096;           // 3*4096 bf16
  float* vbuf  = (float*)(w2f + 3*4096); // 3*64 f32

  // ---- one-time per call: counting sort by col, graph bounds, weight fragments
  hipMemsetAsync(cnt, 0, 2 * NN * sizeof(int), stream);
  hist_kernel<<<NE / 256, 256, 0, stream>>>(ei + NE, cnt);
  scan_kernel<<<1, 256, 0, stream>>>(cnt, soff);
  scatter_kernel<<<NE / 256, 256, 0, stream>>>(ei, soff, cur, srow, scol, perm);
  graph_bounds<<<(NN + 255) / 256, 256, 0, stream>>>(batch, goff);
  prep_weights<<<3, 256, 0, stream>>>(em_w1, em_w2, edge_w, att_edge, w1f, w2f, vbuf);

  for (int l = 0; l < 3; ++l){
    const float* x_in = (l == 0) ? x0 : xcur;

    hipMemsetAsync(musum, 0, 128 * sizeof(float), stream);

    node_prep<<<(NN + 63) / 64, 256, 0, stream>>>(
        x_in, em_w1, em_b1, gat_w, att_src, att_dst, xa, xb, xw, ssrc, sdst, l);

    edge_mlp<<<NE / 128, 256, 0, stream>>>(
        (l == 0) ? ea0 : nullptr, eaB, eaB, xa, xb, ssrc, sdst,
        srow, scol, (l == 0) ? perm : nullptr,
        w1f + (size_t)l*4096, w2f + (size_t)l*4096,
        em_b2 + l*64, vbuf + l*64, lrelu, (l < 2) ? 1 : 0);

    col_agg<<<NN / 4, 256, 0, stream>>>(lrelu, srow, soff, xw, hbuf);

    bn_stats<<<(NN + 255) / 256, 256, 0, stream>>>(hbuf, musum, sqsum);

    bn_apply<<<(int)(N64 / 256), 256, 0, stream>>>(
        hbuf, musum, sqsum, bn_gamma, bn_beta, xcur, l);
  }

  seg_pool<<<32, 256, 0, stream>>>(xcur, goff, pools, pcnt);
  final_mlp<<<1, 256, 0, stream>>>(pools, pcnt, mlp_w1, mlp_b1, mlp_w2, mlp_b2,
                                   mlp_w3, mlp_b3, out);
}

// Round 5
// 1084.232 us; speedup vs baseline: 3.3912x; 1.1373x over previous
//
#include <hip/hip_runtime.h>

// GNN forward: 3 x (edge-MLP -> GAT(softmax over col) -> BN+ReLU) -> mean-pool -> MLP.
// Round-5: edge_mlp gathers restructured. Round-4 was memory-LATENCY bound
// (MfmaUtil 2.5%, VALUBusy 12.6%, HBM 19%): 64 scalar scattered loads/thread.
// Now each wave stages uv[edge][col]=xa[row]+xb[col] into LDS via float4 loads
// (wave-private rows -> no extra barriers), epilogue reads LDS. ea_out stores
// pair-packed to b32. Edge GEMMs stay bf16 MFMA (16x16x32, f32 accum).

#define NN 50000
#define NE 800000
#define DP 68
#define NEG_SLOPE 0.2f

typedef __attribute__((ext_vector_type(8))) __bf16 bf16x8;
typedef __attribute__((ext_vector_type(4))) float f32x4;

__device__ __forceinline__ float4 ld4(const float* __restrict__ p){ return *(const float4* __restrict__)p; }
__device__ __forceinline__ void st4(float* __restrict__ p, float4 v){ *(float4* __restrict__)p = v; }
__device__ __forceinline__ float4 f4zero(){ return make_float4(0.f,0.f,0.f,0.f); }
__device__ __forceinline__ float4 f4add(float4 a, float4 b){
  return make_float4(a.x+b.x, a.y+b.y, a.z+b.z, a.w+b.w);
}
__device__ __forceinline__ float4 f4fma(float a, float4 b, float4 c){
  return make_float4(fmaf(a,b.x,c.x), fmaf(a,b.y,c.y), fmaf(a,b.z,c.z), fmaf(a,b.w,c.w));
}
__device__ __forceinline__ float f4dot(float4 a, float4 b){
  return fmaf(a.x,b.x, fmaf(a.y,b.y, fmaf(a.z,b.z, a.w*b.w)));
}
__device__ __forceinline__ bf16x8 cvt8(float4 a, float4 b){
  bf16x8 r;
  r[0]=(__bf16)a.x; r[1]=(__bf16)a.y; r[2]=(__bf16)a.z; r[3]=(__bf16)a.w;
  r[4]=(__bf16)b.x; r[5]=(__bf16)b.y; r[6]=(__bf16)b.z; r[7]=(__bf16)b.w;
  return r;
}

// 64x64 @ 64x64 f32 block GEMM fragment (node_prep only).
__device__ __forceinline__ void gemm_tile(const float* inT, const float* W,
                                          int el0, int d0, float4 acc[4]){
#pragma unroll 4
  for (int kc = 0; kc < 16; ++kc){
    float4 w0 = ld4(&W[(kc*4+0)*64 + d0]);
    float4 w1 = ld4(&W[(kc*4+1)*64 + d0]);
    float4 w2 = ld4(&W[(kc*4+2)*64 + d0]);
    float4 w3 = ld4(&W[(kc*4+3)*64 + d0]);
#pragma unroll
    for (int i = 0; i < 4; ++i){
      float4 iv = ld4(&inT[(el0+i)*DP + kc*4]);
      acc[i] = f4fma(iv.x, w0, acc[i]);
      acc[i] = f4fma(iv.y, w1, acc[i]);
      acc[i] = f4fma(iv.z, w2, acc[i]);
      acc[i] = f4fma(iv.w, w3, acc[i]);
    }
  }
}

// ---------------- sort: histogram of col
__global__ __launch_bounds__(256) void hist_kernel(const int* __restrict__ ei_col,
                                                   int* __restrict__ cnt){
  int e = blockIdx.x * 256 + threadIdx.x;
  atomicAdd(&cnt[ei_col[e]], 1);
}

// ---------------- sort: exclusive prefix sum over NN bins (single block)
__global__ __launch_bounds__(256) void scan_kernel(const int* __restrict__ cnt,
                                                   int* __restrict__ off){
  __shared__ int wsum[4];
  __shared__ int carry_s;
  const int t = threadIdx.x;
  const int lane = t & 63, w = t >> 6;
  if (t == 0) carry_s = 0;
  __syncthreads();
  for (int base = 0; base < NN; base += 256){
    int idx = base + t;
    int v = (idx < NN) ? cnt[idx] : 0;
    int x = v;
#pragma unroll
    for (int o = 1; o < 64; o <<= 1){
      int u = __shfl_up(x, o);
      if (lane >= o) x += u;
    }
    if (lane == 63) wsum[w] = x;
    __syncthreads();
    int wo = carry_s;
#pragma unroll
    for (int k = 0; k < 4; ++k) if (k < w) wo += wsum[k];
    int incl = x + wo;
    if (idx < NN) off[idx] = incl - v;
    __syncthreads();
    if (t == 255) carry_s = incl;
    __syncthreads();
  }
  if (t == 0) off[NN] = carry_s;
}

// ---------------- sort: scatter into sorted position
__global__ __launch_bounds__(256) void scatter_kernel(
    const int* __restrict__ ei, const int* __restrict__ off, int* __restrict__ cur,
    int* __restrict__ srow, int* __restrict__ scol, int* __restrict__ perm){
  int e = blockIdx.x * 256 + threadIdx.x;
  int r = ei[e], c = ei[NE + e];
  int pos = off[c] + atomicAdd(&cur[c], 1);
  srow[pos] = r; scol[pos] = c; perm[pos] = e;
}

// ---------------- graph segment boundaries from sorted batch
__global__ __launch_bounds__(256) void graph_bounds(const int* __restrict__ batch,
                                                    int* __restrict__ goff){
  int n = blockIdx.x * 256 + threadIdx.x;
  if (n >= NN) return;
  int bn = batch[n];
  int bp = (n == 0) ? -1 : batch[n-1];
  for (int g = bp + 1; g <= bn; ++g) goff[g] = n;
  if (n == NN - 1){ for (int g = bn + 1; g <= 32; ++g) goff[g] = NN; }
}

// ---------------- weights -> bf16 MFMA B-fragment layout + v = edge_w @ att_edge
// Fragment mapping (consistent for A and B everywhere): lane l, elem e, step ks:
//   k = ks*32 + (l>>4)*8 + e, n(col)/m(row) = 16*nt + (l&15); piece = (nt*2+ks)*64 + l.
__global__ __launch_bounds__(256) void prep_weights(
    const float* __restrict__ em_w1, const float* __restrict__ em_w2,
    const float* __restrict__ edge_w, const float* __restrict__ att_edge,
    __bf16* __restrict__ w1f, __bf16* __restrict__ w2f, float* __restrict__ vbuf)
{
  const int l = blockIdx.x, t = threadIdx.x;
  const float* W1 = em_w1 + l*12288 + 8192;   // rows 128..191 of em_w1[l]
  const float* W2 = em_w2 + l*4096;
  for (int p = t; p < 512; p += 256){
    int li = p & 63, ks = (p >> 6) & 1, nt = p >> 7;
    int kbase = ks*32 + (li >> 4)*8;
    int j = nt*16 + (li & 15);
    bf16x8 v1, v2;
#pragma unroll
    for (int e = 0; e < 8; ++e){
      v1[e] = (__bf16)W1[(size_t)(kbase+e)*64 + j];
      v2[e] = (__bf16)W2[(size_t)(kbase+e)*64 + j];
    }
    *(bf16x8*)(w1f + (size_t)l*4096 + p*8) = v1;
    *(bf16x8*)(w2f + (size_t)l*4096 + p*8) = v2;
  }
  if (t < 64){
    float a = 0.f;
    const float* ew = edge_w + l*4096 + t*64;
    const float* ae = att_edge + l*64;
#pragma unroll 8
    for (int j = 0; j < 64; ++j) a = fmaf(ew[j], ae[j], a);
    vbuf[l*64 + t] = a;
  }
}

// ---------------- node prep: xa = x@W1a + b1, xb = x@W1b, xw = x@gat_w, att dots
__global__ __launch_bounds__(256) void node_prep(
    const float* __restrict__ x_in,
    const float* __restrict__ em_w1, const float* __restrict__ em_b1,
    const float* __restrict__ gat_w,
    const float* __restrict__ att_src, const float* __restrict__ att_dst,
    float* __restrict__ xa, float* __restrict__ xb, float* __restrict__ xw,
    float* __restrict__ ssrc, float* __restrict__ sdst, int l)
{
  __shared__ float xt[64*DP];
  __shared__ float Ws[64*64];
  __shared__ float asrc[64], adst[64], b1s[64];
  const int t = threadIdx.x;
  const int n0 = blockIdx.x * 64;

  { int nl = t >> 2, q = t & 3;
    int n = n0 + nl;
    float4 v0, v1, v2, v3;
    if (n < NN){
      const float* src = x_in + (size_t)n*64 + q*16;
      v0 = ld4(src); v1 = ld4(src+4); v2 = ld4(src+8); v3 = ld4(src+12);
    } else { v0 = v1 = v2 = v3 = f4zero(); }
    float* dst = &xt[nl*DP + q*16];
    st4(dst, v0); st4(dst+4, v1); st4(dst+8, v2); st4(dst+12, v3);
  }
  if (t < 64) asrc[t] = att_src[l*64 + t];
  else if (t < 128) adst[t-64] = att_dst[l*64 + (t-64)];
  else if (t < 192) b1s[t-128] = em_b1[l*64 + (t-128)];

  const int nl0 = (t >> 4) << 2;
  const int d0  = (t & 15) << 2;

  for (int p = 0; p < 3; ++p){
    const float* wp = (p == 0) ? (em_w1 + l*12288)
                    : (p == 1) ? (em_w1 + l*12288 + 4096)
                               : (gat_w + l*4096);
    float* op = (p == 0) ? xa : (p == 1) ? xb : xw;
    __syncthreads();
    for (int i = t; i < 1024; i += 256) st4(&Ws[i*4], ld4(wp + i*4));
    __syncthreads();
    float4 acc[4] = {f4zero(), f4zero(), f4zero(), f4zero()};
    gemm_tile(xt, Ws, nl0, d0, acc);
    if (p == 0){
      float4 bb = ld4(&b1s[d0]);
#pragma unroll
      for (int i = 0; i < 4; ++i) acc[i] = f4add(acc[i], bb);
    }
#pragma unroll
    for (int i = 0; i < 4; ++i){
      int n = n0 + nl0 + i;
      if (n < NN) st4(op + (size_t)n*64 + d0, acc[i]);
    }
    if (p == 2){
      float4 a4 = ld4(&asrc[d0]);
      float4 b4 = ld4(&adst[d0]);
      float ps[4], pd[4];
#pragma unroll
      for (int i = 0; i < 4; ++i){ ps[i] = f4dot(acc[i], a4); pd[i] = f4dot(acc[i], b4); }
#pragma unroll
      for (int off = 8; off; off >>= 1){
#pragma unroll
        for (int i = 0; i < 4; ++i){ ps[i] += __shfl_xor(ps[i], off); pd[i] += __shfl_xor(pd[i], off); }
      }
      if ((t & 15) == 0){
#pragma unroll
        for (int i = 0; i < 4; ++i){
          int n = n0 + nl0 + i;
          if (n < NN){ ssrc[n] = ps[i]; sdst[n] = pd[i]; }
        }
      }
    }
  }
}

// ---------------- fused edge MLP (MFMA) + attention logit, 128 edges/block
__global__ __launch_bounds__(256) void edge_mlp(
    const float* __restrict__ ea0,   // layer-0 f32 edge_attr (orig order); null l>0
    const __bf16* ea_in,             // bf16 sorted edge_attr (aliases ea_out)
    __bf16* ea_out,
    const float* __restrict__ xa, const float* __restrict__ xb,
    const float* __restrict__ ssrc, const float* __restrict__ sdst,
    const int* __restrict__ srow, const int* __restrict__ scol,
    const int* __restrict__ permp,
    const __bf16* __restrict__ w1f, const __bf16* __restrict__ w2f,
    const float* __restrict__ b2v, const float* __restrict__ vv,
    float* __restrict__ lrelu, int store_ea)
{
  __shared__ __align__(16) float uv[64*68];      // 17.4 KB: xa[row]+xb[col] (wave-private rows)
  __shared__ __align__(16) unsigned ehw[2048];   // 8 KB: eh in bf16 frag layout (wave-private)
  __shared__ float b2s[64], vs[64], sb[64];      // sb: ssrc[row]+sdst[col] per tile edge
  __shared__ int rs[128], cs[128], ps[128];
  const int t = threadIdx.x;
  const int w = t >> 6, l = t & 63, m = l & 15, kg = l >> 4;
  const int eb = blockIdx.x * 128;

  if (t < 128){ rs[t] = srow[eb+t]; cs[t] = scol[eb+t]; }
  else if (t < 192){ b2s[t-128] = b2v[t-128]; vs[t-128] = vv[t-128]; }
  if (permp && t < 128) ps[t] = permp[eb+t];
  __syncthreads();

  const bf16x8* B1 = (const bf16x8*)w1f;
  const bf16x8* B2 = (const bf16x8*)w2f;
  const f32x4 z4 = {0.f, 0.f, 0.f, 0.f};

  for (int tile = 0; tile < 2; ++tile){
    const int tb = tile * 64;
    // ---- stage uv[edge][col] = xa[row]+xb[col] and sb[edge] (wave-private rows:
    //      thread t stages edge t>>2 in [16w,16w+16) = exactly what wave w consumes)
    { const int e_loc = t >> 2, q = t & 3;
      const int row = rs[tb + e_loc], cn = cs[tb + e_loc];
      const float* pa = xa + (size_t)row*64 + q*16;
      const float* pb = xb + (size_t)cn*64 + q*16;
      float* du = &uv[e_loc*68 + q*16];
#pragma unroll
      for (int i = 0; i < 4; ++i)
        st4(du + i*4, f4add(ld4(pa + i*4), ld4(pb + i*4)));
      if (q == 0) sb[e_loc] = ssrc[row] + sdst[cn];
    }
    // ---- A fragments (GEMM1): edge row = 16w + m, k = ks*32 + kg*8 + e
    bf16x8 a0, a1;
    { const int elA = tb + 16*w + m;
      if (ea0){
        const float* s = ea0 + (size_t)ps[elA]*64 + kg*8;
        a0 = cvt8(ld4(s),    ld4(s+4));
        a1 = cvt8(ld4(s+32), ld4(s+36));
      } else {
        const __bf16* s = ea_in + (size_t)(eb+elA)*64 + kg*8;
        a0 = *(const bf16x8*)s;
        a1 = *(const bf16x8*)(s+32);
      }
    }
    // ---- GEMM1: acc[nt] = ea @ W1c (f32)
    f32x4 acc[4];
#pragma unroll
    for (int nt = 0; nt < 4; ++nt){
      acc[nt] = __builtin_amdgcn_mfma_f32_16x16x32_bf16(a0, B1[(nt*2+0)*64 + l], z4, 0, 0, 0);
      acc[nt] = __builtin_amdgcn_mfma_f32_16x16x32_bf16(a1, B1[(nt*2+1)*64 + l], acc[nt], 0, 0, 0);
    }
    asm volatile("" ::: "memory");   // uv/sb writes ordered before LDS reads (same wave)
    // ---- epilogue1: + uv (from LDS), relu, -> eh frag LDS (bf16, paired)
#pragma unroll
    for (int nt = 0; nt < 4; ++nt){
      const int j = nt*16 + m;
#pragma unroll
      for (int r = 0; r < 4; ++r){
        const int erow = 16*w + 4*kg + r;    // C-layout edge within tile
        float v = acc[nt][r] + uv[erow*68 + j];
        v = fmaxf(v, 0.f);
        unsigned short hu = __builtin_bit_cast(unsigned short, (__bf16)v);
        int pu = __shfl_xor((int)hu, 1);
        if (!(m & 1)){
          unsigned word = (unsigned)hu | ((unsigned)(pu & 0xffff) << 16);
          int piece = (w*2 + (nt>>1))*64 + (((nt&1)<<1) | (m>>3))*16 + 4*kg + r;
          ehw[piece*4 + ((m&7)>>1)] = word;
        }
      }
    }
    asm volatile("" ::: "memory");   // order eh writes before cross-lane reads (same wave)
    // ---- A2 fragments from eh frag LDS
    bf16x8 a20 = *(const bf16x8*)((const __bf16*)ehw + (size_t)((w*2+0)*64 + kg*16 + m)*8);
    bf16x8 a21 = *(const bf16x8*)((const __bf16*)ehw + (size_t)((w*2+1)*64 + kg*16 + m)*8);
    // ---- GEMM2: acc2[nt] = eh @ W2
    f32x4 acc2[4];
#pragma unroll
    for (int nt = 0; nt < 4; ++nt){
      acc2[nt] = __builtin_amdgcn_mfma_f32_16x16x32_bf16(a20, B2[(nt*2+0)*64 + l], z4, 0, 0, 0);
      acc2[nt] = __builtin_amdgcn_mfma_f32_16x16x32_bf16(a21, B2[(nt*2+1)*64 + l], acc2[nt], 0, 0, 0);
    }
    // ---- epilogue2: + b2, store bf16 ea_out (pair-packed b32), logit partials
    float p0 = 0.f, p1 = 0.f, p2 = 0.f, p3 = 0.f;
#pragma unroll
    for (int nt = 0; nt < 4; ++nt){
      const int j = nt*16 + m;
      const float bj = b2s[j], vj = vs[j];
      float vr[4];
      vr[0] = acc2[nt][0] + bj; vr[1] = acc2[nt][1] + bj;
      vr[2] = acc2[nt][2] + bj; vr[3] = acc2[nt][3] + bj;
      if (store_ea){
        const size_t rowb = (size_t)(eb + tb + 16*w + 4*kg)*64 + (j & ~1);
#pragma unroll
        for (int r = 0; r < 4; ++r){
          unsigned short hu = __builtin_bit_cast(unsigned short, (__bf16)vr[r]);
          int pu = __shfl_xor((int)hu, 1);
          if (!(m & 1)){
            unsigned word = (unsigned)hu | ((unsigned)(pu & 0xffff) << 16);
            *(unsigned*)(ea_out + rowb + (size_t)r*64) = word;
          }
        }
      }
      p0 = fmaf(vr[0], vj, p0); p1 = fmaf(vr[1], vj, p1);
      p2 = fmaf(vr[2], vj, p2); p3 = fmaf(vr[3], vj, p3);
    }
#pragma unroll
    for (int o = 8; o; o >>= 1){
      p0 += __shfl_xor(p0, o); p1 += __shfl_xor(p1, o);
      p2 += __shfl_xor(p2, o); p3 += __shfl_xor(p3, o);
    }
    if (m == 0){
      float pv[4] = {p0, p1, p2, p3};
#pragma unroll
      for (int r = 0; r < 4; ++r){
        const int erow = 16*w + 4*kg + r;
        float logit = sb[erow] + pv[r];
        lrelu[eb + tb + erow] = logit > 0.f ? logit : NEG_SLOPE * logit;
      }
    }
    asm volatile("" ::: "memory");   // keep next tile's stage writes after this tile's reads
  }
}

// ---------------- segment softmax + aggregation, atomic-free: one wave per col
__global__ __launch_bounds__(256) void col_agg(
    const float* __restrict__ lrelu, const int* __restrict__ srow,
    const int* __restrict__ off, const float* __restrict__ xw,
    float* __restrict__ h)
{
  const int t = threadIdx.x;
  const int lane = t & 63;
  const int c = blockIdx.x * 4 + (t >> 6);
  const int s0 = off[c], s1 = off[c+1];
  const int L = s1 - s0;

  float m = -3.402823466e38f;
  for (int i = lane; i < L; i += 64) m = fmaxf(m, lrelu[s0+i]);
#pragma unroll
  for (int o = 32; o; o >>= 1) m = fmaxf(m, __shfl_xor(m, o));

  float z0 = 0.f, z1 = 0.f;
  if (lane < L)      z0 = expf(lrelu[s0+lane] - m);
  if (lane+64 < L)   z1 = expf(lrelu[s0+lane+64] - m);
  float s = z0 + z1;
  for (int i = lane+128; i < L; i += 64) s += expf(lrelu[s0+i] - m);
#pragma unroll
  for (int o = 32; o; o >>= 1) s += __shfl_xor(s, o);
  const float inv = 1.f / (s + 1e-16f);

  float hv = 0.f;
  if (L <= 128){
    for (int i = 0; i < L; ++i){
      float z = (i < 64) ? __shfl(z0, i) : __shfl(z1, i - 64);
      int r = srow[s0+i];
      hv = fmaf(z * inv, xw[(size_t)r*64 + lane], hv);
    }
  } else {
    for (int i = 0; i < L; ++i){
      float z = expf(lrelu[s0+i] - m);
      int r = srow[s0+i];
      hv = fmaf(z * inv, xw[(size_t)r*64 + lane], hv);
    }
  }
  h[(size_t)c*64 + lane] = hv;
}

// ---------------- BN stats (sum, sumsq per dim)
__global__ __launch_bounds__(256) void bn_stats(
    const float* __restrict__ h, float* __restrict__ musum, float* __restrict__ sqsum)
{
  const int t = threadIdx.x;
  const int d = t & 63, sub = t >> 6;
  const int base = blockIdx.x * 256;
  float s = 0.f, s2 = 0.f;
  for (int i = sub; i < 256; i += 4){
    int n = base + i;
    if (n < NN){ float v = h[(size_t)n*64 + d]; s += v; s2 = fmaf(v, v, s2); }
  }
  __shared__ float r1[4][64], r2[4][64];
  r1[sub][d] = s; r2[sub][d] = s2;
  __syncthreads();
  if (sub == 0){
    s  = r1[0][d] + r1[1][d] + r1[2][d] + r1[3][d];
    s2 = r2[0][d] + r2[1][d] + r2[2][d] + r2[3][d];
    atomicAdd(&musum[d], s);
    atomicAdd(&sqsum[d], s2);
  }
}

// ---------------- x = relu(BN(h))
__global__ __launch_bounds__(256) void bn_apply(
    const float* __restrict__ h, const float* __restrict__ musum,
    const float* __restrict__ sqsum, const float* __restrict__ gamma,
    const float* __restrict__ beta, float* __restrict__ xout, int l)
{
  int idx = blockIdx.x * 256 + threadIdx.x;
  int d = idx & 63;
  float mu = musum[d] * (1.0f / NN);
  float var = sqsum[d] * (1.0f / NN) - mu * mu;
  float inv = rsqrtf(var + 1e-5f);
  float v = (h[idx] - mu) * inv * gamma[l*64 + d] + beta[l*64 + d];
  xout[idx] = fmaxf(v, 0.f);
}

// ---------------- mean pool: one block per graph, contiguous segment
__global__ __launch_bounds__(256) void seg_pool(
    const float* __restrict__ x, const int* __restrict__ goff,
    float* __restrict__ pools, float* __restrict__ pcnt)
{
  const int g = blockIdx.x;
  const int t = threadIdx.x;
  const int d = t & 63, sub = t >> 6;
  const int s0 = goff[g], s1 = goff[g+1];
  float s = 0.f;
  for (int n = s0 + sub; n < s1; n += 4) s += x[(size_t)n*64 + d];
  __shared__ float r[4][64];
  r[sub][d] = s;
  __syncthreads();
  if (sub == 0){
    s = r[0][d] + r[1][d] + r[2][d] + r[3][d];
    pools[g*64 + d] = s;
    if (d == 0) pcnt[g] = (float)(s1 - s0);
  }
}

// ---------------- readout MLP (one block)
__global__ __launch_bounds__(256) void final_mlp(
    const float* __restrict__ pools, const float* __restrict__ pcnt,
    const float* __restrict__ w1, const float* __restrict__ b1,
    const float* __restrict__ w2, const float* __restrict__ b2,
    const float* __restrict__ w3, const float* __restrict__ b3,
    float* __restrict__ out)
{
  __shared__ float g[32*64], h1[32*64], h2[32*32];
  const int t = threadIdx.x;
  for (int i = t; i < 2048; i += 256) g[i] = pools[i] / fmaxf(pcnt[i >> 6], 1.0f);
  __syncthreads();
  for (int i = t; i < 2048; i += 256){
    int gi = i >> 6, d = i & 63;
    float a = b1[d];
    for (int k = 0; k < 64; ++k) a = fmaf(g[gi*64 + k], w1[k*64 + d], a);
    h1[i] = fmaxf(a, 0.f);
  }
  __syncthreads();
  for (int i = t; i < 1024; i += 256){
    int gi = i >> 5, d = i & 31;
    float a = b2[d];
    for (int k = 0; k < 64; ++k) a = fmaf(h1[gi*64 + k], w2[k*32 + d], a);
    h2[i] = fmaxf(a, 0.f);
  }
  __syncthreads();
  if (t < 32){
    float a = b3[0];
    for (int k = 0; k < 32; ++k) a = fmaf(h2[t*32 + k], w3[k], a);
    out[t] = a;
  }
}

extern "C" void kernel_launch(void* const* d_in, const int* in_sizes, int n_in,
                              void* d_out, int out_size, void* d_ws, size_t ws_size,
                              hipStream_t stream)
{
  (void)in_sizes; (void)n_in; (void)out_size; (void)ws_size;
  const float* x0       = (const float*)d_in[0];
  const int*   ei       = (const int*)  d_in[1];
  const float* ea0      = (const float*)d_in[2];
  const int*   batch    = (const int*)  d_in[3];
  const float* em_w1    = (const float*)d_in[4];
  const float* em_b1    = (const float*)d_in[5];
  const float* em_w2    = (const float*)d_in[6];
  const float* em_b2    = (const float*)d_in[7];
  const float* gat_w    = (const float*)d_in[8];
  const float* att_src  = (const float*)d_in[9];
  const float* att_dst  = (const float*)d_in[10];
  const float* edge_w   = (const float*)d_in[11];
  const float* att_edge = (const float*)d_in[12];
  // d_in[13] gat_bias: cancels inside BatchNorm -> unused
  const float* bn_gamma = (const float*)d_in[14];
  const float* bn_beta  = (const float*)d_in[15];
  const float* mlp_w1   = (const float*)d_in[16];
  const float* mlp_b1   = (const float*)d_in[17];
  const float* mlp_w2   = (const float*)d_in[18];
  const float* mlp_b2   = (const float*)d_in[19];
  const float* mlp_w3   = (const float*)d_in[20];
  const float* mlp_b3   = (const float*)d_in[21];
  float* out = (float*)d_out;

  const size_t N64 = (size_t)NN * 64, E64 = (size_t)NE * 64;
  float* ws    = (float*)d_ws;
  float* wsE   = ws;                 // E64 f32 slots; used as bf16 edge_attr (sorted)
  float* xa    = wsE + E64;          // N64  (= x@W1a + b1)
  float* xb    = xa + N64;           // N64
  float* xw    = xb + N64;           // N64
  float* xcur  = xw + N64;           // N64
  float* hbuf  = xcur + N64;         // N64
  float* musum = hbuf + N64;         // 64  -- per-layer memset start
  float* sqsum = musum + 64;         // 64  -- per-layer memset end
  float* lrelu = sqsum + 64;         // NE
  float* pools = lrelu + NE;         // 2048
  float* pcnt  = pools + 2048;       // 32
  float* ssrc  = pcnt + 32;          // NN
  float* sdst  = ssrc + NN;          // NN
  int*   cnt   = (int*)(sdst + NN);  // NN  -- once memset start
  int*   cur   = cnt + NN;           // NN  -- once memset end
  int*   soff  = cur + NN;           // NN+1
  int*   srow  = soff + NN + 1;      // NE
  int*   scol  = srow + NE;          // NE
  int*   perm  = scol + NE;          // NE
  int*   goff  = perm + NE;          // 33 (pad to 40 for alignment)
  __bf16* eaB  = (__bf16*)wsE;
  __bf16* w1f  = (__bf16*)(goff + 40);   // 3*4096 bf16
  __bf16* w2f  = w1f + 3*4096;           // 3*4096 bf16
  float* vbuf  = (float*)(w2f + 3*4096); // 3*64 f32

  // ---- one-time per call: counting sort by col, graph bounds, weight fragments
  hipMemsetAsync(cnt, 0, 2 * NN * sizeof(int), stream);
  hist_kernel<<<NE / 256, 256, 0, stream>>>(ei + NE, cnt);
  scan_kernel<<<1, 256, 0, stream>>>(cnt, soff);
  scatter_kernel<<<NE / 256, 256, 0, stream>>>(ei, soff, cur, srow, scol, perm);
  graph_bounds<<<(NN + 255) / 256, 256, 0, stream>>>(batch, goff);
  prep_weights<<<3, 256, 0, stream>>>(em_w1, em_w2, edge_w, att_edge, w1f, w2f, vbuf);

  for (int l = 0; l < 3; ++l){
    const float* x_in = (l == 0) ? x0 : xcur;

    hipMemsetAsync(musum, 0, 128 * sizeof(float), stream);

    node_prep<<<(NN + 63) / 64, 256, 0, stream>>>(
        x_in, em_w1, em_b1, gat_w, att_src, att_dst, xa, xb, xw, ssrc, sdst, l);

    edge_mlp<<<NE / 128, 256, 0, stream>>>(
        (l == 0) ? ea0 : nullptr, eaB, eaB, xa, xb, ssrc, sdst,
        srow, scol, (l == 0) ? perm : nullptr,
        w1f + (size_t)l*4096, w2f + (size_t)l*4096,
        em_b2 + l*64, vbuf + l*64, lrelu, (l < 2) ? 1 : 0);

    col_agg<<<NN / 4, 256, 0, stream>>>(lrelu, srow, soff, xw, hbuf);

    bn_stats<<<(NN + 255) / 256, 256, 0, stream>>>(hbuf, musum, sqsum);

    bn_apply<<<(int)(N64 / 256), 256, 0, stream>>>(
        hbuf, musum, sqsum, bn_gamma, bn_beta, xcur, l);
  }

  seg_pool<<<32, 256, 0, stream>>>(xcur, goff, pools, pcnt);
  final_mlp<<<1, 256, 0, stream>>>(pools, pcnt, mlp_w1, mlp_b1, mlp_w2, mlp_b2,
                                   mlp_w3, mlp_b3, out);
}

// Round 6
// 1055.795 us; speedup vs baseline: 3.4825x; 1.0269x over previous
//
#include <hip/hip_runtime.h>

// GNN forward: 3 x (edge-MLP -> GAT(softmax over col) -> BN+ReLU) -> mean-pool -> MLP.
// Round-6: gather tables xa/xb/xw stored BF16 (halves the scattered row-gather
// traffic that dominates edge_mlp AND col_agg; 6.4MB tables L2-cache far better).
// uv staged in LDS as bf16 stride-72 (16B-aligned rows) -> LDS 28->20KB, occupancy up.
// Edge GEMMs bf16 MFMA (16x16x32, f32 accum); node-side GEMMs + softmax stay f32.

#define NN 50000
#define NE 800000
#define DP 68
#define NEG_SLOPE 0.2f

typedef __attribute__((ext_vector_type(8))) __bf16 bf16x8;
typedef __attribute__((ext_vector_type(4))) float f32x4;

__device__ __forceinline__ float4 ld4(const float* __restrict__ p){ return *(const float4* __restrict__)p; }
__device__ __forceinline__ void st4(float* __restrict__ p, float4 v){ *(float4* __restrict__)p = v; }
__device__ __forceinline__ float4 f4zero(){ return make_float4(0.f,0.f,0.f,0.f); }
__device__ __forceinline__ float4 f4add(float4 a, float4 b){
  return make_float4(a.x+b.x, a.y+b.y, a.z+b.z, a.w+b.w);
}
__device__ __forceinline__ float4 f4fma(float a, float4 b, float4 c){
  return make_float4(fmaf(a,b.x,c.x), fmaf(a,b.y,c.y), fmaf(a,b.z,c.z), fmaf(a,b.w,c.w));
}
__device__ __forceinline__ float f4dot(float4 a, float4 b){
  return fmaf(a.x,b.x, fmaf(a.y,b.y, fmaf(a.z,b.z, a.w*b.w)));
}
__device__ __forceinline__ bf16x8 cvt8(float4 a, float4 b){
  bf16x8 r;
  r[0]=(__bf16)a.x; r[1]=(__bf16)a.y; r[2]=(__bf16)a.z; r[3]=(__bf16)a.w;
  r[4]=(__bf16)b.x; r[5]=(__bf16)b.y; r[6]=(__bf16)b.z; r[7]=(__bf16)b.w;
  return r;
}
__device__ __forceinline__ bf16x8 addpack8(bf16x8 a, bf16x8 b){
  bf16x8 r;
#pragma unroll
  for (int e = 0; e < 8; ++e) r[e] = (__bf16)((float)a[e] + (float)b[e]);
  return r;
}
__device__ __forceinline__ ushort4 pack4(float4 v){
  ushort4 u;
  u.x = __builtin_bit_cast(unsigned short, (__bf16)v.x);
  u.y = __builtin_bit_cast(unsigned short, (__bf16)v.y);
  u.z = __builtin_bit_cast(unsigned short, (__bf16)v.z);
  u.w = __builtin_bit_cast(unsigned short, (__bf16)v.w);
  return u;
}

// 64x64 @ 64x64 f32 block GEMM fragment (node_prep only).
__device__ __forceinline__ void gemm_tile(const float* inT, const float* W,
                                          int el0, int d0, float4 acc[4]){
#pragma unroll 4
  for (int kc = 0; kc < 16; ++kc){
    float4 w0 = ld4(&W[(kc*4+0)*64 + d0]);
    float4 w1 = ld4(&W[(kc*4+1)*64 + d0]);
    float4 w2 = ld4(&W[(kc*4+2)*64 + d0]);
    float4 w3 = ld4(&W[(kc*4+3)*64 + d0]);
#pragma unroll
    for (int i = 0; i < 4; ++i){
      float4 iv = ld4(&inT[(el0+i)*DP + kc*4]);
      acc[i] = f4fma(iv.x, w0, acc[i]);
      acc[i] = f4fma(iv.y, w1, acc[i]);
      acc[i] = f4fma(iv.z, w2, acc[i]);
      acc[i] = f4fma(iv.w, w3, acc[i]);
    }
  }
}

// ---------------- sort: histogram of col
__global__ __launch_bounds__(256) void hist_kernel(const int* __restrict__ ei_col,
                                                   int* __restrict__ cnt){
  int e = blockIdx.x * 256 + threadIdx.x;
  atomicAdd(&cnt[ei_col[e]], 1);
}

// ---------------- sort: exclusive prefix sum over NN bins (single block)
__global__ __launch_bounds__(256) void scan_kernel(const int* __restrict__ cnt,
                                                   int* __restrict__ off){
  __shared__ int wsum[4];
  __shared__ int carry_s;
  const int t = threadIdx.x;
  const int lane = t & 63, w = t >> 6;
  if (t == 0) carry_s = 0;
  __syncthreads();
  for (int base = 0; base < NN; base += 256){
    int idx = base + t;
    int v = (idx < NN) ? cnt[idx] : 0;
    int x = v;
#pragma unroll
    for (int o = 1; o < 64; o <<= 1){
      int u = __shfl_up(x, o);
      if (lane >= o) x += u;
    }
    if (lane == 63) wsum[w] = x;
    __syncthreads();
    int wo = carry_s;
#pragma unroll
    for (int k = 0; k < 4; ++k) if (k < w) wo += wsum[k];
    int incl = x + wo;
    if (idx < NN) off[idx] = incl - v;
    __syncthreads();
    if (t == 255) carry_s = incl;
    __syncthreads();
  }
  if (t == 0) off[NN] = carry_s;
}

// ---------------- sort: scatter into sorted position
__global__ __launch_bounds__(256) void scatter_kernel(
    const int* __restrict__ ei, const int* __restrict__ off, int* __restrict__ cur,
    int* __restrict__ srow, int* __restrict__ scol, int* __restrict__ perm){
  int e = blockIdx.x * 256 + threadIdx.x;
  int r = ei[e], c = ei[NE + e];
  int pos = off[c] + atomicAdd(&cur[c], 1);
  srow[pos] = r; scol[pos] = c; perm[pos] = e;
}

// ---------------- graph segment boundaries from sorted batch
__global__ __launch_bounds__(256) void graph_bounds(const int* __restrict__ batch,
                                                    int* __restrict__ goff){
  int n = blockIdx.x * 256 + threadIdx.x;
  if (n >= NN) return;
  int bn = batch[n];
  int bp = (n == 0) ? -1 : batch[n-1];
  for (int g = bp + 1; g <= bn; ++g) goff[g] = n;
  if (n == NN - 1){ for (int g = bn + 1; g <= 32; ++g) goff[g] = NN; }
}

// ---------------- weights -> bf16 MFMA B-fragment layout + v = edge_w @ att_edge
// Fragment mapping (consistent for A and B everywhere): lane l, elem e, step ks:
//   k = ks*32 + (l>>4)*8 + e, n(col)/m(row) = 16*nt + (l&15); piece = (nt*2+ks)*64 + l.
__global__ __launch_bounds__(256) void prep_weights(
    const float* __restrict__ em_w1, const float* __restrict__ em_w2,
    const float* __restrict__ edge_w, const float* __restrict__ att_edge,
    __bf16* __restrict__ w1f, __bf16* __restrict__ w2f, float* __restrict__ vbuf)
{
  const int l = blockIdx.x, t = threadIdx.x;
  const float* W1 = em_w1 + l*12288 + 8192;   // rows 128..191 of em_w1[l]
  const float* W2 = em_w2 + l*4096;
  for (int p = t; p < 512; p += 256){
    int li = p & 63, ks = (p >> 6) & 1, nt = p >> 7;
    int kbase = ks*32 + (li >> 4)*8;
    int j = nt*16 + (li & 15);
    bf16x8 v1, v2;
#pragma unroll
    for (int e = 0; e < 8; ++e){
      v1[e] = (__bf16)W1[(size_t)(kbase+e)*64 + j];
      v2[e] = (__bf16)W2[(size_t)(kbase+e)*64 + j];
    }
    *(bf16x8*)(w1f + (size_t)l*4096 + p*8) = v1;
    *(bf16x8*)(w2f + (size_t)l*4096 + p*8) = v2;
  }
  if (t < 64){
    float a = 0.f;
    const float* ew = edge_w + l*4096 + t*64;
    const float* ae = att_edge + l*64;
#pragma unroll 8
    for (int j = 0; j < 64; ++j) a = fmaf(ew[j], ae[j], a);
    vbuf[l*64 + t] = a;
  }
}

// ---------------- node prep: xaH = bf16(x@W1a + b1), xbH, xwH, att dots (f32)
__global__ __launch_bounds__(256) void node_prep(
    const float* __restrict__ x_in,
    const float* __restrict__ em_w1, const float* __restrict__ em_b1,
    const float* __restrict__ gat_w,
    const float* __restrict__ att_src, const float* __restrict__ att_dst,
    __bf16* __restrict__ xaH, __bf16* __restrict__ xbH, __bf16* __restrict__ xwH,
    float* __restrict__ ssrc, float* __restrict__ sdst, int l)
{
  __shared__ float xt[64*DP];
  __shared__ float Ws[64*64];
  __shared__ float asrc[64], adst[64], b1s[64];
  const int t = threadIdx.x;
  const int n0 = blockIdx.x * 64;

  { int nl = t >> 2, q = t & 3;
    int n = n0 + nl;
    float4 v0, v1, v2, v3;
    if (n < NN){
      const float* src = x_in + (size_t)n*64 + q*16;
      v0 = ld4(src); v1 = ld4(src+4); v2 = ld4(src+8); v3 = ld4(src+12);
    } else { v0 = v1 = v2 = v3 = f4zero(); }
    float* dst = &xt[nl*DP + q*16];
    st4(dst, v0); st4(dst+4, v1); st4(dst+8, v2); st4(dst+12, v3);
  }
  if (t < 64) asrc[t] = att_src[l*64 + t];
  else if (t < 128) adst[t-64] = att_dst[l*64 + (t-64)];
  else if (t < 192) b1s[t-128] = em_b1[l*64 + (t-128)];

  const int nl0 = (t >> 4) << 2;
  const int d0  = (t & 15) << 2;

  for (int p = 0; p < 3; ++p){
    const float* wp = (p == 0) ? (em_w1 + l*12288)
                    : (p == 1) ? (em_w1 + l*12288 + 4096)
                               : (gat_w + l*4096);
    __bf16* op = (p == 0) ? xaH : (p == 1) ? xbH : xwH;
    __syncthreads();
    for (int i = t; i < 1024; i += 256) st4(&Ws[i*4], ld4(wp + i*4));
    __syncthreads();
    float4 acc[4] = {f4zero(), f4zero(), f4zero(), f4zero()};
    gemm_tile(xt, Ws, nl0, d0, acc);
    if (p == 0){
      float4 bb = ld4(&b1s[d0]);
#pragma unroll
      for (int i = 0; i < 4; ++i) acc[i] = f4add(acc[i], bb);
    }
#pragma unroll
    for (int i = 0; i < 4; ++i){
      int n = n0 + nl0 + i;
      if (n < NN) *(ushort4*)(op + (size_t)n*64 + d0) = pack4(acc[i]);
    }
    if (p == 2){
      float4 a4 = ld4(&asrc[d0]);
      float4 b4 = ld4(&adst[d0]);
      float ps[4], pd[4];
#pragma unroll
      for (int i = 0; i < 4; ++i){ ps[i] = f4dot(acc[i], a4); pd[i] = f4dot(acc[i], b4); }
#pragma unroll
      for (int off = 8; off; off >>= 1){
#pragma unroll
        for (int i = 0; i < 4; ++i){ ps[i] += __shfl_xor(ps[i], off); pd[i] += __shfl_xor(pd[i], off); }
      }
      if ((t & 15) == 0){
#pragma unroll
        for (int i = 0; i < 4; ++i){
          int n = n0 + nl0 + i;
          if (n < NN){ ssrc[n] = ps[i]; sdst[n] = pd[i]; }
        }
      }
    }
  }
}

// ---------------- fused edge MLP (MFMA) + attention logit, 128 edges/block
__global__ __launch_bounds__(256) void edge_mlp(
    const float* __restrict__ ea0,   // layer-0 f32 edge_attr (orig order); null l>0
    const __bf16* ea_in,             // bf16 sorted edge_attr (aliases ea_out)
    __bf16* ea_out,
    const __bf16* __restrict__ xaH, const __bf16* __restrict__ xbH,
    const float* __restrict__ ssrc, const float* __restrict__ sdst,
    const int* __restrict__ srow, const int* __restrict__ scol,
    const int* __restrict__ permp,
    const __bf16* __restrict__ w1f, const __bf16* __restrict__ w2f,
    const float* __restrict__ b2v, const float* __restrict__ vv,
    float* __restrict__ lrelu, int store_ea)
{
  __shared__ __align__(16) __bf16 uvh[64*72];    // 9 KB: bf16(xa[row]+xb[col]), wave-private
  __shared__ __align__(16) unsigned ehw[2048];   // 8 KB: eh in bf16 frag layout (wave-private)
  __shared__ float b2s[64], vs[64], sb[64];      // sb: ssrc[row]+sdst[col] per tile edge
  __shared__ int rs[128], cs[128], ps[128];
  const int t = threadIdx.x;
  const int w = t >> 6, l = t & 63, m = l & 15, kg = l >> 4;
  const int eb = blockIdx.x * 128;

  if (t < 128){ rs[t] = srow[eb+t]; cs[t] = scol[eb+t]; }
  else if (t < 192){ b2s[t-128] = b2v[t-128]; vs[t-128] = vv[t-128]; }
  if (permp && t < 128) ps[t] = permp[eb+t];
  __syncthreads();

  const bf16x8* B1 = (const bf16x8*)w1f;
  const bf16x8* B2 = (const bf16x8*)w2f;
  const f32x4 z4 = {0.f, 0.f, 0.f, 0.f};

  for (int tile = 0; tile < 2; ++tile){
    const int tb = tile * 64;
    // ---- stage uvh[edge][col] = bf16(xa[row]+xb[col]) and sb[edge] (wave-private:
    //      thread t stages edge t>>2 in [16w,16w+16) = exactly what wave w consumes)
    { const int e_loc = t >> 2, q = t & 3;
      const int row = rs[tb + e_loc], cn = cs[tb + e_loc];
      const bf16x8* pa = (const bf16x8*)(xaH + (size_t)row*64 + q*16);
      const bf16x8* pb = (const bf16x8*)(xbH + (size_t)cn*64 + q*16);
      bf16x8 u0 = addpack8(pa[0], pb[0]);
      bf16x8 u1 = addpack8(pa[1], pb[1]);
      *(bf16x8*)&uvh[e_loc*72 + q*16]     = u0;
      *(bf16x8*)&uvh[e_loc*72 + q*16 + 8] = u1;
      if (q == 0) sb[e_loc] = ssrc[row] + sdst[cn];
    }
    // ---- A fragments (GEMM1): edge row = 16w + m, k = ks*32 + kg*8 + e
    bf16x8 a0, a1;
    { const int elA = tb + 16*w + m;
      if (ea0){
        const float* s = ea0 + (size_t)ps[elA]*64 + kg*8;
        a0 = cvt8(ld4(s),    ld4(s+4));
        a1 = cvt8(ld4(s+32), ld4(s+36));
      } else {
        const __bf16* s = ea_in + (size_t)(eb+elA)*64 + kg*8;
        a0 = *(const bf16x8*)s;
        a1 = *(const bf16x8*)(s+32);
      }
    }
    // ---- GEMM1: acc[nt] = ea @ W1c (f32)
    f32x4 acc[4];
#pragma unroll
    for (int nt = 0; nt < 4; ++nt){
      acc[nt] = __builtin_amdgcn_mfma_f32_16x16x32_bf16(a0, B1[(nt*2+0)*64 + l], z4, 0, 0, 0);
      acc[nt] = __builtin_amdgcn_mfma_f32_16x16x32_bf16(a1, B1[(nt*2+1)*64 + l], acc[nt], 0, 0, 0);
    }
    asm volatile("" ::: "memory");   // uvh/sb writes ordered before LDS reads (same wave)
    // ---- epilogue1: + uvh (from LDS), relu, -> eh frag LDS (bf16, paired)
#pragma unroll
    for (int nt = 0; nt < 4; ++nt){
      const int j = nt*16 + m;
#pragma unroll
      for (int r = 0; r < 4; ++r){
        const int erow = 16*w + 4*kg + r;    // C-layout edge within tile
        float v = acc[nt][r] + (float)uvh[erow*72 + j];
        v = fmaxf(v, 0.f);
        unsigned short hu = __builtin_bit_cast(unsigned short, (__bf16)v);
        int pu = __shfl_xor((int)hu, 1);
        if (!(m & 1)){
          unsigned word = (unsigned)hu | ((unsigned)(pu & 0xffff) << 16);
          int piece = (w*2 + (nt>>1))*64 + (((nt&1)<<1) | (m>>3))*16 + 4*kg + r;
          ehw[piece*4 + ((m&7)>>1)] = word;
        }
      }
    }
    asm volatile("" ::: "memory");   // order eh writes before cross-lane reads (same wave)
    // ---- A2 fragments from eh frag LDS
    bf16x8 a20 = *(const bf16x8*)((const __bf16*)ehw + (size_t)((w*2+0)*64 + kg*16 + m)*8);
    bf16x8 a21 = *(const bf16x8*)((const __bf16*)ehw + (size_t)((w*2+1)*64 + kg*16 + m)*8);
    // ---- GEMM2: acc2[nt] = eh @ W2
    f32x4 acc2[4];
#pragma unroll
    for (int nt = 0; nt < 4; ++nt){
      acc2[nt] = __builtin_amdgcn_mfma_f32_16x16x32_bf16(a20, B2[(nt*2+0)*64 + l], z4, 0, 0, 0);
      acc2[nt] = __builtin_amdgcn_mfma_f32_16x16x32_bf16(a21, B2[(nt*2+1)*64 + l], acc2[nt], 0, 0, 0);
    }
    // ---- epilogue2: + b2, store bf16 ea_out (pair-packed b32), logit partials
    float p0 = 0.f, p1 = 0.f, p2 = 0.f, p3 = 0.f;
#pragma unroll
    for (int nt = 0; nt < 4; ++nt){
      const int j = nt*16 + m;
      const float bj = b2s[j], vj = vs[j];
      float vr[4];
      vr[0] = acc2[nt][0] + bj; vr[1] = acc2[nt][1] + bj;
      vr[2] = acc2[nt][2] + bj; vr[3] = acc2[nt][3] + bj;
      if (store_ea){
        const size_t rowb = (size_t)(eb + tb + 16*w + 4*kg)*64 + (j & ~1);
#pragma unroll
        for (int r = 0; r < 4; ++r){
          unsigned short hu = __builtin_bit_cast(unsigned short, (__bf16)vr[r]);
          int pu = __shfl_xor((int)hu, 1);
          if (!(m & 1)){
            unsigned word = (unsigned)hu | ((unsigned)(pu & 0xffff) << 16);
            *(unsigned*)(ea_out + rowb + (size_t)r*64) = word;
          }
        }
      }
      p0 = fmaf(vr[0], vj, p0); p1 = fmaf(vr[1], vj, p1);
      p2 = fmaf(vr[2], vj, p2); p3 = fmaf(vr[3], vj, p3);
    }
#pragma unroll
    for (int o = 8; o; o >>= 1){
      p0 += __shfl_xor(p0, o); p1 += __shfl_xor(p1, o);
      p2 += __shfl_xor(p2, o); p3 += __shfl_xor(p3, o);
    }
    if (m == 0){
      float pv[4] = {p0, p1, p2, p3};
#pragma unroll
      for (int r = 0; r < 4; ++r){
        const int erow = 16*w + 4*kg + r;
        float logit = sb[erow] + pv[r];
        lrelu[eb + tb + erow] = logit > 0.f ? logit : NEG_SLOPE * logit;
      }
    }
    asm volatile("" ::: "memory");   // keep next tile's stage writes after this tile's reads
  }
}

// ---------------- segment softmax + aggregation, atomic-free: one wave per col
__global__ __launch_bounds__(256) void col_agg(
    const float* __restrict__ lrelu, const int* __restrict__ srow,
    const int* __restrict__ off, const __bf16* __restrict__ xwH,
    float* __restrict__ h)
{
  const int t = threadIdx.x;
  const int lane = t & 63;
  const int c = blockIdx.x * 4 + (t >> 6);
  const int s0 = off[c], s1 = off[c+1];
  const int L = s1 - s0;

  float m = -3.402823466e38f;
  for (int i = lane; i < L; i += 64) m = fmaxf(m, lrelu[s0+i]);
#pragma unroll
  for (int o = 32; o; o >>= 1) m = fmaxf(m, __shfl_xor(m, o));

  float z0 = 0.f, z1 = 0.f;
  if (lane < L)      z0 = expf(lrelu[s0+lane] - m);
  if (lane+64 < L)   z1 = expf(lrelu[s0+lane+64] - m);
  float s = z0 + z1;
  for (int i = lane+128; i < L; i += 64) s += expf(lrelu[s0+i] - m);
#pragma unroll
  for (int o = 32; o; o >>= 1) s += __shfl_xor(s, o);
  const float inv = 1.f / (s + 1e-16f);

  float hv = 0.f;
  if (L <= 128){
    for (int i = 0; i < L; ++i){
      float z = (i < 64) ? __shfl(z0, i) : __shfl(z1, i - 64);
      int r = srow[s0+i];
      hv = fmaf(z * inv, (float)xwH[(size_t)r*64 + lane], hv);
    }
  } else {
    for (int i = 0; i < L; ++i){
      float z = expf(lrelu[s0+i] - m);
      int r = srow[s0+i];
      hv = fmaf(z * inv, (float)xwH[(size_t)r*64 + lane], hv);
    }
  }
  h[(size_t)c*64 + lane] = hv;
}

// ---------------- BN stats (sum, sumsq per dim)
__global__ __launch_bounds__(256) void bn_stats(
    const float* __restrict__ h, float* __restrict__ musum, float* __restrict__ sqsum)
{
  const int t = threadIdx.x;
  const int d = t & 63, sub = t >> 6;
  const int base = blockIdx.x * 256;
  float s = 0.f, s2 = 0.f;
  for (int i = sub; i < 256; i += 4){
    int n = base + i;
    if (n < NN){ float v = h[(size_t)n*64 + d]; s += v; s2 = fmaf(v, v, s2); }
  }
  __shared__ float r1[4][64], r2[4][64];
  r1[sub][d] = s; r2[sub][d] = s2;
  __syncthreads();
  if (sub == 0){
    s  = r1[0][d] + r1[1][d] + r1[2][d] + r1[3][d];
    s2 = r2[0][d] + r2[1][d] + r2[2][d] + r2[3][d];
    atomicAdd(&musum[d], s);
    atomicAdd(&sqsum[d], s2);
  }
}

// ---------------- x = relu(BN(h))
__global__ __launch_bounds__(256) void bn_apply(
    const float* __restrict__ h, const float* __restrict__ musum,
    const float* __restrict__ sqsum, const float* __restrict__ gamma,
    const float* __restrict__ beta, float* __restrict__ xout, int l)
{
  int idx = blockIdx.x * 256 + threadIdx.x;
  int d = idx & 63;
  float mu = musum[d] * (1.0f / NN);
  float var = sqsum[d] * (1.0f / NN) - mu * mu;
  float inv = rsqrtf(var + 1e-5f);
  float v = (h[idx] - mu) * inv * gamma[l*64 + d] + beta[l*64 + d];
  xout[idx] = fmaxf(v, 0.f);
}

// ---------------- mean pool: one block per graph, contiguous segment
__global__ __launch_bounds__(256) void seg_pool(
    const float* __restrict__ x, const int* __restrict__ goff,
    float* __restrict__ pools, float* __restrict__ pcnt)
{
  const int g = blockIdx.x;
  const int t = threadIdx.x;
  const int d = t & 63, sub = t >> 6;
  const int s0 = goff[g], s1 = goff[g+1];
  float s = 0.f;
  for (int n = s0 + sub; n < s1; n += 4) s += x[(size_t)n*64 + d];
  __shared__ float r[4][64];
  r[sub][d] = s;
  __syncthreads();
  if (sub == 0){
    s = r[0][d] + r[1][d] + r[2][d] + r[3][d];
    pools[g*64 + d] = s;
    if (d == 0) pcnt[g] = (float)(s1 - s0);
  }
}

// ---------------- readout MLP (one block)
__global__ __launch_bounds__(256) void final_mlp(
    const float* __restrict__ pools, const float* __restrict__ pcnt,
    const float* __restrict__ w1, const float* __restrict__ b1,
    const float* __restrict__ w2, const float* __restrict__ b2,
    const float* __restrict__ w3, const float* __restrict__ b3,
    float* __restrict__ out)
{
  __shared__ float g[32*64], h1[32*64], h2[32*32];
  const int t = threadIdx.x;
  for (int i = t; i < 2048; i += 256) g[i] = pools[i] / fmaxf(pcnt[i >> 6], 1.0f);
  __syncthreads();
  for (int i = t; i < 2048; i += 256){
    int gi = i >> 6, d = i & 63;
    float a = b1[d];
    for (int k = 0; k < 64; ++k) a = fmaf(g[gi*64 + k], w1[k*64 + d], a);
    h1[i] = fmaxf(a, 0.f);
  }
  __syncthreads();
  for (int i = t; i < 1024; i += 256){
    int gi = i >> 5, d = i & 31;
    float a = b2[d];
    for (int k = 0; k < 64; ++k) a = fmaf(h1[gi*64 + k], w2[k*32 + d], a);
    h2[i] = fmaxf(a, 0.f);
  }
  __syncthreads();
  if (t < 32){
    float a = b3[0];
    for (int k = 0; k < 32; ++k) a = fmaf(h2[t*32 + k], w3[k], a);
    out[t] = a;
  }
}

extern "C" void kernel_launch(void* const* d_in, const int* in_sizes, int n_in,
                              void* d_out, int out_size, void* d_ws, size_t ws_size,
                              hipStream_t stream)
{
  (void)in_sizes; (void)n_in; (void)out_size; (void)ws_size;
  const float* x0       = (const float*)d_in[0];
  const int*   ei       = (const int*)  d_in[1];
  const float* ea0      = (const float*)d_in[2];
  const int*   batch    = (const int*)  d_in[3];
  const float* em_w1    = (const float*)d_in[4];
  const float* em_b1    = (const float*)d_in[5];
  const float* em_w2    = (const float*)d_in[6];
  const float* em_b2    = (const float*)d_in[7];
  const float* gat_w    = (const float*)d_in[8];
  const float* att_src  = (const float*)d_in[9];
  const float* att_dst  = (const float*)d_in[10];
  const float* edge_w   = (const float*)d_in[11];
  const float* att_edge = (const float*)d_in[12];
  // d_in[13] gat_bias: cancels inside BatchNorm -> unused
  const float* bn_gamma = (const float*)d_in[14];
  const float* bn_beta  = (const float*)d_in[15];
  const float* mlp_w1   = (const float*)d_in[16];
  const float* mlp_b1   = (const float*)d_in[17];
  const float* mlp_w2   = (const float*)d_in[18];
  const float* mlp_b2   = (const float*)d_in[19];
  const float* mlp_w3   = (const float*)d_in[20];
  const float* mlp_b3   = (const float*)d_in[21];
  float* out = (float*)d_out;

  const size_t N64 = (size_t)NN * 64, E64 = (size_t)NE * 64;
  float* ws    = (float*)d_ws;
  float* wsE   = ws;                 // E64 f32 slots; used as bf16 edge_attr (sorted)
  float* sxa   = wsE + E64;          // N64 f32 slot -> bf16 xaH (= x@W1a + b1)
  float* sxb   = sxa + N64;          // N64 f32 slot -> bf16 xbH
  float* sxw   = sxb + N64;          // N64 f32 slot -> bf16 xwH
  float* xcur  = sxw + N64;          // N64
  float* hbuf  = xcur + N64;         // N64
  float* musum = hbuf + N64;         // 64  -- per-layer memset start
  float* sqsum = musum + 64;         // 64  -- per-layer memset end
  float* lrelu = sqsum + 64;         // NE
  float* pools = lrelu + NE;         // 2048
  float* pcnt  = pools + 2048;       // 32
  float* ssrc  = pcnt + 32;          // NN
  float* sdst  = ssrc + NN;          // NN
  int*   cnt   = (int*)(sdst + NN);  // NN  -- once memset start
  int*   cur   = cnt + NN;           // NN  -- once memset end
  int*   soff  = cur + NN;           // NN+1
  int*   srow  = soff + NN + 1;      // NE
  int*   scol  = srow + NE;          // NE
  int*   perm  = scol + NE;          // NE
  int*   goff  = perm + NE;          // 33 (pad to 40 for alignment)
  __bf16* eaB  = (__bf16*)wsE;
  __bf16* xaH  = (__bf16*)sxa;
  __bf16* xbH  = (__bf16*)sxb;
  __bf16* xwH  = (__bf16*)sxw;
  __bf16* w1f  = (__bf16*)(goff + 40);   // 3*4096 bf16
  __bf16* w2f  = w1f + 3*4096;           // 3*4096 bf16
  float* vbuf  = (float*)(w2f + 3*4096); // 3*64 f32

  // ---- one-time per call: counting sort by col, graph bounds, weight fragments
  hipMemsetAsync(cnt, 0, 2 * NN * sizeof(int), stream);
  hist_kernel<<<NE / 256, 256, 0, stream>>>(ei + NE, cnt);
  scan_kernel<<<1, 256, 0, stream>>>(cnt, soff);
  scatter_kernel<<<NE / 256, 256, 0, stream>>>(ei, soff, cur, srow, scol, perm);
  graph_bounds<<<(NN + 255) / 256, 256, 0, stream>>>(batch, goff);
  prep_weights<<<3, 256, 0, stream>>>(em_w1, em_w2, edge_w, att_edge, w1f, w2f, vbuf);

  for (int l = 0; l < 3; ++l){
    const float* x_in = (l == 0) ? x0 : xcur;

    hipMemsetAsync(musum, 0, 128 * sizeof(float), stream);

    node_prep<<<(NN + 63) / 64, 256, 0, stream>>>(
        x_in, em_w1, em_b1, gat_w, att_src, att_dst, xaH, xbH, xwH, ssrc, sdst, l);

    edge_mlp<<<NE / 128, 256, 0, stream>>>(
        (l == 0) ? ea0 : nullptr, eaB, eaB, xaH, xbH, ssrc, sdst,
        srow, scol, (l == 0) ? perm : nullptr,
        w1f + (size_t)l*4096, w2f + (size_t)l*4096,
        em_b2 + l*64, vbuf + l*64, lrelu, (l < 2) ? 1 : 0);

    col_agg<<<NN / 4, 256, 0, stream>>>(lrelu, srow, soff, xwH, hbuf);

    bn_stats<<<(NN + 255) / 256, 256, 0, stream>>>(hbuf, musum, sqsum);

    bn_apply<<<(int)(N64 / 256), 256, 0, stream>>>(
        hbuf, musum, sqsum, bn_gamma, bn_beta, xcur, l);
  }

  seg_pool<<<32, 256, 0, stream>>>(xcur, goff, pools, pcnt);
  final_mlp<<<1, 256, 0, stream>>>(pools, pcnt, mlp_w1, mlp_b1, mlp_w2, mlp_b2,
                                   mlp_w3, mlp_b3, out);
}

// Round 7
// 990.455 us; speedup vs baseline: 3.7122x; 1.0660x over previous
//
#include <hip/hip_runtime.h>

// GNN forward: 3 x (edge-MLP -> GAT(softmax over col) -> BN+ReLU) -> mean-pool -> MLP.
// Round-7: edge_mlp software-pipelined: ALL global loads (A frags + uv gathers +
// logit scalars, both tiles) issue before the first LDS fence into registers;
// uvh double-buffered; compute phase is VGPR/LDS-only. Epilogue1 uses direct
// scalar ds_write_b16 (no pairing shuffles). node_prep split into 3 parallel
// pass-blocks (grid x 3). Tables bf16; edge GEMMs bf16 MFMA (f32 accum).

#define NN 50000
#define NE 800000
#define DP 68
#define NEG_SLOPE 0.2f

typedef __attribute__((ext_vector_type(8))) __bf16 bf16x8;
typedef __attribute__((ext_vector_type(4))) float f32x4;

__device__ __forceinline__ float4 ld4(const float* __restrict__ p){ return *(const float4* __restrict__)p; }
__device__ __forceinline__ void st4(float* __restrict__ p, float4 v){ *(float4* __restrict__)p = v; }
__device__ __forceinline__ float4 f4zero(){ return make_float4(0.f,0.f,0.f,0.f); }
__device__ __forceinline__ float4 f4add(float4 a, float4 b){
  return make_float4(a.x+b.x, a.y+b.y, a.z+b.z, a.w+b.w);
}
__device__ __forceinline__ float4 f4fma(float a, float4 b, float4 c){
  return make_float4(fmaf(a,b.x,c.x), fmaf(a,b.y,c.y), fmaf(a,b.z,c.z), fmaf(a,b.w,c.w));
}
__device__ __forceinline__ float f4dot(float4 a, float4 b){
  return fmaf(a.x,b.x, fmaf(a.y,b.y, fmaf(a.z,b.z, a.w*b.w)));
}
__device__ __forceinline__ bf16x8 cvt8(float4 a, float4 b){
  bf16x8 r;
  r[0]=(__bf16)a.x; r[1]=(__bf16)a.y; r[2]=(__bf16)a.z; r[3]=(__bf16)a.w;
  r[4]=(__bf16)b.x; r[5]=(__bf16)b.y; r[6]=(__bf16)b.z; r[7]=(__bf16)b.w;
  return r;
}
__device__ __forceinline__ bf16x8 addpack8(bf16x8 a, bf16x8 b){
  bf16x8 r;
#pragma unroll
  for (int e = 0; e < 8; ++e) r[e] = (__bf16)((float)a[e] + (float)b[e]);
  return r;
}
__device__ __forceinline__ ushort4 pack4(float4 v){
  ushort4 u;
  u.x = __builtin_bit_cast(unsigned short, (__bf16)v.x);
  u.y = __builtin_bit_cast(unsigned short, (__bf16)v.y);
  u.z = __builtin_bit_cast(unsigned short, (__bf16)v.z);
  u.w = __builtin_bit_cast(unsigned short, (__bf16)v.w);
  return u;
}

// 64x64 @ 64x64 f32 block GEMM fragment (node_prep only).
__device__ __forceinline__ void gemm_tile(const float* inT, const float* W,
                                          int el0, int d0, float4 acc[4]){
#pragma unroll 4
  for (int kc = 0; kc < 16; ++kc){
    float4 w0 = ld4(&W[(kc*4+0)*64 + d0]);
    float4 w1 = ld4(&W[(kc*4+1)*64 + d0]);
    float4 w2 = ld4(&W[(kc*4+2)*64 + d0]);
    float4 w3 = ld4(&W[(kc*4+3)*64 + d0]);
#pragma unroll
    for (int i = 0; i < 4; ++i){
      float4 iv = ld4(&inT[(el0+i)*DP + kc*4]);
      acc[i] = f4fma(iv.x, w0, acc[i]);
      acc[i] = f4fma(iv.y, w1, acc[i]);
      acc[i] = f4fma(iv.z, w2, acc[i]);
      acc[i] = f4fma(iv.w, w3, acc[i]);
    }
  }
}

// ---------------- sort: histogram of col
__global__ __launch_bounds__(256) void hist_kernel(const int* __restrict__ ei_col,
                                                   int* __restrict__ cnt){
  int e = blockIdx.x * 256 + threadIdx.x;
  atomicAdd(&cnt[ei_col[e]], 1);
}

// ---------------- sort: exclusive prefix sum over NN bins (single block)
__global__ __launch_bounds__(256) void scan_kernel(const int* __restrict__ cnt,
                                                   int* __restrict__ off){
  __shared__ int wsum[4];
  __shared__ int carry_s;
  const int t = threadIdx.x;
  const int lane = t & 63, w = t >> 6;
  if (t == 0) carry_s = 0;
  __syncthreads();
  for (int base = 0; base < NN; base += 256){
    int idx = base + t;
    int v = (idx < NN) ? cnt[idx] : 0;
    int x = v;
#pragma unroll
    for (int o = 1; o < 64; o <<= 1){
      int u = __shfl_up(x, o);
      if (lane >= o) x += u;
    }
    if (lane == 63) wsum[w] = x;
    __syncthreads();
    int wo = carry_s;
#pragma unroll
    for (int k = 0; k < 4; ++k) if (k < w) wo += wsum[k];
    int incl = x + wo;
    if (idx < NN) off[idx] = incl - v;
    __syncthreads();
    if (t == 255) carry_s = incl;
    __syncthreads();
  }
  if (t == 0) off[NN] = carry_s;
}

// ---------------- sort: scatter into sorted position
__global__ __launch_bounds__(256) void scatter_kernel(
    const int* __restrict__ ei, const int* __restrict__ off, int* __restrict__ cur,
    int* __restrict__ srow, int* __restrict__ scol, int* __restrict__ perm){
  int e = blockIdx.x * 256 + threadIdx.x;
  int r = ei[e], c = ei[NE + e];
  int pos = off[c] + atomicAdd(&cur[c], 1);
  srow[pos] = r; scol[pos] = c; perm[pos] = e;
}

// ---------------- graph segment boundaries from sorted batch
__global__ __launch_bounds__(256) void graph_bounds(const int* __restrict__ batch,
                                                    int* __restrict__ goff){
  int n = blockIdx.x * 256 + threadIdx.x;
  if (n >= NN) return;
  int bn = batch[n];
  int bp = (n == 0) ? -1 : batch[n-1];
  for (int g = bp + 1; g <= bn; ++g) goff[g] = n;
  if (n == NN - 1){ for (int g = bn + 1; g <= 32; ++g) goff[g] = NN; }
}

// ---------------- weights -> bf16 MFMA B-fragment layout + v = edge_w @ att_edge
__global__ __launch_bounds__(256) void prep_weights(
    const float* __restrict__ em_w1, const float* __restrict__ em_w2,
    const float* __restrict__ edge_w, const float* __restrict__ att_edge,
    __bf16* __restrict__ w1f, __bf16* __restrict__ w2f, float* __restrict__ vbuf)
{
  const int l = blockIdx.x, t = threadIdx.x;
  const float* W1 = em_w1 + l*12288 + 8192;   // rows 128..191 of em_w1[l]
  const float* W2 = em_w2 + l*4096;
  for (int p = t; p < 512; p += 256){
    int li = p & 63, ks = (p >> 6) & 1, nt = p >> 7;
    int kbase = ks*32 + (li >> 4)*8;
    int j = nt*16 + (li & 15);
    bf16x8 v1, v2;
#pragma unroll
    for (int e = 0; e < 8; ++e){
      v1[e] = (__bf16)W1[(size_t)(kbase+e)*64 + j];
      v2[e] = (__bf16)W2[(size_t)(kbase+e)*64 + j];
    }
    *(bf16x8*)(w1f + (size_t)l*4096 + p*8) = v1;
    *(bf16x8*)(w2f + (size_t)l*4096 + p*8) = v2;
  }
  if (t < 64){
    float a = 0.f;
    const float* ew = edge_w + l*4096 + t*64;
    const float* ae = att_edge + l*64;
#pragma unroll 8
    for (int j = 0; j < 64; ++j) a = fmaf(ew[j], ae[j], a);
    vbuf[l*64 + t] = a;
  }
}

// ---------------- node prep, pass-split: blockIdx.y = p (0:xa+b1, 1:xb, 2:xw+dots)
__global__ __launch_bounds__(256) void node_prep(
    const float* __restrict__ x_in,
    const float* __restrict__ em_w1, const float* __restrict__ em_b1,
    const float* __restrict__ gat_w,
    const float* __restrict__ att_src, const float* __restrict__ att_dst,
    __bf16* __restrict__ xaH, __bf16* __restrict__ xbH, __bf16* __restrict__ xwH,
    float* __restrict__ ssrc, float* __restrict__ sdst, int l)
{
  __shared__ float xt[64*DP];
  __shared__ float Ws[64*64];
  __shared__ float asrc[64], adst[64], b1s[64];
  const int t = threadIdx.x;
  const int n0 = blockIdx.x * 64;
  const int p = blockIdx.y;

  { int nl = t >> 2, q = t & 3;
    int n = n0 + nl;
    float4 v0, v1, v2, v3;
    if (n < NN){
      const float* src = x_in + (size_t)n*64 + q*16;
      v0 = ld4(src); v1 = ld4(src+4); v2 = ld4(src+8); v3 = ld4(src+12);
    } else { v0 = v1 = v2 = v3 = f4zero(); }
    float* dst = &xt[nl*DP + q*16];
    st4(dst, v0); st4(dst+4, v1); st4(dst+8, v2); st4(dst+12, v3);
  }
  if (p == 2){
    if (t < 64) asrc[t] = att_src[l*64 + t];
    else if (t < 128) adst[t-64] = att_dst[l*64 + (t-64)];
  } else if (p == 0 && t < 64){
    b1s[t] = em_b1[l*64 + t];
  }
  const float* wp = (p == 0) ? (em_w1 + l*12288)
                  : (p == 1) ? (em_w1 + l*12288 + 4096)
                             : (gat_w + l*4096);
  for (int i = t; i < 1024; i += 256) st4(&Ws[i*4], ld4(wp + i*4));
  __syncthreads();

  const int nl0 = (t >> 4) << 2;
  const int d0  = (t & 15) << 2;
  __bf16* op = (p == 0) ? xaH : (p == 1) ? xbH : xwH;

  float4 acc[4] = {f4zero(), f4zero(), f4zero(), f4zero()};
  gemm_tile(xt, Ws, nl0, d0, acc);
  if (p == 0){
    float4 bb = ld4(&b1s[d0]);
#pragma unroll
    for (int i = 0; i < 4; ++i) acc[i] = f4add(acc[i], bb);
  }
#pragma unroll
  for (int i = 0; i < 4; ++i){
    int n = n0 + nl0 + i;
    if (n < NN) *(ushort4*)(op + (size_t)n*64 + d0) = pack4(acc[i]);
  }
  if (p == 2){
    float4 a4 = ld4(&asrc[d0]);
    float4 b4 = ld4(&adst[d0]);
    float ps[4], pd[4];
#pragma unroll
    for (int i = 0; i < 4; ++i){ ps[i] = f4dot(acc[i], a4); pd[i] = f4dot(acc[i], b4); }
#pragma unroll
    for (int off = 8; off; off >>= 1){
#pragma unroll
      for (int i = 0; i < 4; ++i){ ps[i] += __shfl_xor(ps[i], off); pd[i] += __shfl_xor(pd[i], off); }
    }
    if ((t & 15) == 0){
#pragma unroll
      for (int i = 0; i < 4; ++i){
        int n = n0 + nl0 + i;
        if (n < NN){ ssrc[n] = ps[i]; sdst[n] = pd[i]; }
      }
    }
  }
}

// ---------------- fused edge MLP (MFMA) + attention logit, 128 edges/block
// Software-pipelined: all global loads for BOTH 64-edge tiles issued up front.
__global__ __launch_bounds__(256) void edge_mlp(
    const float* __restrict__ ea0,   // layer-0 f32 edge_attr (orig order); null l>0
    const __bf16* ea_in,             // bf16 sorted edge_attr (aliases ea_out)
    __bf16* ea_out,
    const __bf16* __restrict__ xaH, const __bf16* __restrict__ xbH,
    const float* __restrict__ ssrc, const float* __restrict__ sdst,
    const int* __restrict__ srow, const int* __restrict__ scol,
    const int* __restrict__ permp,
    const __bf16* __restrict__ w1f, const __bf16* __restrict__ w2f,
    const float* __restrict__ b2v, const float* __restrict__ vv,
    float* __restrict__ lrelu, int store_ea)
{
  __shared__ __align__(16) __bf16 uvh[2][64*72];  // 18 KB: bf16(xa[row]+xb[col]) per tile
  __shared__ __align__(16) unsigned ehw[2048];    // 8 KB: eh frags (reused across tiles)
  __shared__ float b2s[64], vs[64], sb[128];
  __shared__ int rs[128], cs[128], ps[128];
  const int t = threadIdx.x;
  const int w = t >> 6, l = t & 63, m = l & 15, kg = l >> 4;
  const int eb = blockIdx.x * 128;

  if (t < 128){ rs[t] = srow[eb+t]; cs[t] = scol[eb+t]; }
  else if (t < 192){ b2s[t-128] = b2v[t-128]; vs[t-128] = vv[t-128]; }
  if (permp && t < 128) ps[t] = permp[eb+t];
  __syncthreads();

  const bf16x8* B1 = (const bf16x8*)w1f;
  const bf16x8* B2 = (const bf16x8*)w2f;
  const f32x4 z4 = {0.f, 0.f, 0.f, 0.f};
  const int e_loc = t >> 2, q = t & 3;

  // ======== global load phase: everything issued before any fence ========
  const int r0 = rs[e_loc],      c0 = cs[e_loc];
  const int r1 = rs[64 + e_loc], c1 = cs[64 + e_loc];
  const bf16x8* pa0 = (const bf16x8*)(xaH + (size_t)r0*64 + q*16);
  const bf16x8* pb0 = (const bf16x8*)(xbH + (size_t)c0*64 + q*16);
  const bf16x8* pa1 = (const bf16x8*)(xaH + (size_t)r1*64 + q*16);
  const bf16x8* pb1 = (const bf16x8*)(xbH + (size_t)c1*64 + q*16);
  bf16x8 g_a0l = pa0[0], g_a0h = pa0[1], g_b0l = pb0[0], g_b0h = pb0[1];
  bf16x8 g_a1l = pa1[0], g_a1h = pa1[1], g_b1l = pb1[0], g_b1h = pb1[1];
  float sb0 = 0.f, sb1 = 0.f;
  if (q == 0){ sb0 = ssrc[r0] + sdst[c0]; sb1 = ssrc[r1] + sdst[c1]; }

  bf16x8 A00, A01, A10, A11;    // A-frags: tile, k-half
  { const int elA = 16*w + m;
    if (ea0){
      const float* s0 = ea0 + (size_t)ps[elA]*64 + kg*8;
      const float* s1 = ea0 + (size_t)ps[64+elA]*64 + kg*8;
      A00 = cvt8(ld4(s0),    ld4(s0+4));  A01 = cvt8(ld4(s0+32), ld4(s0+36));
      A10 = cvt8(ld4(s1),    ld4(s1+4));  A11 = cvt8(ld4(s1+32), ld4(s1+36));
    } else {
      const __bf16* s0 = ea_in + (size_t)(eb+elA)*64 + kg*8;
      const __bf16* s1 = ea_in + (size_t)(eb+64+elA)*64 + kg*8;
      A00 = *(const bf16x8*)s0;  A01 = *(const bf16x8*)(s0+32);
      A10 = *(const bf16x8*)s1;  A11 = *(const bf16x8*)(s1+32);
    }
  }

  // ======== LDS write phase (both tiles) ========
  *(bf16x8*)&uvh[0][e_loc*72 + q*16]     = addpack8(g_a0l, g_b0l);
  *(bf16x8*)&uvh[0][e_loc*72 + q*16 + 8] = addpack8(g_a0h, g_b0h);
  *(bf16x8*)&uvh[1][e_loc*72 + q*16]     = addpack8(g_a1l, g_b1l);
  *(bf16x8*)&uvh[1][e_loc*72 + q*16 + 8] = addpack8(g_a1h, g_b1h);
  if (q == 0){ sb[e_loc] = sb0; sb[64 + e_loc] = sb1; }
  asm volatile("" ::: "memory");   // LDS writes ordered before compute reads (same wave)

  // ======== compute phase: VGPR/LDS only ========
  __bf16* esc = (__bf16*)ehw;
  auto tile_compute = [&](bf16x8 a0, bf16x8 a1, const __bf16* uvt, int tb){
    f32x4 acc[4];
#pragma unroll
    for (int nt = 0; nt < 4; ++nt){
      acc[nt] = __builtin_amdgcn_mfma_f32_16x16x32_bf16(a0, B1[(nt*2+0)*64 + l], z4, 0, 0, 0);
      acc[nt] = __builtin_amdgcn_mfma_f32_16x16x32_bf16(a1, B1[(nt*2+1)*64 + l], acc[nt], 0, 0, 0);
    }
#pragma unroll
    for (int nt = 0; nt < 4; ++nt){
      const int j = nt*16 + m;
#pragma unroll
      for (int r = 0; r < 4; ++r){
        const int erow = 16*w + 4*kg + r;
        float v = acc[nt][r] + (float)uvt[erow*72 + j];
        v = fmaxf(v, 0.f);
        const int piece = (w*2 + (nt>>1))*64 + (((nt&1)<<1) | (m>>3))*16 + 4*kg + r;
        esc[piece*8 + (m&7)] = (__bf16)v;
      }
    }
    asm volatile("" ::: "memory");   // eh writes before cross-lane reads (same wave)
    bf16x8 a20 = *(const bf16x8*)(esc + (size_t)((w*2+0)*64 + kg*16 + m)*8);
    bf16x8 a21 = *(const bf16x8*)(esc + (size_t)((w*2+1)*64 + kg*16 + m)*8);
    f32x4 acc2[4];
#pragma unroll
    for (int nt = 0; nt < 4; ++nt){
      acc2[nt] = __builtin_amdgcn_mfma_f32_16x16x32_bf16(a20, B2[(nt*2+0)*64 + l], z4, 0, 0, 0);
      acc2[nt] = __builtin_amdgcn_mfma_f32_16x16x32_bf16(a21, B2[(nt*2+1)*64 + l], acc2[nt], 0, 0, 0);
    }
    float p0 = 0.f, p1 = 0.f, p2 = 0.f, p3 = 0.f;
#pragma unroll
    for (int nt = 0; nt < 4; ++nt){
      const int j = nt*16 + m;
      const float bj = b2s[j], vj = vs[j];
      float vr[4];
      vr[0] = acc2[nt][0] + bj; vr[1] = acc2[nt][1] + bj;
      vr[2] = acc2[nt][2] + bj; vr[3] = acc2[nt][3] + bj;
      if (store_ea){
        const size_t rowb = (size_t)(eb + tb + 16*w + 4*kg)*64 + (j & ~1);
#pragma unroll
        for (int r = 0; r < 4; ++r){
          unsigned short hu = __builtin_bit_cast(unsigned short, (__bf16)vr[r]);
          int pu = __shfl_xor((int)hu, 1);
          if (!(m & 1)){
            unsigned word = (unsigned)hu | ((unsigned)(pu & 0xffff) << 16);
            *(unsigned*)(ea_out + rowb + (size_t)r*64) = word;
          }
        }
      }
      p0 = fmaf(vr[0], vj, p0); p1 = fmaf(vr[1], vj, p1);
      p2 = fmaf(vr[2], vj, p2); p3 = fmaf(vr[3], vj, p3);
    }
#pragma unroll
    for (int o = 8; o; o >>= 1){
      p0 += __shfl_xor(p0, o); p1 += __shfl_xor(p1, o);
      p2 += __shfl_xor(p2, o); p3 += __shfl_xor(p3, o);
    }
    if (m == 0){
      float pv[4] = {p0, p1, p2, p3};
#pragma unroll
      for (int r = 0; r < 4; ++r){
        const int erow = 16*w + 4*kg + r;
        float logit = sb[tb + erow] + pv[r];
        lrelu[eb + tb + erow] = logit > 0.f ? logit : NEG_SLOPE * logit;
      }
    }
  };

  tile_compute(A00, A01, &uvh[0][0], 0);
  asm volatile("" ::: "memory");   // tile0 ehw reads before tile1 ehw writes
  tile_compute(A10, A11, &uvh[1][0], 64);
}

// ---------------- segment softmax + aggregation, atomic-free: one wave per col
__global__ __launch_bounds__(256) void col_agg(
    const float* __restrict__ lrelu, const int* __restrict__ srow,
    const int* __restrict__ off, const __bf16* __restrict__ xwH,
    float* __restrict__ h)
{
  const int t = threadIdx.x;
  const int lane = t & 63;
  const int c = blockIdx.x * 4 + (t >> 6);
  const int s0 = off[c], s1 = off[c+1];
  const int L = s1 - s0;

  float m = -3.402823466e38f;
  for (int i = lane; i < L; i += 64) m = fmaxf(m, lrelu[s0+i]);
#pragma unroll
  for (int o = 32; o; o >>= 1) m = fmaxf(m, __shfl_xor(m, o));

  float z0 = 0.f, z1 = 0.f;
  if (lane < L)      z0 = expf(lrelu[s0+lane] - m);
  if (lane+64 < L)   z1 = expf(lrelu[s0+lane+64] - m);
  float s = z0 + z1;
  for (int i = lane+128; i < L; i += 64) s += expf(lrelu[s0+i] - m);
#pragma unroll
  for (int o = 32; o; o >>= 1) s += __shfl_xor(s, o);
  const float inv = 1.f / (s + 1e-16f);

  float hv = 0.f;
  if (L <= 128){
    for (int i = 0; i < L; ++i){
      float z = (i < 64) ? __shfl(z0, i) : __shfl(z1, i - 64);
      int r = srow[s0+i];
      hv = fmaf(z * inv, (float)xwH[(size_t)r*64 + lane], hv);
    }
  } else {
    for (int i = 0; i < L; ++i){
      float z = expf(lrelu[s0+i] - m);
      int r = srow[s0+i];
      hv = fmaf(z * inv, (float)xwH[(size_t)r*64 + lane], hv);
    }
  }
  h[(size_t)c*64 + lane] = hv;
}

// ---------------- BN stats (sum, sumsq per dim)
__global__ __launch_bounds__(256) void bn_stats(
    const float* __restrict__ h, float* __restrict__ musum, float* __restrict__ sqsum)
{
  const int t = threadIdx.x;
  const int d = t & 63, sub = t >> 6;
  const int base = blockIdx.x * 256;
  float s = 0.f, s2 = 0.f;
  for (int i = sub; i < 256; i += 4){
    int n = base + i;
    if (n < NN){ float v = h[(size_t)n*64 + d]; s += v; s2 = fmaf(v, v, s2); }
  }
  __shared__ float r1[4][64], r2[4][64];
  r1[sub][d] = s; r2[sub][d] = s2;
  __syncthreads();
  if (sub == 0){
    s  = r1[0][d] + r1[1][d] + r1[2][d] + r1[3][d];
    s2 = r2[0][d] + r2[1][d] + r2[2][d] + r2[3][d];
    atomicAdd(&musum[d], s);
    atomicAdd(&sqsum[d], s2);
  }
}

// ---------------- x = relu(BN(h))
__global__ __launch_bounds__(256) void bn_apply(
    const float* __restrict__ h, const float* __restrict__ musum,
    const float* __restrict__ sqsum, const float* __restrict__ gamma,
    const float* __restrict__ beta, float* __restrict__ xout, int l)
{
  int idx = blockIdx.x * 256 + threadIdx.x;
  int d = idx & 63;
  float mu = musum[d] * (1.0f / NN);
  float var = sqsum[d] * (1.0f / NN) - mu * mu;
  float inv = rsqrtf(var + 1e-5f);
  float v = (h[idx] - mu) * inv * gamma[l*64 + d] + beta[l*64 + d];
  xout[idx] = fmaxf(v, 0.f);
}

// ---------------- mean pool: one block per graph, contiguous segment
__global__ __launch_bounds__(256) void seg_pool(
    const float* __restrict__ x, const int* __restrict__ goff,
    float* __restrict__ pools, float* __restrict__ pcnt)
{
  const int g = blockIdx.x;
  const int t = threadIdx.x;
  const int d = t & 63, sub = t >> 6;
  const int s0 = goff[g], s1 = goff[g+1];
  float s = 0.f;
  for (int n = s0 + sub; n < s1; n += 4) s += x[(size_t)n*64 + d];
  __shared__ float r[4][64];
  r[sub][d] = s;
  __syncthreads();
  if (sub == 0){
    s = r[0][d] + r[1][d] + r[2][d] + r[3][d];
    pools[g*64 + d] = s;
    if (d == 0) pcnt[g] = (float)(s1 - s0);
  }
}

// ---------------- readout MLP (one block)
__global__ __launch_bounds__(256) void final_mlp(
    const float* __restrict__ pools, const float* __restrict__ pcnt,
    const float* __restrict__ w1, const float* __restrict__ b1,
    const float* __restrict__ w2, const float* __restrict__ b2,
    const float* __restrict__ w3, const float* __restrict__ b3,
    float* __restrict__ out)
{
  __shared__ float g[32*64], h1[32*64], h2[32*32];
  const int t = threadIdx.x;
  for (int i = t; i < 2048; i += 256) g[i] = pools[i] / fmaxf(pcnt[i >> 6], 1.0f);
  __syncthreads();
  for (int i = t; i < 2048; i += 256){
    int gi = i >> 6, d = i & 63;
    float a = b1[d];
    for (int k = 0; k < 64; ++k) a = fmaf(g[gi*64 + k], w1[k*64 + d], a);
    h1[i] = fmaxf(a, 0.f);
  }
  __syncthreads();
  for (int i = t; i < 1024; i += 256){
    int gi = i >> 5, d = i & 31;
    float a = b2[d];
    for (int k = 0; k < 64; ++k) a = fmaf(h1[gi*64 + k], w2[k*32 + d], a);
    h2[i] = fmaxf(a, 0.f);
  }
  __syncthreads();
  if (t < 32){
    float a = b3[0];
    for (int k = 0; k < 32; ++k) a = fmaf(h2[t*32 + k], w3[k], a);
    out[t] = a;
  }
}

extern "C" void kernel_launch(void* const* d_in, const int* in_sizes, int n_in,
                              void* d_out, int out_size, void* d_ws, size_t ws_size,
                              hipStream_t stream)
{
  (void)in_sizes; (void)n_in; (void)out_size; (void)ws_size;
  const float* x0       = (const float*)d_in[0];
  const int*   ei       = (const int*)  d_in[1];
  const float* ea0      = (const float*)d_in[2];
  const int*   batch    = (const int*)  d_in[3];
  const float* em_w1    = (const float*)d_in[4];
  const float* em_b1    = (const float*)d_in[5];
  const float* em_w2    = (const float*)d_in[6];
  const float* em_b2    = (const float*)d_in[7];
  const float* gat_w    = (const float*)d_in[8];
  const float* att_src  = (const float*)d_in[9];
  const float* att_dst  = (const float*)d_in[10];
  const float* edge_w   = (const float*)d_in[11];
  const float* att_edge = (const float*)d_in[12];
  // d_in[13] gat_bias: cancels inside BatchNorm -> unused
  const float* bn_gamma = (const float*)d_in[14];
  const float* bn_beta  = (const float*)d_in[15];
  const float* mlp_w1   = (const float*)d_in[16];
  const float* mlp_b1   = (const float*)d_in[17];
  const float* mlp_w2   = (const float*)d_in[18];
  const float* mlp_b2   = (const float*)d_in[19];
  const float* mlp_w3   = (const float*)d_in[20];
  const float* mlp_b3   = (const float*)d_in[21];
  float* out = (float*)d_out;

  const size_t N64 = (size_t)NN * 64, E64 = (size_t)NE * 64;
  float* ws    = (float*)d_ws;
  float* wsE   = ws;                 // E64 f32 slots; used as bf16 edge_attr (sorted)
  float* sxa   = wsE + E64;          // N64 f32 slot -> bf16 xaH (= x@W1a + b1)
  float* sxb   = sxa + N64;          // N64 f32 slot -> bf16 xbH
  float* sxw   = sxb + N64;          // N64 f32 slot -> bf16 xwH
  float* xcur  = sxw + N64;          // N64
  float* hbuf  = xcur + N64;         // N64
  float* musum = hbuf + N64;         // 64  -- per-layer memset start
  float* sqsum = musum + 64;         // 64  -- per-layer memset end
  float* lrelu = sqsum + 64;         // NE
  float* pools = lrelu + NE;         // 2048
  float* pcnt  = pools + 2048;       // 32
  float* ssrc  = pcnt + 32;          // NN
  float* sdst  = ssrc + NN;          // NN
  int*   cnt   = (int*)(sdst + NN);  // NN  -- once memset start
  int*   cur   = cnt + NN;           // NN  -- once memset end
  int*   soff  = cur + NN;           // NN+1
  int*   srow  = soff + NN + 1;      // NE
  int*   scol  = srow + NE;          // NE
  int*   perm  = scol + NE;          // NE
  int*   goff  = perm + NE;          // 33 (pad to 40 for alignment)
  __bf16* eaB  = (__bf16*)wsE;
  __bf16* xaH  = (__bf16*)sxa;
  __bf16* xbH  = (__bf16*)sxb;
  __bf16* xwH  = (__bf16*)sxw;
  __bf16* w1f  = (__bf16*)(goff + 40);   // 3*4096 bf16
  __bf16* w2f  = w1f + 3*4096;           // 3*4096 bf16
  float* vbuf  = (float*)(w2f + 3*4096); // 3*64 f32

  // ---- one-time per call: counting sort by col, graph bounds, weight fragments
  hipMemsetAsync(cnt, 0, 2 * NN * sizeof(int), stream);
  hist_kernel<<<NE / 256, 256, 0, stream>>>(ei + NE, cnt);
  scan_kernel<<<1, 256, 0, stream>>>(cnt, soff);
  scatter_kernel<<<NE / 256, 256, 0, stream>>>(ei, soff, cur, srow, scol, perm);
  graph_bounds<<<(NN + 255) / 256, 256, 0, stream>>>(batch, goff);
  prep_weights<<<3, 256, 0, stream>>>(em_w1, em_w2, edge_w, att_edge, w1f, w2f, vbuf);

  for (int l = 0; l < 3; ++l){
    const float* x_in = (l == 0) ? x0 : xcur;

    hipMemsetAsync(musum, 0, 128 * sizeof(float), stream);

    dim3 npg((NN + 63) / 64, 3);
    node_prep<<<npg, 256, 0, stream>>>(
        x_in, em_w1, em_b1, gat_w, att_src, att_dst, xaH, xbH, xwH, ssrc, sdst, l);

    edge_mlp<<<NE / 128, 256, 0, stream>>>(
        (l == 0) ? ea0 : nullptr, eaB, eaB, xaH, xbH, ssrc, sdst,
        srow, scol, (l == 0) ? perm : nullptr,
        w1f + (size_t)l*4096, w2f + (size_t)l*4096,
        em_b2 + l*64, vbuf + l*64, lrelu, (l < 2) ? 1 : 0);

    col_agg<<<NN / 4, 256, 0, stream>>>(lrelu, srow, soff, xwH, hbuf);

    bn_stats<<<(NN + 255) / 256, 256, 0, stream>>>(hbuf, musum, sqsum);

    bn_apply<<<(int)(N64 / 256), 256, 0, stream>>>(
        hbuf, musum, sqsum, bn_gamma, bn_beta, xcur, l);
  }

  seg_pool<<<32, 256, 0, stream>>>(xcur, goff, pools, pcnt);
  final_mlp<<<1, 256, 0, stream>>>(pools, pcnt, mlp_w1, mlp_b1, mlp_w2, mlp_b2,
                                   mlp_w3, mlp_b3, out);
}

// Round 8
// 813.155 us; speedup vs baseline: 4.5217x; 1.2180x over previous
//
#include <hip/hip_runtime.h>

// GNN forward: 3 x (edge-MLP -> GAT(softmax over col) -> BN+ReLU) -> mean-pool -> MLP.
// Round-8: (a) col_agg rewritten: z/srow staged in LDS once, 4-way unrolled
// aggregation with 4 independent accumulators (4 gathers in flight), inv factored
// out. (b) bn_apply kernel removed: node_prep applies BN+ReLU inline when staging
// h (stats of layer l-1); seg_pool applies BN+ReLU for layer 2. Stats memset moved
// after node_prep (which consumes layer l-1 stats). Edge GEMMs bf16 MFMA.

#define NN 50000
#define NE 800000
#define DP 68
#define NEG_SLOPE 0.2f

typedef __attribute__((ext_vector_type(8))) __bf16 bf16x8;
typedef __attribute__((ext_vector_type(4))) float f32x4;

__device__ __forceinline__ float4 ld4(const float* __restrict__ p){ return *(const float4* __restrict__)p; }
__device__ __forceinline__ void st4(float* __restrict__ p, float4 v){ *(float4* __restrict__)p = v; }
__device__ __forceinline__ float4 f4zero(){ return make_float4(0.f,0.f,0.f,0.f); }
__device__ __forceinline__ float4 f4add(float4 a, float4 b){
  return make_float4(a.x+b.x, a.y+b.y, a.z+b.z, a.w+b.w);
}
__device__ __forceinline__ float4 f4fma(float a, float4 b, float4 c){
  return make_float4(fmaf(a,b.x,c.x), fmaf(a,b.y,c.y), fmaf(a,b.z,c.z), fmaf(a,b.w,c.w));
}
__device__ __forceinline__ float f4dot(float4 a, float4 b){
  return fmaf(a.x,b.x, fmaf(a.y,b.y, fmaf(a.z,b.z, a.w*b.w)));
}
__device__ __forceinline__ bf16x8 cvt8(float4 a, float4 b){
  bf16x8 r;
  r[0]=(__bf16)a.x; r[1]=(__bf16)a.y; r[2]=(__bf16)a.z; r[3]=(__bf16)a.w;
  r[4]=(__bf16)b.x; r[5]=(__bf16)b.y; r[6]=(__bf16)b.z; r[7]=(__bf16)b.w;
  return r;
}
__device__ __forceinline__ bf16x8 addpack8(bf16x8 a, bf16x8 b){
  bf16x8 r;
#pragma unroll
  for (int e = 0; e < 8; ++e) r[e] = (__bf16)((float)a[e] + (float)b[e]);
  return r;
}
__device__ __forceinline__ ushort4 pack4(float4 v){
  ushort4 u;
  u.x = __builtin_bit_cast(unsigned short, (__bf16)v.x);
  u.y = __builtin_bit_cast(unsigned short, (__bf16)v.y);
  u.z = __builtin_bit_cast(unsigned short, (__bf16)v.z);
  u.w = __builtin_bit_cast(unsigned short, (__bf16)v.w);
  return u;
}
__device__ __forceinline__ float4 bnrelu4(float4 v, const float* sc, const float* sh, int d){
  return make_float4(
    fmaxf(fmaf(v.x, sc[d+0], sh[d+0]), 0.f),
    fmaxf(fmaf(v.y, sc[d+1], sh[d+1]), 0.f),
    fmaxf(fmaf(v.z, sc[d+2], sh[d+2]), 0.f),
    fmaxf(fmaf(v.w, sc[d+3], sh[d+3]), 0.f));
}

// 64x64 @ 64x64 f32 block GEMM fragment (node_prep only).
__device__ __forceinline__ void gemm_tile(const float* inT, const float* W,
                                          int el0, int d0, float4 acc[4]){
#pragma unroll 4
  for (int kc = 0; kc < 16; ++kc){
    float4 w0 = ld4(&W[(kc*4+0)*64 + d0]);
    float4 w1 = ld4(&W[(kc*4+1)*64 + d0]);
    float4 w2 = ld4(&W[(kc*4+2)*64 + d0]);
    float4 w3 = ld4(&W[(kc*4+3)*64 + d0]);
#pragma unroll
    for (int i = 0; i < 4; ++i){
      float4 iv = ld4(&inT[(el0+i)*DP + kc*4]);
      acc[i] = f4fma(iv.x, w0, acc[i]);
      acc[i] = f4fma(iv.y, w1, acc[i]);
      acc[i] = f4fma(iv.z, w2, acc[i]);
      acc[i] = f4fma(iv.w, w3, acc[i]);
    }
  }
}

// ---------------- sort: histogram of col
__global__ __launch_bounds__(256) void hist_kernel(const int* __restrict__ ei_col,
                                                   int* __restrict__ cnt){
  int e = blockIdx.x * 256 + threadIdx.x;
  atomicAdd(&cnt[ei_col[e]], 1);
}

// ---------------- sort: exclusive prefix sum over NN bins (single block)
__global__ __launch_bounds__(256) void scan_kernel(const int* __restrict__ cnt,
                                                   int* __restrict__ off){
  __shared__ int wsum[4];
  __shared__ int carry_s;
  const int t = threadIdx.x;
  const int lane = t & 63, w = t >> 6;
  if (t == 0) carry_s = 0;
  __syncthreads();
  for (int base = 0; base < NN; base += 256){
    int idx = base + t;
    int v = (idx < NN) ? cnt[idx] : 0;
    int x = v;
#pragma unroll
    for (int o = 1; o < 64; o <<= 1){
      int u = __shfl_up(x, o);
      if (lane >= o) x += u;
    }
    if (lane == 63) wsum[w] = x;
    __syncthreads();
    int wo = carry_s;
#pragma unroll
    for (int k = 0; k < 4; ++k) if (k < w) wo += wsum[k];
    int incl = x + wo;
    if (idx < NN) off[idx] = incl - v;
    __syncthreads();
    if (t == 255) carry_s = incl;
    __syncthreads();
  }
  if (t == 0) off[NN] = carry_s;
}

// ---------------- sort: scatter into sorted position
__global__ __launch_bounds__(256) void scatter_kernel(
    const int* __restrict__ ei, const int* __restrict__ off, int* __restrict__ cur,
    int* __restrict__ srow, int* __restrict__ scol, int* __restrict__ perm){
  int e = blockIdx.x * 256 + threadIdx.x;
  int r = ei[e], c = ei[NE + e];
  int pos = off[c] + atomicAdd(&cur[c], 1);
  srow[pos] = r; scol[pos] = c; perm[pos] = e;
}

// ---------------- graph segment boundaries from sorted batch
__global__ __launch_bounds__(256) void graph_bounds(const int* __restrict__ batch,
                                                    int* __restrict__ goff){
  int n = blockIdx.x * 256 + threadIdx.x;
  if (n >= NN) return;
  int bn = batch[n];
  int bp = (n == 0) ? -1 : batch[n-1];
  for (int g = bp + 1; g <= bn; ++g) goff[g] = n;
  if (n == NN - 1){ for (int g = bn + 1; g <= 32; ++g) goff[g] = NN; }
}

// ---------------- weights -> bf16 MFMA B-fragment layout + v = edge_w @ att_edge
__global__ __launch_bounds__(256) void prep_weights(
    const float* __restrict__ em_w1, const float* __restrict__ em_w2,
    const float* __restrict__ edge_w, const float* __restrict__ att_edge,
    __bf16* __restrict__ w1f, __bf16* __restrict__ w2f, float* __restrict__ vbuf)
{
  const int l = blockIdx.x, t = threadIdx.x;
  const float* W1 = em_w1 + l*12288 + 8192;   // rows 128..191 of em_w1[l]
  const float* W2 = em_w2 + l*4096;
  for (int p = t; p < 512; p += 256){
    int li = p & 63, ks = (p >> 6) & 1, nt = p >> 7;
    int kbase = ks*32 + (li >> 4)*8;
    int j = nt*16 + (li & 15);
    bf16x8 v1, v2;
#pragma unroll
    for (int e = 0; e < 8; ++e){
      v1[e] = (__bf16)W1[(size_t)(kbase+e)*64 + j];
      v2[e] = (__bf16)W2[(size_t)(kbase+e)*64 + j];
    }
    *(bf16x8*)(w1f + (size_t)l*4096 + p*8) = v1;
    *(bf16x8*)(w2f + (size_t)l*4096 + p*8) = v2;
  }
  if (t < 64){
    float a = 0.f;
    const float* ew = edge_w + l*4096 + t*64;
    const float* ae = att_edge + l*64;
#pragma unroll 8
    for (int j = 0; j < 64; ++j) a = fmaf(ew[j], ae[j], a);
    vbuf[l*64 + t] = a;
  }
}

// ---------------- node prep, pass-split (blockIdx.y = p), BN+ReLU of layer l-1 fused
__global__ __launch_bounds__(256) void node_prep(
    const float* __restrict__ x0_in, const float* __restrict__ h_in,
    const float* __restrict__ musum, const float* __restrict__ sqsum,
    const float* __restrict__ gamma, const float* __restrict__ beta,
    const float* __restrict__ em_w1, const float* __restrict__ em_b1,
    const float* __restrict__ gat_w,
    const float* __restrict__ att_src, const float* __restrict__ att_dst,
    __bf16* __restrict__ xaH, __bf16* __restrict__ xbH, __bf16* __restrict__ xwH,
    float* __restrict__ ssrc, float* __restrict__ sdst, int l)
{
  __shared__ float xt[64*DP];
  __shared__ float Ws[64*64];
  __shared__ float asrc[64], adst[64], b1s[64];
  __shared__ float sc[64], sh[64];
  const int t = threadIdx.x;
  const int n0 = blockIdx.x * 64;
  const int p = blockIdx.y;

  if (l > 0){
    if (t < 64){
      float mu  = musum[t] * (1.0f / NN);
      float var = sqsum[t] * (1.0f / NN) - mu * mu;
      float iv  = rsqrtf(var + 1e-5f) * gamma[(l-1)*64 + t];
      sc[t] = iv;
      sh[t] = beta[(l-1)*64 + t] - mu * iv;
    }
    __syncthreads();
  }

  { int nl = t >> 2, q = t & 3;
    int n = n0 + nl;
    float4 v0, v1, v2, v3;
    if (n < NN){
      const float* src = ((l == 0) ? x0_in : h_in) + (size_t)n*64 + q*16;
      v0 = ld4(src); v1 = ld4(src+4); v2 = ld4(src+8); v3 = ld4(src+12);
      if (l > 0){
        v0 = bnrelu4(v0, sc, sh, q*16);
        v1 = bnrelu4(v1, sc, sh, q*16+4);
        v2 = bnrelu4(v2, sc, sh, q*16+8);
        v3 = bnrelu4(v3, sc, sh, q*16+12);
      }
    } else { v0 = v1 = v2 = v3 = f4zero(); }
    float* dst = &xt[nl*DP + q*16];
    st4(dst, v0); st4(dst+4, v1); st4(dst+8, v2); st4(dst+12, v3);
  }
  if (p == 2){
    if (t < 64) asrc[t] = att_src[l*64 + t];
    else if (t < 128) adst[t-64] = att_dst[l*64 + (t-64)];
  } else if (p == 0 && t < 64){
    b1s[t] = em_b1[l*64 + t];
  }
  const float* wp = (p == 0) ? (em_w1 + l*12288)
                  : (p == 1) ? (em_w1 + l*12288 + 4096)
                             : (gat_w + l*4096);
  for (int i = t; i < 1024; i += 256) st4(&Ws[i*4], ld4(wp + i*4));
  __syncthreads();

  const int nl0 = (t >> 4) << 2;
  const int d0  = (t & 15) << 2;
  __bf16* op = (p == 0) ? xaH : (p == 1) ? xbH : xwH;

  float4 acc[4] = {f4zero(), f4zero(), f4zero(), f4zero()};
  gemm_tile(xt, Ws, nl0, d0, acc);
  if (p == 0){
    float4 bb = ld4(&b1s[d0]);
#pragma unroll
    for (int i = 0; i < 4; ++i) acc[i] = f4add(acc[i], bb);
  }
#pragma unroll
  for (int i = 0; i < 4; ++i){
    int n = n0 + nl0 + i;
    if (n < NN) *(ushort4*)(op + (size_t)n*64 + d0) = pack4(acc[i]);
  }
  if (p == 2){
    float4 a4 = ld4(&asrc[d0]);
    float4 b4 = ld4(&adst[d0]);
    float ps[4], pd[4];
#pragma unroll
    for (int i = 0; i < 4; ++i){ ps[i] = f4dot(acc[i], a4); pd[i] = f4dot(acc[i], b4); }
#pragma unroll
    for (int off = 8; off; off >>= 1){
#pragma unroll
      for (int i = 0; i < 4; ++i){ ps[i] += __shfl_xor(ps[i], off); pd[i] += __shfl_xor(pd[i], off); }
    }
    if ((t & 15) == 0){
#pragma unroll
      for (int i = 0; i < 4; ++i){
        int n = n0 + nl0 + i;
        if (n < NN){ ssrc[n] = ps[i]; sdst[n] = pd[i]; }
      }
    }
  }
}

// ---------------- fused edge MLP (MFMA) + attention logit, 128 edges/block
__global__ __launch_bounds__(256) void edge_mlp(
    const float* __restrict__ ea0,   // layer-0 f32 edge_attr (orig order); null l>0
    const __bf16* ea_in,             // bf16 sorted edge_attr (aliases ea_out)
    __bf16* ea_out,
    const __bf16* __restrict__ xaH, const __bf16* __restrict__ xbH,
    const float* __restrict__ ssrc, const float* __restrict__ sdst,
    const int* __restrict__ srow, const int* __restrict__ scol,
    const int* __restrict__ permp,
    const __bf16* __restrict__ w1f, const __bf16* __restrict__ w2f,
    const float* __restrict__ b2v, const float* __restrict__ vv,
    float* __restrict__ lrelu, int store_ea)
{
  __shared__ __align__(16) __bf16 uvh[2][64*72];  // 18 KB: bf16(xa[row]+xb[col]) per tile
  __shared__ __align__(16) unsigned ehw[2048];    // 8 KB: eh frags (reused across tiles)
  __shared__ float b2s[64], vs[64], sb[128];
  __shared__ int rs[128], cs[128], ps[128];
  const int t = threadIdx.x;
  const int w = t >> 6, l = t & 63, m = l & 15, kg = l >> 4;
  const int eb = blockIdx.x * 128;

  if (t < 128){ rs[t] = srow[eb+t]; cs[t] = scol[eb+t]; }
  else if (t < 192){ b2s[t-128] = b2v[t-128]; vs[t-128] = vv[t-128]; }
  if (permp && t < 128) ps[t] = permp[eb+t];
  __syncthreads();

  const bf16x8* B1 = (const bf16x8*)w1f;
  const bf16x8* B2 = (const bf16x8*)w2f;
  const f32x4 z4 = {0.f, 0.f, 0.f, 0.f};
  const int e_loc = t >> 2, q = t & 3;

  // ======== global load phase: everything issued before any fence ========
  const int r0 = rs[e_loc],      c0 = cs[e_loc];
  const int r1 = rs[64 + e_loc], c1 = cs[64 + e_loc];
  const bf16x8* pa0 = (const bf16x8*)(xaH + (size_t)r0*64 + q*16);
  const bf16x8* pb0 = (const bf16x8*)(xbH + (size_t)c0*64 + q*16);
  const bf16x8* pa1 = (const bf16x8*)(xaH + (size_t)r1*64 + q*16);
  const bf16x8* pb1 = (const bf16x8*)(xbH + (size_t)c1*64 + q*16);
  bf16x8 g_a0l = pa0[0], g_a0h = pa0[1], g_b0l = pb0[0], g_b0h = pb0[1];
  bf16x8 g_a1l = pa1[0], g_a1h = pa1[1], g_b1l = pb1[0], g_b1h = pb1[1];
  float sb0 = 0.f, sb1 = 0.f;
  if (q == 0){ sb0 = ssrc[r0] + sdst[c0]; sb1 = ssrc[r1] + sdst[c1]; }

  bf16x8 A00, A01, A10, A11;    // A-frags: tile, k-half
  { const int elA = 16*w + m;
    if (ea0){
      const float* s0 = ea0 + (size_t)ps[elA]*64 + kg*8;
      const float* s1 = ea0 + (size_t)ps[64+elA]*64 + kg*8;
      A00 = cvt8(ld4(s0),    ld4(s0+4));  A01 = cvt8(ld4(s0+32), ld4(s0+36));
      A10 = cvt8(ld4(s1),    ld4(s1+4));  A11 = cvt8(ld4(s1+32), ld4(s1+36));
    } else {
      const __bf16* s0 = ea_in + (size_t)(eb+elA)*64 + kg*8;
      const __bf16* s1 = ea_in + (size_t)(eb+64+elA)*64 + kg*8;
      A00 = *(const bf16x8*)s0;  A01 = *(const bf16x8*)(s0+32);
      A10 = *(const bf16x8*)s1;  A11 = *(const bf16x8*)(s1+32);
    }
  }

  // ======== LDS write phase (both tiles) ========
  *(bf16x8*)&uvh[0][e_loc*72 + q*16]     = addpack8(g_a0l, g_b0l);
  *(bf16x8*)&uvh[0][e_loc*72 + q*16 + 8] = addpack8(g_a0h, g_b0h);
  *(bf16x8*)&uvh[1][e_loc*72 + q*16]     = addpack8(g_a1l, g_b1l);
  *(bf16x8*)&uvh[1][e_loc*72 + q*16 + 8] = addpack8(g_a1h, g_b1h);
  if (q == 0){ sb[e_loc] = sb0; sb[64 + e_loc] = sb1; }
  asm volatile("" ::: "memory");   // LDS writes ordered before compute reads (same wave)

  // ======== compute phase: VGPR/LDS only ========
  __bf16* esc = (__bf16*)ehw;
  auto tile_compute = [&](bf16x8 a0, bf16x8 a1, const __bf16* uvt, int tb){
    f32x4 acc[4];
#pragma unroll
    for (int nt = 0; nt < 4; ++nt){
      acc[nt] = __builtin_amdgcn_mfma_f32_16x16x32_bf16(a0, B1[(nt*2+0)*64 + l], z4, 0, 0, 0);
      acc[nt] = __builtin_amdgcn_mfma_f32_16x16x32_bf16(a1, B1[(nt*2+1)*64 + l], acc[nt], 0, 0, 0);
    }
#pragma unroll
    for (int nt = 0; nt < 4; ++nt){
      const int j = nt*16 + m;
#pragma unroll
      for (int r = 0; r < 4; ++r){
        const int erow = 16*w + 4*kg + r;
        float v = acc[nt][r] + (float)uvt[erow*72 + j];
        v = fmaxf(v, 0.f);
        const int piece = (w*2 + (nt>>1))*64 + (((nt&1)<<1) | (m>>3))*16 + 4*kg + r;
        esc[piece*8 + (m&7)] = (__bf16)v;
      }
    }
    asm volatile("" ::: "memory");   // eh writes before cross-lane reads (same wave)
    bf16x8 a20 = *(const bf16x8*)(esc + (size_t)((w*2+0)*64 + kg*16 + m)*8);
    bf16x8 a21 = *(const bf16x8*)(esc + (size_t)((w*2+1)*64 + kg*16 + m)*8);
    f32x4 acc2[4];
#pragma unroll
    for (int nt = 0; nt < 4; ++nt){
      acc2[nt] = __builtin_amdgcn_mfma_f32_16x16x32_bf16(a20, B2[(nt*2+0)*64 + l], z4, 0, 0, 0);
      acc2[nt] = __builtin_amdgcn_mfma_f32_16x16x32_bf16(a21, B2[(nt*2+1)*64 + l], acc2[nt], 0, 0, 0);
    }
    float p0 = 0.f, p1 = 0.f, p2 = 0.f, p3 = 0.f;
#pragma unroll
    for (int nt = 0; nt < 4; ++nt){
      const int j = nt*16 + m;
      const float bj = b2s[j], vj = vs[j];
      float vr[4];
      vr[0] = acc2[nt][0] + bj; vr[1] = acc2[nt][1] + bj;
      vr[2] = acc2[nt][2] + bj; vr[3] = acc2[nt][3] + bj;
      if (store_ea){
        const size_t rowb = (size_t)(eb + tb + 16*w + 4*kg)*64 + (j & ~1);
#pragma unroll
        for (int r = 0; r < 4; ++r){
          unsigned short hu = __builtin_bit_cast(unsigned short, (__bf16)vr[r]);
          int pu = __shfl_xor((int)hu, 1);
          if (!(m & 1)){
            unsigned word = (unsigned)hu | ((unsigned)(pu & 0xffff) << 16);
            *(unsigned*)(ea_out + rowb + (size_t)r*64) = word;
          }
        }
      }
      p0 = fmaf(vr[0], vj, p0); p1 = fmaf(vr[1], vj, p1);
      p2 = fmaf(vr[2], vj, p2); p3 = fmaf(vr[3], vj, p3);
    }
#pragma unroll
    for (int o = 8; o; o >>= 1){
      p0 += __shfl_xor(p0, o); p1 += __shfl_xor(p1, o);
      p2 += __shfl_xor(p2, o); p3 += __shfl_xor(p3, o);
    }
    if (m == 0){
      float pv[4] = {p0, p1, p2, p3};
#pragma unroll
      for (int r = 0; r < 4; ++r){
        const int erow = 16*w + 4*kg + r;
        float logit = sb[tb + erow] + pv[r];
        lrelu[eb + tb + erow] = logit > 0.f ? logit : NEG_SLOPE * logit;
      }
    }
  };

  tile_compute(A00, A01, &uvh[0][0], 0);
  asm volatile("" ::: "memory");   // tile0 ehw reads before tile1 ehw writes
  tile_compute(A10, A11, &uvh[1][0], 64);
}

// ---------------- segment softmax + aggregation: one wave per col, 4-way unrolled
__global__ __launch_bounds__(256) void col_agg(
    const float* __restrict__ lrelu, const int* __restrict__ srow,
    const int* __restrict__ off, const __bf16* __restrict__ xwH,
    float* __restrict__ h)
{
  __shared__ float zS[4][128];
  __shared__ int   rS[4][128];
  const int t = threadIdx.x;
  const int lane = t & 63;
  const int wv = t >> 6;
  const int c = blockIdx.x * 4 + wv;
  const int s0 = off[c], s1 = off[c+1];
  const int L = s1 - s0;

  float l0 = (lane < L)    ? lrelu[s0+lane]    : -3.402823466e38f;
  float l1 = (lane+64 < L) ? lrelu[s0+64+lane] : -3.402823466e38f;
  int   r0 = (lane < L)    ? srow[s0+lane]     : 0;
  int   r1 = (lane+64 < L) ? srow[s0+64+lane]  : 0;

  float m = fmaxf(l0, l1);
  for (int i = lane+128; i < L; i += 64) m = fmaxf(m, lrelu[s0+i]);
#pragma unroll
  for (int o = 32; o; o >>= 1) m = fmaxf(m, __shfl_xor(m, o));

  float z0 = (lane < L)    ? expf(l0 - m) : 0.f;
  float z1 = (lane+64 < L) ? expf(l1 - m) : 0.f;
  float s = z0 + z1;
  for (int i = lane+128; i < L; i += 64) s += expf(lrelu[s0+i] - m);
#pragma unroll
  for (int o = 32; o; o >>= 1) s += __shfl_xor(s, o);
  const float inv = 1.f / (s + 1e-16f);

  zS[wv][lane] = z0;  zS[wv][64+lane] = z1;
  rS[wv][lane] = r0;  rS[wv][64+lane] = r1;
  asm volatile("" ::: "memory");   // same-wave LDS write->read ordering

  float hv0 = 0.f, hv1 = 0.f, hv2 = 0.f, hv3 = 0.f;
  if (L <= 128){
    int i = 0;
    for (; i + 4 <= L; i += 4){
      float za = zS[wv][i],   zb = zS[wv][i+1], zc = zS[wv][i+2], zd = zS[wv][i+3];
      int   ra = rS[wv][i],   rb = rS[wv][i+1], rc = rS[wv][i+2], rd = rS[wv][i+3];
      hv0 = fmaf(za, (float)xwH[(size_t)ra*64 + lane], hv0);
      hv1 = fmaf(zb, (float)xwH[(size_t)rb*64 + lane], hv1);
      hv2 = fmaf(zc, (float)xwH[(size_t)rc*64 + lane], hv2);
      hv3 = fmaf(zd, (float)xwH[(size_t)rd*64 + lane], hv3);
    }
    for (; i < L; ++i)
      hv0 = fmaf(zS[wv][i], (float)xwH[(size_t)rS[wv][i]*64 + lane], hv0);
  } else {
    for (int i = 0; i < L; ++i){
      float z = expf(lrelu[s0+i] - m);
      int r = srow[s0+i];
      hv0 = fmaf(z, (float)xwH[(size_t)r*64 + lane], hv0);
    }
  }
  h[(size_t)c*64 + lane] = ((hv0 + hv1) + (hv2 + hv3)) * inv;
}

// ---------------- BN stats (sum, sumsq per dim)
__global__ __launch_bounds__(256) void bn_stats(
    const float* __restrict__ h, float* __restrict__ musum, float* __restrict__ sqsum)
{
  const int t = threadIdx.x;
  const int d = t & 63, sub = t >> 6;
  const int base = blockIdx.x * 256;
  float s = 0.f, s2 = 0.f;
  for (int i = sub; i < 256; i += 4){
    int n = base + i;
    if (n < NN){ float v = h[(size_t)n*64 + d]; s += v; s2 = fmaf(v, v, s2); }
  }
  __shared__ float r1[4][64], r2[4][64];
  r1[sub][d] = s; r2[sub][d] = s2;
  __syncthreads();
  if (sub == 0){
    s  = r1[0][d] + r1[1][d] + r1[2][d] + r1[3][d];
    s2 = r2[0][d] + r2[1][d] + r2[2][d] + r2[3][d];
    atomicAdd(&musum[d], s);
    atomicAdd(&sqsum[d], s2);
  }
}

// ---------------- mean pool over graphs, BN+ReLU of layer 2 fused
__global__ __launch_bounds__(256) void seg_pool(
    const float* __restrict__ h, const int* __restrict__ goff,
    const float* __restrict__ musum, const float* __restrict__ sqsum,
    const float* __restrict__ gamma2, const float* __restrict__ beta2,
    float* __restrict__ pools, float* __restrict__ pcnt)
{
  const int g = blockIdx.x;
  const int t = threadIdx.x;
  const int d = t & 63, sub = t >> 6;
  const int s0 = goff[g], s1 = goff[g+1];
  float mu  = musum[d] * (1.0f / NN);
  float var = sqsum[d] * (1.0f / NN) - mu * mu;
  float iv  = rsqrtf(var + 1e-5f) * gamma2[d];
  float shv = beta2[d] - mu * iv;
  float s = 0.f;
  for (int n = s0 + sub; n < s1; n += 4)
    s += fmaxf(fmaf(h[(size_t)n*64 + d], iv, shv), 0.f);
  __shared__ float r[4][64];
  r[sub][d] = s;
  __syncthreads();
  if (sub == 0){
    s = r[0][d] + r[1][d] + r[2][d] + r[3][d];
    pools[g*64 + d] = s;
    if (d == 0) pcnt[g] = (float)(s1 - s0);
  }
}

// ---------------- readout MLP (one block)
__global__ __launch_bounds__(256) void final_mlp(
    const float* __restrict__ pools, const float* __restrict__ pcnt,
    const float* __restrict__ w1, const float* __restrict__ b1,
    const float* __restrict__ w2, const float* __restrict__ b2,
    const float* __restrict__ w3, const float* __restrict__ b3,
    float* __restrict__ out)
{
  __shared__ float g[32*64], h1[32*64], h2[32*32];
  const int t = threadIdx.x;
  for (int i = t; i < 2048; i += 256) g[i] = pools[i] / fmaxf(pcnt[i >> 6], 1.0f);
  __syncthreads();
  for (int i = t; i < 2048; i += 256){
    int gi = i >> 6, d = i & 63;
    float a = b1[d];
    for (int k = 0; k < 64; ++k) a = fmaf(g[gi*64 + k], w1[k*64 + d], a);
    h1[i] = fmaxf(a, 0.f);
  }
  __syncthreads();
  for (int i = t; i < 1024; i += 256){
    int gi = i >> 5, d = i & 31;
    float a = b2[d];
    for (int k = 0; k < 64; ++k) a = fmaf(h1[gi*64 + k], w2[k*32 + d], a);
    h2[i] = fmaxf(a, 0.f);
  }
  __syncthreads();
  if (t < 32){
    float a = b3[0];
    for (int k = 0; k < 32; ++k) a = fmaf(h2[t*32 + k], w3[k], a);
    out[t] = a;
  }
}

extern "C" void kernel_launch(void* const* d_in, const int* in_sizes, int n_in,
                              void* d_out, int out_size, void* d_ws, size_t ws_size,
                              hipStream_t stream)
{
  (void)in_sizes; (void)n_in; (void)out_size; (void)ws_size;
  const float* x0       = (const float*)d_in[0];
  const int*   ei       = (const int*)  d_in[1];
  const float* ea0      = (const float*)d_in[2];
  const int*   batch    = (const int*)  d_in[3];
  const float* em_w1    = (const float*)d_in[4];
  const float* em_b1    = (const float*)d_in[5];
  const float* em_w2    = (const float*)d_in[6];
  const float* em_b2    = (const float*)d_in[7];
  const float* gat_w    = (const float*)d_in[8];
  const float* att_src  = (const float*)d_in[9];
  const float* att_dst  = (const float*)d_in[10];
  const float* edge_w   = (const float*)d_in[11];
  const float* att_edge = (const float*)d_in[12];
  // d_in[13] gat_bias: cancels inside BatchNorm -> unused
  const float* bn_gamma = (const float*)d_in[14];
  const float* bn_beta  = (const float*)d_in[15];
  const float* mlp_w1   = (const float*)d_in[16];
  const float* mlp_b1   = (const float*)d_in[17];
  const float* mlp_w2   = (const float*)d_in[18];
  const float* mlp_b2   = (const float*)d_in[19];
  const float* mlp_w3   = (const float*)d_in[20];
  const float* mlp_b3   = (const float*)d_in[21];
  float* out = (float*)d_out;

  const size_t N64 = (size_t)NN * 64, E64 = (size_t)NE * 64;
  float* ws    = (float*)d_ws;
  float* wsE   = ws;                 // E64 f32 slots; used as bf16 edge_attr (sorted)
  float* sxa   = wsE + E64;          // N64 f32 slot -> bf16 xaH (= x@W1a + b1)
  float* sxb   = sxa + N64;          // N64 f32 slot -> bf16 xbH
  float* sxw   = sxb + N64;          // N64 f32 slot -> bf16 xwH
  float* hbuf  = sxw + N64;          // N64
  float* musum = hbuf + N64;         // 64  -- memset after node_prep each layer
  float* sqsum = musum + 64;         // 64
  float* lrelu = sqsum + 64;         // NE
  float* pools = lrelu + NE;         // 2048
  float* pcnt  = pools + 2048;       // 32
  float* ssrc  = pcnt + 32;          // NN
  float* sdst  = ssrc + NN;          // NN
  int*   cnt   = (int*)(sdst + NN);  // NN  -- once memset start
  int*   cur   = cnt + NN;           // NN  -- once memset end
  int*   soff  = cur + NN;           // NN+1
  int*   srow  = soff + NN + 1;      // NE
  int*   scol  = srow + NE;          // NE
  int*   perm  = scol + NE;          // NE
  int*   goff  = perm + NE;          // 33 (pad to 40 for alignment)
  __bf16* eaB  = (__bf16*)wsE;
  __bf16* xaH  = (__bf16*)sxa;
  __bf16* xbH  = (__bf16*)sxb;
  __bf16* xwH  = (__bf16*)sxw;
  __bf16* w1f  = (__bf16*)(goff + 40);   // 3*4096 bf16
  __bf16* w2f  = w1f + 3*4096;           // 3*4096 bf16
  float* vbuf  = (float*)(w2f + 3*4096); // 3*64 f32

  // ---- one-time per call: counting sort by col, graph bounds, weight fragments
  hipMemsetAsync(cnt, 0, 2 * NN * sizeof(int), stream);
  hist_kernel<<<NE / 256, 256, 0, stream>>>(ei + NE, cnt);
  scan_kernel<<<1, 256, 0, stream>>>(cnt, soff);
  scatter_kernel<<<NE / 256, 256, 0, stream>>>(ei, soff, cur, srow, scol, perm);
  graph_bounds<<<(NN + 255) / 256, 256, 0, stream>>>(batch, goff);
  prep_weights<<<3, 256, 0, stream>>>(em_w1, em_w2, edge_w, att_edge, w1f, w2f, vbuf);

  for (int l = 0; l < 3; ++l){
    dim3 npg((NN + 63) / 64, 3);
    node_prep<<<npg, 256, 0, stream>>>(           // consumes stats of layer l-1
        x0, hbuf, musum, sqsum, bn_gamma, bn_beta,
        em_w1, em_b1, gat_w, att_src, att_dst, xaH, xbH, xwH, ssrc, sdst, l);

    hipMemsetAsync(musum, 0, 128 * sizeof(float), stream);   // reset for layer l stats

    edge_mlp<<<NE / 128, 256, 0, stream>>>(
        (l == 0) ? ea0 : nullptr, eaB, eaB, xaH, xbH, ssrc, sdst,
        srow, scol, (l == 0) ? perm : nullptr,
        w1f + (size_t)l*4096, w2f + (size_t)l*4096,
        em_b2 + l*64, vbuf + l*64, lrelu, (l < 2) ? 1 : 0);

    col_agg<<<NN / 4, 256, 0, stream>>>(lrelu, srow, soff, xwH, hbuf);

    bn_stats<<<(NN + 255) / 256, 256, 0, stream>>>(hbuf, musum, sqsum);
  }

  seg_pool<<<32, 256, 0, stream>>>(hbuf, goff, musum, sqsum,
                                   bn_gamma + 128, bn_beta + 128, pools, pcnt);
  final_mlp<<<1, 256, 0, stream>>>(pools, pcnt, mlp_w1, mlp_b1, mlp_w2, mlp_b2,
                                   mlp_w3, mlp_b3, out);
}